// Round 10
// baseline (461.060 us; speedup 1.0000x reference)
//
#include <hip/hip_runtime.h>
#include <hip/hip_bf16.h>
#include <hip/hip_fp16.h>

// B=2, N=1024, C=512, H=8, D=64, m=128, p=8
#define Hh 8
#define Bz 2
#define Nn 1024
#define Cc 512
#define Dd 64
#define Mm 128
#define NS_EPS 1e-4f
#define WHITE_EPS 1e-5f

__device__ __forceinline__ float h2f(__half v) { return __half2float(v); }
__device__ __forceinline__ __half f2h(float v) { return __float2half(v); }

typedef _Float16 half8 __attribute__((ext_vector_type(8)));
typedef float float4v __attribute__((ext_vector_type(4)));

// ---------------------------------------------------------------------------
// K1: QKV GEMM via MFMA f16. M=2048, N=1536, K=512. Block tile 128x128.
__global__ __launch_bounds__(256) void qkv_gemm(
    const float* __restrict__ x, const float* __restrict__ w,
    const float* __restrict__ bias, const float* __restrict__ tm,
    __half* __restrict__ Q, __half* __restrict__ K, __half* __restrict__ V) {
  __shared__ _Float16 As[128 * 40];
  __shared__ _Float16 Bs[128 * 40];
  int m0 = blockIdx.x * 128, n0 = blockIdx.y * 128;
  int tid = threadIdx.x;
  int lane = tid & 63, wv = tid >> 6;
  int wm = (wv >> 1) * 64, wn = (wv & 1) * 64;
  int l15 = lane & 15, quad = lane >> 4;
  int srow = tid >> 1, shalf = tid & 1;
  float4v acc[4][4] = {};
  for (int k0 = 0; k0 < 512; k0 += 32) {
    __syncthreads();
    {
      const float4* ga = (const float4*)(x + (size_t)(m0 + srow) * 512 + k0 + shalf * 16);
      const float4* gb = (const float4*)(w + (size_t)(n0 + srow) * 512 + k0 + shalf * 16);
      float4 a0 = ga[0], a1 = ga[1], a2 = ga[2], a3 = ga[3];
      float4 b0 = gb[0], b1 = gb[1], b2 = gb[2], b3 = gb[3];
      half8 ha0 = {(_Float16)a0.x, (_Float16)a0.y, (_Float16)a0.z, (_Float16)a0.w,
                   (_Float16)a1.x, (_Float16)a1.y, (_Float16)a1.z, (_Float16)a1.w};
      half8 ha1 = {(_Float16)a2.x, (_Float16)a2.y, (_Float16)a2.z, (_Float16)a2.w,
                   (_Float16)a3.x, (_Float16)a3.y, (_Float16)a3.z, (_Float16)a3.w};
      half8 hb0 = {(_Float16)b0.x, (_Float16)b0.y, (_Float16)b0.z, (_Float16)b0.w,
                   (_Float16)b1.x, (_Float16)b1.y, (_Float16)b1.z, (_Float16)b1.w};
      half8 hb1 = {(_Float16)b2.x, (_Float16)b2.y, (_Float16)b2.z, (_Float16)b2.w,
                   (_Float16)b3.x, (_Float16)b3.y, (_Float16)b3.z, (_Float16)b3.w};
      int lo = srow * 40 + shalf * 16;
      *(half8*)&As[lo] = ha0;
      *(half8*)&As[lo + 8] = ha1;
      *(half8*)&Bs[lo] = hb0;
      *(half8*)&Bs[lo + 8] = hb1;
    }
    __syncthreads();
    half8 a[4], b[4];
#pragma unroll
    for (int mt = 0; mt < 4; ++mt)
      a[mt] = *(const half8*)&As[(wm + mt * 16 + l15) * 40 + quad * 8];
#pragma unroll
    for (int nt = 0; nt < 4; ++nt)
      b[nt] = *(const half8*)&Bs[(wn + nt * 16 + l15) * 40 + quad * 8];
#pragma unroll
    for (int mt = 0; mt < 4; ++mt)
#pragma unroll
      for (int nt = 0; nt < 4; ++nt)
        acc[mt][nt] =
            __builtin_amdgcn_mfma_f32_16x16x32_f16(a[mt], b[nt], acc[mt][nt], 0, 0, 0);
  }
#pragma unroll
  for (int mt = 0; mt < 4; ++mt) {
#pragma unroll
    for (int r = 0; r < 4; ++r) {
      int row = m0 + wm + mt * 16 + quad * 4 + r;
      int b_ = row >> 10, n_ = row & 1023;
      float t = tm[b_ * 1024 + n_];
#pragma unroll
      for (int nt = 0; nt < 4; ++nt) {
        int c3 = n0 + wn + nt * 16 + l15;
        float v = (acc[mt][nt][r] + bias[c3]) * t;
        int sec = c3 >> 9, ch = c3 & 511;
        __half* dst = (sec == 0) ? Q : (sec == 1 ? K : V);
        dst[(size_t)b_ * (Nn * Cc) + (size_t)n_ * 512 + ch] = f2h(v);
      }
    }
  }
}

// ---------------------------------------------------------------------------
// K2: pool — block per (b,h,u-tile of 64). Coalesced row staging.
__global__ __launch_bounds__(256) void pool_kernel(
    const __half* __restrict__ Q, const __half* __restrict__ K,
    const float* __restrict__ tm, __half* __restrict__ QL,
    __half* __restrict__ KL, float* __restrict__ LM) {
  int ut = blockIdx.x;
  int bh = blockIdx.y;
  int b = bh >> 3, h = bh & 7;
  int u0 = ut * 64;
  int delta = u0 >> 9;
  int ch0 = u0 & 511;
  __shared__ float Qs[64][65];
  __shared__ float Ks[64][65];
  int tid = threadIdx.x;
  for (int e = tid; e < 4096; e += 256) {
    int d = e >> 6, uu = e & 63;
    int row = 2 * (h * 64 + d) + delta;
    size_t gi = (size_t)b * (Nn * Cc) + (size_t)row * 512 + ch0 + uu;
    Qs[d][uu] = h2f(Q[gi]);
    Ks[d][uu] = h2f(K[gi]);
  }
  __syncthreads();
  int d = tid & 63, s = tid >> 6;
#pragma unroll
  for (int jr = 0; jr < 2; ++jr) {
    int jl = s + 4 * jr;
    int j = ut * 8 + jl;
    float pm = 0.f, sq = 0.f, sk = 0.f;
#pragma unroll
    for (int i = 0; i < 8; ++i) {
      float t = tm[b * 1024 + 8 * j + i];
      pm += t;
      sq += Qs[d][8 * jl + i] * t;
      sk += Ks[d][8 * jl + i] * t;
    }
    pm *= 0.125f;
    float pms = fmaxf(pm, 1e-6f);
    size_t oi = ((size_t)bh * 128 + j) * 64 + d;
    QL[oi] = f2h(sq * 0.125f / pms);
    KL[oi] = f2h(sk * 0.125f / pms);
    if (h == 0 && d == 0) LM[b * 128 + j] = (pm > 0.f) ? 1.f : 0.f;
  }
}

// ---------------------------------------------------------------------------
// K3: wbuild_ns — fused W_eps build + Frobenius + X0 = scale * W^T.
// One block per bh. W stored to global (d_out) for ns_iter; X0 to XA.
__global__ __launch_bounds__(256) void wbuild_ns(
    const __half* __restrict__ QL, const __half* __restrict__ KL,
    const float* __restrict__ LM, float* __restrict__ W, float* __restrict__ X0) {
  int bh = blockIdx.x;
  int b = bh >> 3;
  __shared__ float smem[128 * 130];  // phase1: ks/qs; phase2: Wlds[i*129+j]
  __shared__ float red[256];
  float* ks = smem;             // [128][65]
  float* qs = smem + 128 * 65;  // [128][65]
  int tid = threadIdx.x;
  for (int e = tid; e < 8192; e += 256) {
    ks[(e >> 6) * 65 + (e & 63)] = h2f(KL[(size_t)bh * 8192 + e]);
    qs[(e >> 6) * 65 + (e & 63)] = h2f(QL[(size_t)bh * 8192 + e]);
  }
  __syncthreads();
  float wv[64];
#pragma unroll 4
  for (int k = 0; k < 64; ++k) {
    int e = tid + k * 256;
    int i = e >> 7, j = e & 127;
    float s = 0.f;
#pragma unroll
    for (int d = 0; d < 64; ++d) s += fabsf(qs[i * 65 + d] - ks[j * 65 + d]);
    float w0 = expf(-s * 0.25f);
    float pr = LM[b * Mm + i] * LM[b * Mm + j];
    float diag = (i == j) ? 1.f : 0.f;
    wv[k] = w0 * pr + diag * (1.f - pr) + diag * NS_EPS;
  }
  __syncthreads();  // everyone done reading ks/qs
  float fro = 0.f;
#pragma unroll 4
  for (int k = 0; k < 64; ++k) {
    int e = tid + k * 256;
    int i = e >> 7, j = e & 127;
    smem[i * 129 + j] = wv[k];
    W[(size_t)bh * 16384 + e] = wv[k];
    fro += wv[k] * wv[k];
  }
  red[tid] = fro;
  __syncthreads();
  for (int off = 128; off > 0; off >>= 1) {
    if (tid < off) red[tid] += red[tid + off];
    __syncthreads();
  }
  float scale = 2.f / (sqrtf(red[0]) + 1e-8f);
#pragma unroll 4
  for (int k = 0; k < 64; ++k) {
    int e = tid + k * 256;
    int i = e >> 7, j = e & 127;
    X0[(size_t)bh * 16384 + e] = scale * smem[j * 129 + i];
  }
}

// ---------------------------------------------------------------------------
// K5: ns_iter — Xn = Xc @ (2I - W @ Xc), 8 column-blocks of 16.
__global__ __launch_bounds__(256) void ns_iter(const float* __restrict__ W,
                                               const float* __restrict__ Xc,
                                               float* __restrict__ Xn) {
  int bh = blockIdx.y;
  int cb = blockIdx.x;  // 0..7
  const float* Wb = W + (size_t)bh * 16384;
  const float* Xb = Xc + (size_t)bh * 16384;
  float* Ob = Xn + (size_t)bh * 16384;
  __shared__ float Xs[128][17];
  __shared__ float Ts[128][17];
  __shared__ float St[128][33];
  int tid = threadIdx.x;
  int jc = tid & 15;
  int ibase = (tid >> 4) * 8;
  for (int e = tid; e < 2048; e += 256) {
    int k = e >> 4, j = e & 15;
    Xs[k][j] = Xb[(size_t)k * 128 + cb * 16 + j];
  }
  float acc[8];
#pragma unroll
  for (int r = 0; r < 8; ++r) acc[r] = 0.f;
  for (int kt = 0; kt < 4; ++kt) {
    __syncthreads();
    for (int e = tid; e < 4096; e += 256)
      St[e >> 5][e & 31] = Wb[(size_t)(e >> 5) * 128 + kt * 32 + (e & 31)];
    __syncthreads();
#pragma unroll 8
    for (int kk = 0; kk < 32; ++kk) {
      float xv = Xs[kt * 32 + kk][jc];
#pragma unroll
      for (int r = 0; r < 8; ++r) acc[r] += St[ibase + r][kk] * xv;
    }
  }
#pragma unroll
  for (int r = 0; r < 8; ++r) {
    int i = ibase + r;
    Ts[i][jc] = ((i == cb * 16 + jc) ? 2.f : 0.f) - acc[r];
  }
  float acc2[8];
#pragma unroll
  for (int r = 0; r < 8; ++r) acc2[r] = 0.f;
  for (int kt = 0; kt < 4; ++kt) {
    __syncthreads();
    for (int e = tid; e < 4096; e += 256)
      St[e >> 5][e & 31] = Xb[(size_t)(e >> 5) * 128 + kt * 32 + (e & 31)];
    __syncthreads();
#pragma unroll 8
    for (int kk = 0; kk < 32; ++kk) {
      float tv = Ts[kt * 32 + kk][jc];
#pragma unroll
      for (int r = 0; r < 8; ++r) acc2[r] += St[ibase + r][kk] * tv;
    }
  }
#pragma unroll
  for (int r = 0; r < 8; ++r)
    Ob[(size_t)(ibase + r) * 128 + cb * 16 + jc] = acc2[r];
}

// ---------------------------------------------------------------------------
// K7: ktv v5 — fused C_k + K^T V. 32 j per block, half8 staging,
// 2jx2n register-tiled L1 phase, (1j x 8d) PV phase.
__global__ __launch_bounds__(256) void ktv_fused(
    const __half* __restrict__ K, const __half* __restrict__ QL,
    const float* __restrict__ LM, const __half* __restrict__ V,
    float* __restrict__ KTV) {
  int jt = blockIdx.x;   // 4 (32 j each)
  int bh = blockIdx.y;   // 16
  int nc = blockIdx.z;   // 8 (128 n each)
  int b = bh >> 3, h = bh & 7;
  int j0 = jt * 32;
  __shared__ __align__(16) float qls[32 * 68];
  __shared__ __align__(16) float Ks[32 * 68];
  __shared__ __align__(16) float Vs[32 * 68];
  __shared__ float P[32 * 36];
  int tid = threadIdx.x;
  int sr = tid >> 3, sd8 = (tid & 7) * 8;
  {
    half8 q = *(const half8*)(QL + (size_t)bh * 8192 + (size_t)(j0 + sr) * 64 + sd8);
    float4 f0 = {(float)q[0], (float)q[1], (float)q[2], (float)q[3]};
    float4 f1 = {(float)q[4], (float)q[5], (float)q[6], (float)q[7]};
    *(float4*)&qls[sr * 68 + sd8] = f0;
    *(float4*)&qls[sr * 68 + sd8 + 4] = f1;
  }
  int jq = tid & 15, nq = tid >> 4;   // L1: j = jq*2(+1), n = nq*2(+1)
  int dq2 = tid & 7, jl = tid >> 3;   // PV: d8 = dq2*8, j = jl
  float acc[8] = {};
  for (int nt = 0; nt < 4; ++nt) {
    int n0 = nc * 128 + nt * 32;
    __syncthreads();
    {
      size_t gi = (size_t)b * (Nn * Cc) + (size_t)(n0 + sr) * 512 + h * 64 + sd8;
      half8 kv = *(const half8*)(K + gi);
      half8 vv = *(const half8*)(V + gi);
      float4 k0 = {(float)kv[0], (float)kv[1], (float)kv[2], (float)kv[3]};
      float4 k1 = {(float)kv[4], (float)kv[5], (float)kv[6], (float)kv[7]};
      float4 v0 = {(float)vv[0], (float)vv[1], (float)vv[2], (float)vv[3]};
      float4 v1 = {(float)vv[4], (float)vv[5], (float)vv[6], (float)vv[7]};
      *(float4*)&Ks[sr * 68 + sd8] = k0;
      *(float4*)&Ks[sr * 68 + sd8 + 4] = k1;
      *(float4*)&Vs[sr * 68 + sd8] = v0;
      *(float4*)&Vs[sr * 68 + sd8 + 4] = v1;
    }
    __syncthreads();
    {
      const float4* q0p = (const float4*)&qls[(jq * 2) * 68];
      const float4* q1p = (const float4*)&qls[(jq * 2 + 1) * 68];
      const float4* k0p = (const float4*)&Ks[(nq * 2) * 68];
      const float4* k1p = (const float4*)&Ks[(nq * 2 + 1) * 68];
      float s00 = 0.f, s01 = 0.f, s10 = 0.f, s11 = 0.f;
#pragma unroll
      for (int i = 0; i < 16; ++i) {
        int dq = (i + tid) & 15;
        float4 q0 = q0p[dq], q1 = q1p[dq];
        float4 k0 = k0p[dq], k1 = k1p[dq];
        s00 += fabsf(q0.x - k0.x) + fabsf(q0.y - k0.y) + fabsf(q0.z - k0.z) + fabsf(q0.w - k0.w);
        s01 += fabsf(q0.x - k1.x) + fabsf(q0.y - k1.y) + fabsf(q0.z - k1.z) + fabsf(q0.w - k1.w);
        s10 += fabsf(q1.x - k0.x) + fabsf(q1.y - k0.y) + fabsf(q1.z - k0.z) + fabsf(q1.w - k0.w);
        s11 += fabsf(q1.x - k1.x) + fabsf(q1.y - k1.y) + fabsf(q1.z - k1.z) + fabsf(q1.w - k1.w);
      }
      P[(nq * 2) * 36 + jq * 2] = expf(-s00 * 0.25f);
      P[(nq * 2) * 36 + jq * 2 + 1] = expf(-s10 * 0.25f);
      P[(nq * 2 + 1) * 36 + jq * 2] = expf(-s01 * 0.25f);
      P[(nq * 2 + 1) * 36 + jq * 2 + 1] = expf(-s11 * 0.25f);
    }
    __syncthreads();
    {
#pragma unroll 4
      for (int n = 0; n < 32; ++n) {
        float p = P[n * 36 + jl];
        float4 v0 = *(const float4*)&Vs[n * 68 + dq2 * 8];
        float4 v1 = *(const float4*)&Vs[n * 68 + dq2 * 8 + 4];
        acc[0] += p * v0.x; acc[1] += p * v0.y; acc[2] += p * v0.z; acc[3] += p * v0.w;
        acc[4] += p * v1.x; acc[5] += p * v1.y; acc[6] += p * v1.z; acc[7] += p * v1.w;
      }
    }
  }
  {
    float lm = LM[b * 128 + j0 + jl];
    float* dst = &KTV[(size_t)bh * 8192 + (size_t)(j0 + jl) * 64 + dq2 * 8];
#pragma unroll
    for (int u = 0; u < 8; ++u) atomicAdd(dst + u, acc[u] * lm);
  }
}

// ---------------------------------------------------------------------------
// K8: CTX[bh,i,d] = sum_j X[bh,i,j] * KTV[bh,j,d]  (f32 in, f16 out)
__global__ __launch_bounds__(256) void ctx_kernel(const float* __restrict__ X,
                                                  const float* __restrict__ KTV,
                                                  __half* __restrict__ CTX) {
  int bh = blockIdx.y;
  int i = blockIdx.x * 4 + (threadIdx.x >> 6);
  int d = threadIdx.x & 63;
  const float* wb = X + (size_t)bh * 16384 + (size_t)i * 128;
  const float* kb = KTV + (size_t)bh * 8192 + d;
  float acc = 0.f;
#pragma unroll 4
  for (int jj = 0; jj < 128; ++jj) acc += wb[jj] * kb[(size_t)jj * 64];
  CTX[(size_t)bh * 8192 + (size_t)i * 64 + d] = f2h(acc);
}

// ---------------------------------------------------------------------------
// K9: stats_partial v3 — float4 LDS reads, 2j x 4n register tile.
__global__ __launch_bounds__(256) void stats_partial(
    const __half* __restrict__ Q, const __half* __restrict__ KL,
    const float* __restrict__ LM, const float* __restrict__ tm,
    float* __restrict__ PS, __half* __restrict__ Pbuf) {
  int nt = blockIdx.x;   // 64
  int bh = blockIdx.y;   // 16
  int b = bh >> 3, h = bh & 7;
  int n0 = nt * 16;
  __shared__ __align__(16) float kls[128 * 68];
  __shared__ __align__(16) float qs[16 * 68];
  __shared__ __half ps[16 * 132];
  __shared__ float part[128 * 12];
  int tid = threadIdx.x;
  for (int e = tid; e < 8192; e += 256)
    kls[(e >> 6) * 68 + (e & 63)] = h2f(KL[(size_t)bh * 8192 + e]);
  for (int e = tid; e < 1024; e += 256)
    qs[(e >> 6) * 68 + (e & 63)] =
        h2f(Q[(size_t)b * (Nn * Cc) + (size_t)(n0 + (e >> 6)) * 512 + h * 64 + (e & 63)]);
  __syncthreads();
  int jg = tid & 63, ng = tid >> 6;
  int j = jg * 2;
  const float4* kA = (const float4*)&kls[j * 68];
  const float4* kB = (const float4*)&kls[(j + 1) * 68];
  float sA[4] = {}, sB[4] = {};
#pragma unroll
  for (int i = 0; i < 16; ++i) {
    int dq = (i + jg) & 15;
    float4 ka = kA[dq];
    float4 kb = kB[dq];
#pragma unroll
    for (int r = 0; r < 4; ++r) {
      float4 qv = *(const float4*)&qs[(ng * 4 + r) * 68 + dq * 4];
      sA[r] += fabsf(qv.x - ka.x) + fabsf(qv.y - ka.y) + fabsf(qv.z - ka.z) + fabsf(qv.w - ka.w);
      sB[r] += fabsf(qv.x - kb.x) + fabsf(qv.y - kb.y) + fabsf(qv.z - kb.z) + fabsf(qv.w - kb.w);
    }
  }
  float lmA = LM[b * 128 + j], lmB = LM[b * 128 + j + 1];
  float a1 = 0.f, a2 = 0.f, a3 = 0.f, b1 = 0.f, b2 = 0.f, b3 = 0.f;
#pragma unroll
  for (int r = 0; r < 4; ++r) {
    int nn = ng * 4 + r;
    float t = tm[b * 1024 + n0 + nn];
    float xa = expf(-sA[r] * 0.25f) * lmA;
    float xb = expf(-sB[r] * 0.25f) * lmB;
    ps[nn * 132 + j] = f2h(xa);
    ps[nn * 132 + j + 1] = f2h(xb);
    float xta = xa * t, xtb = xb * t;
    a1 += xta; a2 += xta * xta; a3 += xta * t;
    b1 += xtb; b2 += xtb * xtb; b3 += xtb * t;
  }
  part[j * 12 + ng * 3 + 0] = a1;
  part[j * 12 + ng * 3 + 1] = a2;
  part[j * 12 + ng * 3 + 2] = a3;
  part[(j + 1) * 12 + ng * 3 + 0] = b1;
  part[(j + 1) * 12 + ng * 3 + 1] = b2;
  part[(j + 1) * 12 + ng * 3 + 2] = b3;
  __syncthreads();
  for (int e = tid; e < 2048; e += 256)
    Pbuf[((size_t)bh * 1024 + n0 + (e >> 7)) * 128 + (e & 127)] =
        ps[(e >> 7) * 132 + (e & 127)];
  if (tid < 128) {
    float s1 = part[tid * 12 + 0] + part[tid * 12 + 3] + part[tid * 12 + 6] + part[tid * 12 + 9];
    float s2 = part[tid * 12 + 1] + part[tid * 12 + 4] + part[tid * 12 + 7] + part[tid * 12 + 10];
    float s3 = part[tid * 12 + 2] + part[tid * 12 + 5] + part[tid * 12 + 8] + part[tid * 12 + 11];
    size_t base = ((size_t)(b * 64 + nt) * 8 + h) * 384 + tid * 3;
    PS[base] = s1; PS[base + 1] = s2; PS[base + 2] = s3;
  }
}

// ---------------------------------------------------------------------------
// K10: stats_final — reduce PS over 128 (b,nt) tiles per (h,j).
__global__ __launch_bounds__(256) void stats_final(const float* __restrict__ PS,
                                                   const float* __restrict__ tm,
                                                   float* __restrict__ MU,
                                                   float* __restrict__ RS) {
  __shared__ float red[256][2];
  __shared__ float ts0, ts1;
  int tid = threadIdx.x;
  float a = 0.f, c = 0.f;
  for (int i = tid; i < 2048; i += 256) { float t = tm[i]; a += t; c += t * t; }
  red[tid][0] = a; red[tid][1] = c;
  __syncthreads();
  for (int off = 128; off > 0; off >>= 1) {
    if (tid < off) { red[tid][0] += red[tid + off][0]; red[tid][1] += red[tid + off][1]; }
    __syncthreads();
  }
  if (tid == 0) { ts0 = red[0][0]; ts1 = red[0][1]; }
  __syncthreads();
  int hj = blockIdx.x * 256 + tid;
  int h = hj >> 7, j = hj & 127;
  float s1 = 0.f, s2 = 0.f, s3 = 0.f;
  for (int bnt = 0; bnt < 128; ++bnt) {
    const float* p = PS + ((size_t)bnt * 8 + h) * 384 + j * 3;
    s1 += p[0]; s2 += p[1]; s3 += p[2];
  }
  float valid = fmaxf(ts0, 1.f);
  float mu = s1 / valid;
  float var = (s2 - 2.f * mu * s3 + mu * mu * ts1) / valid;
  var = fmaxf(var, 0.f);
  MU[hj] = mu;
  RS[hj] = rsqrtf(var + WHITE_EPS);
}

// ---------------------------------------------------------------------------
// K11: vlocal — LDS-tiled scrambled depthwise conv.
__global__ __launch_bounds__(256) void vlocal_kernel(
    const __half* __restrict__ V, const float* __restrict__ dwc_w,
    const float* __restrict__ dwc_b, const float* __restrict__ tm,
    __half* __restrict__ VL) {
  int t0 = blockIdx.x * 64;
  int ct = blockIdx.y & 7, b = blockIdx.y >> 3;
  int c0 = ct * 64;
  __shared__ float vs[64][67];
  int tid = threadIdx.x;
  for (int e = tid; e < 64 * 66; e += 256) {
    int cl = e / 66, uu = e % 66;
    int u = t0 - 1 + uu;
    float val = 0.f;
    if (u >= 0 && u < 1024) {
      int c = c0 + cl;
      int n = 2 * c + (u >> 9), ch = u & 511;
      val = h2f(V[(size_t)b * (Nn * Cc) + (size_t)n * 512 + ch]);
    }
    vs[cl][uu] = val;
  }
  __syncthreads();
  int cl = tid & 63;
  int c = c0 + cl;
  float w0 = dwc_w[c * 3], w1 = dwc_w[c * 3 + 1], w2 = dwc_w[c * 3 + 2];
  float bb = dwc_b[c];
  int tg = tid >> 6;
#pragma unroll
  for (int i = 0; i < 16; ++i) {
    int tl = tg * 16 + i;
    int t = t0 + tl;
    float acc = bb + w0 * vs[cl][tl] + w1 * vs[cl][tl + 1] + w2 * vs[cl][tl + 2];
    VL[(size_t)b * (Nn * Cc) + (size_t)t * 512 + c] = f2h(acc * tm[b * 1024 + t]);
  }
}

// ---------------------------------------------------------------------------
// K12: ga — load precomputed P, whiten, @context, accumulate into VL.
__global__ __launch_bounds__(256) void ga_fused(
    const __half* __restrict__ Pbuf, const float* __restrict__ MU,
    const float* __restrict__ RS, const __half* __restrict__ CTXg,
    const float* __restrict__ tm, __half* __restrict__ VL) {
  int bh = blockIdx.y;
  int b = bh >> 3, h = bh & 7;
  int n0 = blockIdx.x * 16;
  __shared__ __half Ps[16][130];
  __shared__ __align__(16) __half2 ctx2[128][32];
  __shared__ float musr[128][2];
  int tid = threadIdx.x;
  for (int e = tid; e < 2048; e += 256)
    Ps[e >> 7][e & 127] = Pbuf[((size_t)bh * 1024 + n0 + (e >> 7)) * 128 + (e & 127)];
  {
    const __half2* cg = (const __half2*)(CTXg + (size_t)bh * 8192);
    for (int e = tid; e < 4096; e += 256) ctx2[e >> 5][e & 31] = cg[e];
  }
  if (tid < 128) { musr[tid][0] = MU[h * 128 + tid]; musr[tid][1] = RS[h * 128 + tid]; }
  __syncthreads();
  int nn = tid >> 4, dq = tid & 15;
  float a0 = 0.f, a1 = 0.f, a2 = 0.f, a3 = 0.f;
#pragma unroll 4
  for (int j = 0; j < 128; ++j) {
    float pj = (h2f(Ps[nn][j]) - musr[j][0]) * musr[j][1];
    uint2 cc = *(const uint2*)&ctx2[j][dq * 2];
    __half2 c01 = __builtin_bit_cast(__half2, cc.x);
    __half2 c23 = __builtin_bit_cast(__half2, cc.y);
    a0 += pj * h2f(c01.x); a1 += pj * h2f(c01.y);
    a2 += pj * h2f(c23.x); a3 += pj * h2f(c23.y);
  }
  float t = tm[b * 1024 + n0 + nn];
  float t2 = t * t;
  size_t base = (size_t)b * (Nn * Cc) + (size_t)(n0 + nn) * 512 + h * 64 + dq * 4;
  VL[base] = f2h(h2f(VL[base]) + t2 * a0);
  VL[base + 1] = f2h(h2f(VL[base + 1]) + t2 * a1);
  VL[base + 2] = f2h(h2f(VL[base + 2]) + t2 * a2);
  VL[base + 3] = f2h(h2f(VL[base + 3]) + t2 * a3);
}

// ---------------------------------------------------------------------------
// K13: proj via MFMA f16. M=2048, N=512, K=512.
__global__ __launch_bounds__(256) void proj_gemm(
    const __half* __restrict__ Ain, const float* __restrict__ w,
    const float* __restrict__ bias, const float* __restrict__ tm,
    float* __restrict__ out) {
  __shared__ _Float16 As[128 * 40];
  __shared__ _Float16 Bs[128 * 40];
  int m0 = blockIdx.x * 128, n0 = blockIdx.y * 128;
  int tid = threadIdx.x;
  int lane = tid & 63, wv = tid >> 6;
  int wm = (wv >> 1) * 64, wn = (wv & 1) * 64;
  int l15 = lane & 15, quad = lane >> 4;
  int srow = tid >> 1, shalf = tid & 1;
  float4v acc[4][4] = {};
  for (int k0 = 0; k0 < 512; k0 += 32) {
    __syncthreads();
    {
      const half8* ga = (const half8*)(Ain + (size_t)(m0 + srow) * 512 + k0 + shalf * 16);
      const float4* gb = (const float4*)(w + (size_t)(n0 + srow) * 512 + k0 + shalf * 16);
      half8 ha0 = ga[0], ha1 = ga[1];
      float4 b0 = gb[0], b1 = gb[1], b2 = gb[2], b3 = gb[3];
      half8 hb0 = {(_Float16)b0.x, (_Float16)b0.y, (_Float16)b0.z, (_Float16)b0.w,
                   (_Float16)b1.x, (_Float16)b1.y, (_Float16)b1.z, (_Float16)b1.w};
      half8 hb1 = {(_Float16)b2.x, (_Float16)b2.y, (_Float16)b2.z, (_Float16)b2.w,
                   (_Float16)b3.x, (_Float16)b3.y, (_Float16)b3.z, (_Float16)b3.w};
      int lo = srow * 40 + shalf * 16;
      *(half8*)&As[lo] = ha0;
      *(half8*)&As[lo + 8] = ha1;
      *(half8*)&Bs[lo] = hb0;
      *(half8*)&Bs[lo + 8] = hb1;
    }
    __syncthreads();
    half8 a[4], b[4];
#pragma unroll
    for (int mt = 0; mt < 4; ++mt)
      a[mt] = *(const half8*)&As[(wm + mt * 16 + l15) * 40 + quad * 8];
#pragma unroll
    for (int nt = 0; nt < 4; ++nt)
      b[nt] = *(const half8*)&Bs[(wn + nt * 16 + l15) * 40 + quad * 8];
#pragma unroll
    for (int mt = 0; mt < 4; ++mt)
#pragma unroll
      for (int nt = 0; nt < 4; ++nt)
        acc[mt][nt] =
            __builtin_amdgcn_mfma_f32_16x16x32_f16(a[mt], b[nt], acc[mt][nt], 0, 0, 0);
  }
#pragma unroll
  for (int mt = 0; mt < 4; ++mt) {
#pragma unroll
    for (int r = 0; r < 4; ++r) {
      int row = m0 + wm + mt * 16 + quad * 4 + r;
      int b_ = row >> 10, n_ = row & 1023;
      float t = tm[b_ * 1024 + n_];
#pragma unroll
      for (int nt = 0; nt < 4; ++nt) {
        int co = n0 + wn + nt * 16 + l15;
        out[(size_t)row * 512 + co] = (acc[mt][nt][r] + bias[co]) * t;
      }
    }
  }
}

// ---------------------------------------------------------------------------
extern "C" void kernel_launch(void* const* d_in, const int* in_sizes, int n_in,
                              void* d_out, int out_size, void* d_ws, size_t ws_size,
                              hipStream_t stream) {
  const float* x      = (const float*)d_in[0];
  const float* tm     = (const float*)d_in[1];
  const float* qkv_w  = (const float*)d_in[2];
  const float* qkv_b  = (const float*)d_in[3];
  const float* proj_w = (const float*)d_in[4];
  const float* proj_b = (const float*)d_in[5];
  const float* dwc_w  = (const float*)d_in[6];
  const float* dwc_b  = (const float*)d_in[7];
  float* out = (float*)d_out;

  char* wsb = (char*)d_ws;
  __half* Qh  = (__half*)(wsb + 0);
  __half* Kh  = (__half*)(wsb + 2097152);
  __half* Vh  = (__half*)(wsb + 4194304);
  __half* VLh = (__half*)(wsb + 6291456);
  __half* QLh = (__half*)(wsb + 8388608);
  __half* KLh = (__half*)(wsb + 8650752);
  float*  LM  = (float*)(wsb + 8912896);
  float*  MU  = (float*)(wsb + 8913920);
  float*  RS  = (float*)(wsb + 8918016);
  float*  KTV = (float*)(wsb + 8922112);
  __half* CTX = (__half*)(wsb + 9446400);
  float*  XA  = (float*)(wsb + 9708544);
  float*  XB  = (float*)(wsb + 10757120);
  float*  PS  = (float*)(wsb + 9708544);  // overlays XA+XB after ctx

  char* ob = (char*)d_out;
  float*  Wf   = (float*)ob;
  __half* Pbuf = (__half*)ob;

  qkv_gemm<<<dim3(16, 12), 256, 0, stream>>>(x, qkv_w, qkv_b, tm, Qh, Kh, Vh);
  pool_kernel<<<dim3(16, 16), 256, 0, stream>>>(Qh, Kh, tm, QLh, KLh, LM);
  wbuild_ns<<<16, 256, 0, stream>>>(QLh, KLh, LM, Wf, XA);
  float* Xc = XA;
  float* Xn = XB;
  for (int it = 0; it < 5; ++it) {
    ns_iter<<<dim3(8, 16), 256, 0, stream>>>(Wf, Xc, Xn);
    float* tswap = Xc; Xc = Xn; Xn = tswap;
  }
  hipMemsetAsync(KTV, 0, 131072 * sizeof(float), stream);
  ktv_fused<<<dim3(4, 16, 8), 256, 0, stream>>>(Kh, QLh, LM, Vh, KTV);
  ctx_kernel<<<dim3(32, 16), 256, 0, stream>>>(Xc, KTV, CTX);
  stats_partial<<<dim3(64, 16), 256, 0, stream>>>(Qh, KLh, LM, tm, PS, Pbuf);
  stats_final<<<4, 256, 0, stream>>>(PS, tm, MU, RS);
  vlocal_kernel<<<dim3(16, 16), 256, 0, stream>>>(Vh, dwc_w, dwc_b, tm, VLh);
  ga_fused<<<dim3(64, 16), 256, 0, stream>>>(Pbuf, MU, RS, CTX, tm, VLh);
  proj_gemm<<<dim3(16, 4), 256, 0, stream>>>(VLh, proj_w, proj_b, tm, out);
}

// Round 11
// 445.077 us; speedup vs baseline: 1.0359x; 1.0359x over previous
//
#include <hip/hip_runtime.h>
#include <hip/hip_bf16.h>
#include <hip/hip_fp16.h>

// B=2, N=1024, C=512, H=8, D=64, m=128, p=8
#define Hh 8
#define Bz 2
#define Nn 1024
#define Cc 512
#define Dd 64
#define Mm 128
#define NS_EPS 1e-4f
#define WHITE_EPS 1e-5f

__device__ __forceinline__ float h2f(__half v) { return __half2float(v); }
__device__ __forceinline__ __half f2h(float v) { return __float2half(v); }

typedef _Float16 half8 __attribute__((ext_vector_type(8)));
typedef float float4v __attribute__((ext_vector_type(4)));

// ---------------------------------------------------------------------------
// K1: QKV GEMM via MFMA f16. M=2048, N=1536, K=512. Block tile 128x128.
__global__ __launch_bounds__(256) void qkv_gemm(
    const float* __restrict__ x, const float* __restrict__ w,
    const float* __restrict__ bias, const float* __restrict__ tm,
    __half* __restrict__ Q, __half* __restrict__ K, __half* __restrict__ V) {
  __shared__ _Float16 As[128 * 40];
  __shared__ _Float16 Bs[128 * 40];
  int m0 = blockIdx.x * 128, n0 = blockIdx.y * 128;
  int tid = threadIdx.x;
  int lane = tid & 63, wv = tid >> 6;
  int wm = (wv >> 1) * 64, wn = (wv & 1) * 64;
  int l15 = lane & 15, quad = lane >> 4;
  int srow = tid >> 1, shalf = tid & 1;
  float4v acc[4][4] = {};
  for (int k0 = 0; k0 < 512; k0 += 32) {
    __syncthreads();
    {
      const float4* ga = (const float4*)(x + (size_t)(m0 + srow) * 512 + k0 + shalf * 16);
      const float4* gb = (const float4*)(w + (size_t)(n0 + srow) * 512 + k0 + shalf * 16);
      float4 a0 = ga[0], a1 = ga[1], a2 = ga[2], a3 = ga[3];
      float4 b0 = gb[0], b1 = gb[1], b2 = gb[2], b3 = gb[3];
      half8 ha0 = {(_Float16)a0.x, (_Float16)a0.y, (_Float16)a0.z, (_Float16)a0.w,
                   (_Float16)a1.x, (_Float16)a1.y, (_Float16)a1.z, (_Float16)a1.w};
      half8 ha1 = {(_Float16)a2.x, (_Float16)a2.y, (_Float16)a2.z, (_Float16)a2.w,
                   (_Float16)a3.x, (_Float16)a3.y, (_Float16)a3.z, (_Float16)a3.w};
      half8 hb0 = {(_Float16)b0.x, (_Float16)b0.y, (_Float16)b0.z, (_Float16)b0.w,
                   (_Float16)b1.x, (_Float16)b1.y, (_Float16)b1.z, (_Float16)b1.w};
      half8 hb1 = {(_Float16)b2.x, (_Float16)b2.y, (_Float16)b2.z, (_Float16)b2.w,
                   (_Float16)b3.x, (_Float16)b3.y, (_Float16)b3.z, (_Float16)b3.w};
      int lo = srow * 40 + shalf * 16;
      *(half8*)&As[lo] = ha0;
      *(half8*)&As[lo + 8] = ha1;
      *(half8*)&Bs[lo] = hb0;
      *(half8*)&Bs[lo + 8] = hb1;
    }
    __syncthreads();
    half8 a[4], b[4];
#pragma unroll
    for (int mt = 0; mt < 4; ++mt)
      a[mt] = *(const half8*)&As[(wm + mt * 16 + l15) * 40 + quad * 8];
#pragma unroll
    for (int nt = 0; nt < 4; ++nt)
      b[nt] = *(const half8*)&Bs[(wn + nt * 16 + l15) * 40 + quad * 8];
#pragma unroll
    for (int mt = 0; mt < 4; ++mt)
#pragma unroll
      for (int nt = 0; nt < 4; ++nt)
        acc[mt][nt] =
            __builtin_amdgcn_mfma_f32_16x16x32_f16(a[mt], b[nt], acc[mt][nt], 0, 0, 0);
  }
#pragma unroll
  for (int mt = 0; mt < 4; ++mt) {
#pragma unroll
    for (int r = 0; r < 4; ++r) {
      int row = m0 + wm + mt * 16 + quad * 4 + r;
      int b_ = row >> 10, n_ = row & 1023;
      float t = tm[b_ * 1024 + n_];
#pragma unroll
      for (int nt = 0; nt < 4; ++nt) {
        int c3 = n0 + wn + nt * 16 + l15;
        float v = (acc[mt][nt][r] + bias[c3]) * t;
        int sec = c3 >> 9, ch = c3 & 511;
        __half* dst = (sec == 0) ? Q : (sec == 1 ? K : V);
        dst[(size_t)b_ * (Nn * Cc) + (size_t)n_ * 512 + ch] = f2h(v);
      }
    }
  }
}

// ---------------------------------------------------------------------------
// K2: pool — block per (b,h,u-tile of 64). Coalesced row staging.
__global__ __launch_bounds__(256) void pool_kernel(
    const __half* __restrict__ Q, const __half* __restrict__ K,
    const float* __restrict__ tm, __half* __restrict__ QL,
    __half* __restrict__ KL, float* __restrict__ LM) {
  int ut = blockIdx.x;
  int bh = blockIdx.y;
  int b = bh >> 3, h = bh & 7;
  int u0 = ut * 64;
  int delta = u0 >> 9;
  int ch0 = u0 & 511;
  __shared__ float Qs[64][65];
  __shared__ float Ks[64][65];
  int tid = threadIdx.x;
  for (int e = tid; e < 4096; e += 256) {
    int d = e >> 6, uu = e & 63;
    int row = 2 * (h * 64 + d) + delta;
    size_t gi = (size_t)b * (Nn * Cc) + (size_t)row * 512 + ch0 + uu;
    Qs[d][uu] = h2f(Q[gi]);
    Ks[d][uu] = h2f(K[gi]);
  }
  __syncthreads();
  int d = tid & 63, s = tid >> 6;
#pragma unroll
  for (int jr = 0; jr < 2; ++jr) {
    int jl = s + 4 * jr;
    int j = ut * 8 + jl;
    float pm = 0.f, sq = 0.f, sk = 0.f;
#pragma unroll
    for (int i = 0; i < 8; ++i) {
      float t = tm[b * 1024 + 8 * j + i];
      pm += t;
      sq += Qs[d][8 * jl + i] * t;
      sk += Ks[d][8 * jl + i] * t;
    }
    pm *= 0.125f;
    float pms = fmaxf(pm, 1e-6f);
    size_t oi = ((size_t)bh * 128 + j) * 64 + d;
    QL[oi] = f2h(sq * 0.125f / pms);
    KL[oi] = f2h(sk * 0.125f / pms);
    if (h == 0 && d == 0) LM[b * 128 + j] = (pm > 0.f) ? 1.f : 0.f;
  }
}

// ---------------------------------------------------------------------------
// K3: W_eps[b,h,i,j] (f32, lives in d_out during NS)
__global__ __launch_bounds__(256) void wbuild_kernel(
    const __half* __restrict__ QL, const __half* __restrict__ KL,
    const float* __restrict__ LM, float* __restrict__ W) {
  int bh = blockIdx.y;
  int b = bh >> 3;
  int i0 = blockIdx.x * 64;
  __shared__ float ks[128][65];
  __shared__ float qs[64][65];
  int tid = threadIdx.x;
  const __half* klb = KL + (size_t)bh * (Mm * Dd);
  const __half* qlb = QL + (size_t)bh * (Mm * Dd);
  for (int e = tid; e < 128 * 64; e += 256) ks[e >> 6][e & 63] = h2f(klb[e]);
  for (int e = tid; e < 64 * 64; e += 256) qs[e >> 6][e & 63] = h2f(qlb[i0 * 64 + e]);
  __syncthreads();
  for (int e = tid; e < 64 * 128; e += 256) {
    int il = e >> 7, j = e & 127;
    int i = i0 + il;
    float s = 0.f;
#pragma unroll
    for (int d = 0; d < 64; ++d) s += fabsf(qs[il][d] - ks[j][d]);
    float wv = expf(-s * 0.25f);
    float pr = LM[b * Mm + i] * LM[b * Mm + j];
    float diag = (i == j) ? 1.f : 0.f;
    wv = wv * pr + diag * (1.f - pr) + diag * NS_EPS;
    W[(size_t)bh * (Mm * Mm) + i * 128 + j] = wv;
  }
}

// ---------------------------------------------------------------------------
// K4: X0 = 2/(fro+1e-8) * W^T  (f32)
__global__ __launch_bounds__(256) void nsinit_kernel(const float* __restrict__ W,
                                                     float* __restrict__ X) {
  int bh = blockIdx.x;
  const float* Wb = W + (size_t)bh * 16384;
  float* Xb = X + (size_t)bh * 16384;
  __shared__ float red[256];
  int tid = threadIdx.x;
  float s = 0.f;
  for (int e = tid; e < 16384; e += 256) { float wv = Wb[e]; s += wv * wv; }
  red[tid] = s;
  __syncthreads();
  for (int off = 128; off > 0; off >>= 1) {
    if (tid < off) red[tid] += red[tid + off];
    __syncthreads();
  }
  float scale = 2.f / (sqrtf(red[0]) + 1e-8f);
  for (int e = tid; e < 16384; e += 256) {
    int i = e >> 7, j = e & 127;
    Xb[e] = scale * Wb[j * 128 + i];
  }
}

// ---------------------------------------------------------------------------
// K5: ns_iter — Xn = Xc @ (2I - W @ Xc), 8 column-blocks of 16.
__global__ __launch_bounds__(256) void ns_iter(const float* __restrict__ W,
                                               const float* __restrict__ Xc,
                                               float* __restrict__ Xn) {
  int bh = blockIdx.y;
  int cb = blockIdx.x;  // 0..7
  const float* Wb = W + (size_t)bh * 16384;
  const float* Xb = Xc + (size_t)bh * 16384;
  float* Ob = Xn + (size_t)bh * 16384;
  __shared__ float Xs[128][17];
  __shared__ float Ts[128][17];
  __shared__ float St[128][33];
  int tid = threadIdx.x;
  int jc = tid & 15;
  int ibase = (tid >> 4) * 8;
  for (int e = tid; e < 2048; e += 256) {
    int k = e >> 4, j = e & 15;
    Xs[k][j] = Xb[(size_t)k * 128 + cb * 16 + j];
  }
  float acc[8];
#pragma unroll
  for (int r = 0; r < 8; ++r) acc[r] = 0.f;
  for (int kt = 0; kt < 4; ++kt) {
    __syncthreads();
    for (int e = tid; e < 4096; e += 256)
      St[e >> 5][e & 31] = Wb[(size_t)(e >> 5) * 128 + kt * 32 + (e & 31)];
    __syncthreads();
#pragma unroll 8
    for (int kk = 0; kk < 32; ++kk) {
      float xv = Xs[kt * 32 + kk][jc];
#pragma unroll
      for (int r = 0; r < 8; ++r) acc[r] += St[ibase + r][kk] * xv;
    }
  }
#pragma unroll
  for (int r = 0; r < 8; ++r) {
    int i = ibase + r;
    Ts[i][jc] = ((i == cb * 16 + jc) ? 2.f : 0.f) - acc[r];
  }
  float acc2[8];
#pragma unroll
  for (int r = 0; r < 8; ++r) acc2[r] = 0.f;
  for (int kt = 0; kt < 4; ++kt) {
    __syncthreads();
    for (int e = tid; e < 4096; e += 256)
      St[e >> 5][e & 31] = Xb[(size_t)(e >> 5) * 128 + kt * 32 + (e & 31)];
    __syncthreads();
#pragma unroll 8
    for (int kk = 0; kk < 32; ++kk) {
      float tv = Ts[kt * 32 + kk][jc];
#pragma unroll
      for (int r = 0; r < 8; ++r) acc2[r] += St[ibase + r][kk] * tv;
    }
  }
#pragma unroll
  for (int r = 0; r < 8; ++r)
    Ob[(size_t)(ibase + r) * 128 + cb * 16 + jc] = acc2[r];
}

// ---------------------------------------------------------------------------
// K7: ktv v5 — fused C_k + K^T V. 32 j per block, half8 staging,
// 2jx2n register-tiled L1 phase, (1j x 8d) PV phase.
__global__ __launch_bounds__(256) void ktv_fused(
    const __half* __restrict__ K, const __half* __restrict__ QL,
    const float* __restrict__ LM, const __half* __restrict__ V,
    float* __restrict__ KTV) {
  int jt = blockIdx.x;   // 4 (32 j each)
  int bh = blockIdx.y;   // 16
  int nc = blockIdx.z;   // 8 (128 n each)
  int b = bh >> 3, h = bh & 7;
  int j0 = jt * 32;
  __shared__ __align__(16) float qls[32 * 68];
  __shared__ __align__(16) float Ks[32 * 68];
  __shared__ __align__(16) float Vs[32 * 68];
  __shared__ float P[32 * 36];
  int tid = threadIdx.x;
  int sr = tid >> 3, sd8 = (tid & 7) * 8;
  {
    half8 q = *(const half8*)(QL + (size_t)bh * 8192 + (size_t)(j0 + sr) * 64 + sd8);
    float4 f0 = {(float)q[0], (float)q[1], (float)q[2], (float)q[3]};
    float4 f1 = {(float)q[4], (float)q[5], (float)q[6], (float)q[7]};
    *(float4*)&qls[sr * 68 + sd8] = f0;
    *(float4*)&qls[sr * 68 + sd8 + 4] = f1;
  }
  int jq = tid & 15, nq = tid >> 4;   // L1: j = jq*2(+1), n = nq*2(+1)
  int dq2 = tid & 7, jl = tid >> 3;   // PV: d8 = dq2*8, j = jl
  float acc[8] = {};
  for (int nt = 0; nt < 4; ++nt) {
    int n0 = nc * 128 + nt * 32;
    __syncthreads();
    {
      size_t gi = (size_t)b * (Nn * Cc) + (size_t)(n0 + sr) * 512 + h * 64 + sd8;
      half8 kv = *(const half8*)(K + gi);
      half8 vv = *(const half8*)(V + gi);
      float4 k0 = {(float)kv[0], (float)kv[1], (float)kv[2], (float)kv[3]};
      float4 k1 = {(float)kv[4], (float)kv[5], (float)kv[6], (float)kv[7]};
      float4 v0 = {(float)vv[0], (float)vv[1], (float)vv[2], (float)vv[3]};
      float4 v1 = {(float)vv[4], (float)vv[5], (float)vv[6], (float)vv[7]};
      *(float4*)&Ks[sr * 68 + sd8] = k0;
      *(float4*)&Ks[sr * 68 + sd8 + 4] = k1;
      *(float4*)&Vs[sr * 68 + sd8] = v0;
      *(float4*)&Vs[sr * 68 + sd8 + 4] = v1;
    }
    __syncthreads();
    {
      const float4* q0p = (const float4*)&qls[(jq * 2) * 68];
      const float4* q1p = (const float4*)&qls[(jq * 2 + 1) * 68];
      const float4* k0p = (const float4*)&Ks[(nq * 2) * 68];
      const float4* k1p = (const float4*)&Ks[(nq * 2 + 1) * 68];
      float s00 = 0.f, s01 = 0.f, s10 = 0.f, s11 = 0.f;
#pragma unroll
      for (int i = 0; i < 16; ++i) {
        int dq = (i + tid) & 15;
        float4 q0 = q0p[dq], q1 = q1p[dq];
        float4 k0 = k0p[dq], k1 = k1p[dq];
        s00 += fabsf(q0.x - k0.x) + fabsf(q0.y - k0.y) + fabsf(q0.z - k0.z) + fabsf(q0.w - k0.w);
        s01 += fabsf(q0.x - k1.x) + fabsf(q0.y - k1.y) + fabsf(q0.z - k1.z) + fabsf(q0.w - k1.w);
        s10 += fabsf(q1.x - k0.x) + fabsf(q1.y - k0.y) + fabsf(q1.z - k0.z) + fabsf(q1.w - k0.w);
        s11 += fabsf(q1.x - k1.x) + fabsf(q1.y - k1.y) + fabsf(q1.z - k1.z) + fabsf(q1.w - k1.w);
      }
      P[(nq * 2) * 36 + jq * 2] = expf(-s00 * 0.25f);
      P[(nq * 2) * 36 + jq * 2 + 1] = expf(-s10 * 0.25f);
      P[(nq * 2 + 1) * 36 + jq * 2] = expf(-s01 * 0.25f);
      P[(nq * 2 + 1) * 36 + jq * 2 + 1] = expf(-s11 * 0.25f);
    }
    __syncthreads();
    {
#pragma unroll 4
      for (int n = 0; n < 32; ++n) {
        float p = P[n * 36 + jl];
        float4 v0 = *(const float4*)&Vs[n * 68 + dq2 * 8];
        float4 v1 = *(const float4*)&Vs[n * 68 + dq2 * 8 + 4];
        acc[0] += p * v0.x; acc[1] += p * v0.y; acc[2] += p * v0.z; acc[3] += p * v0.w;
        acc[4] += p * v1.x; acc[5] += p * v1.y; acc[6] += p * v1.z; acc[7] += p * v1.w;
      }
    }
  }
  {
    float lm = LM[b * 128 + j0 + jl];
    float* dst = &KTV[(size_t)bh * 8192 + (size_t)(j0 + jl) * 64 + dq2 * 8];
#pragma unroll
    for (int u = 0; u < 8; ++u) atomicAdd(dst + u, acc[u] * lm);
  }
}

// ---------------------------------------------------------------------------
// K8: CTX[bh,i,d] = sum_j X[bh,i,j] * KTV[bh,j,d]  (f32 in, f16 out)
__global__ __launch_bounds__(256) void ctx_kernel(const float* __restrict__ X,
                                                  const float* __restrict__ KTV,
                                                  __half* __restrict__ CTX) {
  int bh = blockIdx.y;
  int i = blockIdx.x * 4 + (threadIdx.x >> 6);
  int d = threadIdx.x & 63;
  const float* wb = X + (size_t)bh * 16384 + (size_t)i * 128;
  const float* kb = KTV + (size_t)bh * 8192 + d;
  float acc = 0.f;
#pragma unroll 4
  for (int jj = 0; jj < 128; ++jj) acc += wb[jj] * kb[(size_t)jj * 64];
  CTX[(size_t)bh * 8192 + (size_t)i * 64 + d] = f2h(acc);
}

// ---------------------------------------------------------------------------
// K9: stats_partial v3 — float4 LDS reads, 2j x 4n register tile.
__global__ __launch_bounds__(256) void stats_partial(
    const __half* __restrict__ Q, const __half* __restrict__ KL,
    const float* __restrict__ LM, const float* __restrict__ tm,
    float* __restrict__ PS, __half* __restrict__ Pbuf) {
  int nt = blockIdx.x;   // 64
  int bh = blockIdx.y;   // 16
  int b = bh >> 3, h = bh & 7;
  int n0 = nt * 16;
  __shared__ __align__(16) float kls[128 * 68];
  __shared__ __align__(16) float qs[16 * 68];
  __shared__ __half ps[16 * 132];
  __shared__ float part[128 * 12];
  int tid = threadIdx.x;
  for (int e = tid; e < 8192; e += 256)
    kls[(e >> 6) * 68 + (e & 63)] = h2f(KL[(size_t)bh * 8192 + e]);
  for (int e = tid; e < 1024; e += 256)
    qs[(e >> 6) * 68 + (e & 63)] =
        h2f(Q[(size_t)b * (Nn * Cc) + (size_t)(n0 + (e >> 6)) * 512 + h * 64 + (e & 63)]);
  __syncthreads();
  int jg = tid & 63, ng = tid >> 6;
  int j = jg * 2;
  const float4* kA = (const float4*)&kls[j * 68];
  const float4* kB = (const float4*)&kls[(j + 1) * 68];
  float sA[4] = {}, sB[4] = {};
#pragma unroll
  for (int i = 0; i < 16; ++i) {
    int dq = (i + jg) & 15;
    float4 ka = kA[dq];
    float4 kb = kB[dq];
#pragma unroll
    for (int r = 0; r < 4; ++r) {
      float4 qv = *(const float4*)&qs[(ng * 4 + r) * 68 + dq * 4];
      sA[r] += fabsf(qv.x - ka.x) + fabsf(qv.y - ka.y) + fabsf(qv.z - ka.z) + fabsf(qv.w - ka.w);
      sB[r] += fabsf(qv.x - kb.x) + fabsf(qv.y - kb.y) + fabsf(qv.z - kb.z) + fabsf(qv.w - kb.w);
    }
  }
  float lmA = LM[b * 128 + j], lmB = LM[b * 128 + j + 1];
  float a1 = 0.f, a2 = 0.f, a3 = 0.f, b1 = 0.f, b2 = 0.f, b3 = 0.f;
#pragma unroll
  for (int r = 0; r < 4; ++r) {
    int nn = ng * 4 + r;
    float t = tm[b * 1024 + n0 + nn];
    float xa = expf(-sA[r] * 0.25f) * lmA;
    float xb = expf(-sB[r] * 0.25f) * lmB;
    ps[nn * 132 + j] = f2h(xa);
    ps[nn * 132 + j + 1] = f2h(xb);
    float xta = xa * t, xtb = xb * t;
    a1 += xta; a2 += xta * xta; a3 += xta * t;
    b1 += xtb; b2 += xtb * xtb; b3 += xtb * t;
  }
  part[j * 12 + ng * 3 + 0] = a1;
  part[j * 12 + ng * 3 + 1] = a2;
  part[j * 12 + ng * 3 + 2] = a3;
  part[(j + 1) * 12 + ng * 3 + 0] = b1;
  part[(j + 1) * 12 + ng * 3 + 1] = b2;
  part[(j + 1) * 12 + ng * 3 + 2] = b3;
  __syncthreads();
  for (int e = tid; e < 2048; e += 256)
    Pbuf[((size_t)bh * 1024 + n0 + (e >> 7)) * 128 + (e & 127)] =
        ps[(e >> 7) * 132 + (e & 127)];
  if (tid < 128) {
    float s1 = part[tid * 12 + 0] + part[tid * 12 + 3] + part[tid * 12 + 6] + part[tid * 12 + 9];
    float s2 = part[tid * 12 + 1] + part[tid * 12 + 4] + part[tid * 12 + 7] + part[tid * 12 + 10];
    float s3 = part[tid * 12 + 2] + part[tid * 12 + 5] + part[tid * 12 + 8] + part[tid * 12 + 11];
    size_t base = ((size_t)(b * 64 + nt) * 8 + h) * 384 + tid * 3;
    PS[base] = s1; PS[base + 1] = s2; PS[base + 2] = s3;
  }
}

// ---------------------------------------------------------------------------
// K10: stats_final — reduce PS over 128 (b,nt) tiles per (h,j).
__global__ __launch_bounds__(256) void stats_final(const float* __restrict__ PS,
                                                   const float* __restrict__ tm,
                                                   float* __restrict__ MU,
                                                   float* __restrict__ RS) {
  __shared__ float red[256][2];
  __shared__ float ts0, ts1;
  int tid = threadIdx.x;
  float a = 0.f, c = 0.f;
  for (int i = tid; i < 2048; i += 256) { float t = tm[i]; a += t; c += t * t; }
  red[tid][0] = a; red[tid][1] = c;
  __syncthreads();
  for (int off = 128; off > 0; off >>= 1) {
    if (tid < off) { red[tid][0] += red[tid + off][0]; red[tid][1] += red[tid + off][1]; }
    __syncthreads();
  }
  if (tid == 0) { ts0 = red[0][0]; ts1 = red[0][1]; }
  __syncthreads();
  int hj = blockIdx.x * 256 + tid;
  int h = hj >> 7, j = hj & 127;
  float s1 = 0.f, s2 = 0.f, s3 = 0.f;
  for (int bnt = 0; bnt < 128; ++bnt) {
    const float* p = PS + ((size_t)bnt * 8 + h) * 384 + j * 3;
    s1 += p[0]; s2 += p[1]; s3 += p[2];
  }
  float valid = fmaxf(ts0, 1.f);
  float mu = s1 / valid;
  float var = (s2 - 2.f * mu * s3 + mu * mu * ts1) / valid;
  var = fmaxf(var, 0.f);
  MU[hj] = mu;
  RS[hj] = rsqrtf(var + WHITE_EPS);
}

// ---------------------------------------------------------------------------
// K11: vlocal — LDS-tiled scrambled depthwise conv.
__global__ __launch_bounds__(256) void vlocal_kernel(
    const __half* __restrict__ V, const float* __restrict__ dwc_w,
    const float* __restrict__ dwc_b, const float* __restrict__ tm,
    __half* __restrict__ VL) {
  int t0 = blockIdx.x * 64;
  int ct = blockIdx.y & 7, b = blockIdx.y >> 3;
  int c0 = ct * 64;
  __shared__ float vs[64][67];
  int tid = threadIdx.x;
  for (int e = tid; e < 64 * 66; e += 256) {
    int cl = e / 66, uu = e % 66;
    int u = t0 - 1 + uu;
    float val = 0.f;
    if (u >= 0 && u < 1024) {
      int c = c0 + cl;
      int n = 2 * c + (u >> 9), ch = u & 511;
      val = h2f(V[(size_t)b * (Nn * Cc) + (size_t)n * 512 + ch]);
    }
    vs[cl][uu] = val;
  }
  __syncthreads();
  int cl = tid & 63;
  int c = c0 + cl;
  float w0 = dwc_w[c * 3], w1 = dwc_w[c * 3 + 1], w2 = dwc_w[c * 3 + 2];
  float bb = dwc_b[c];
  int tg = tid >> 6;
#pragma unroll
  for (int i = 0; i < 16; ++i) {
    int tl = tg * 16 + i;
    int t = t0 + tl;
    float acc = bb + w0 * vs[cl][tl] + w1 * vs[cl][tl + 1] + w2 * vs[cl][tl + 2];
    VL[(size_t)b * (Nn * Cc) + (size_t)t * 512 + c] = f2h(acc * tm[b * 1024 + t]);
  }
}

// ---------------------------------------------------------------------------
// K12: ga — load precomputed P, whiten, @context, accumulate into VL.
__global__ __launch_bounds__(256) void ga_fused(
    const __half* __restrict__ Pbuf, const float* __restrict__ MU,
    const float* __restrict__ RS, const __half* __restrict__ CTXg,
    const float* __restrict__ tm, __half* __restrict__ VL) {
  int bh = blockIdx.y;
  int b = bh >> 3, h = bh & 7;
  int n0 = blockIdx.x * 16;
  __shared__ __half Ps[16][130];
  __shared__ __align__(16) __half2 ctx2[128][32];
  __shared__ float musr[128][2];
  int tid = threadIdx.x;
  for (int e = tid; e < 2048; e += 256)
    Ps[e >> 7][e & 127] = Pbuf[((size_t)bh * 1024 + n0 + (e >> 7)) * 128 + (e & 127)];
  {
    const __half2* cg = (const __half2*)(CTXg + (size_t)bh * 8192);
    for (int e = tid; e < 4096; e += 256) ctx2[e >> 5][e & 31] = cg[e];
  }
  if (tid < 128) { musr[tid][0] = MU[h * 128 + tid]; musr[tid][1] = RS[h * 128 + tid]; }
  __syncthreads();
  int nn = tid >> 4, dq = tid & 15;
  float a0 = 0.f, a1 = 0.f, a2 = 0.f, a3 = 0.f;
#pragma unroll 4
  for (int j = 0; j < 128; ++j) {
    float pj = (h2f(Ps[nn][j]) - musr[j][0]) * musr[j][1];
    uint2 cc = *(const uint2*)&ctx2[j][dq * 2];
    __half2 c01 = __builtin_bit_cast(__half2, cc.x);
    __half2 c23 = __builtin_bit_cast(__half2, cc.y);
    a0 += pj * h2f(c01.x); a1 += pj * h2f(c01.y);
    a2 += pj * h2f(c23.x); a3 += pj * h2f(c23.y);
  }
  float t = tm[b * 1024 + n0 + nn];
  float t2 = t * t;
  size_t base = (size_t)b * (Nn * Cc) + (size_t)(n0 + nn) * 512 + h * 64 + dq * 4;
  VL[base] = f2h(h2f(VL[base]) + t2 * a0);
  VL[base + 1] = f2h(h2f(VL[base + 1]) + t2 * a1);
  VL[base + 2] = f2h(h2f(VL[base + 2]) + t2 * a2);
  VL[base + 3] = f2h(h2f(VL[base + 3]) + t2 * a3);
}

// ---------------------------------------------------------------------------
// K13: proj via MFMA f16. M=2048, N=512, K=512.
__global__ __launch_bounds__(256) void proj_gemm(
    const __half* __restrict__ Ain, const float* __restrict__ w,
    const float* __restrict__ bias, const float* __restrict__ tm,
    float* __restrict__ out) {
  __shared__ _Float16 As[128 * 40];
  __shared__ _Float16 Bs[128 * 40];
  int m0 = blockIdx.x * 128, n0 = blockIdx.y * 128;
  int tid = threadIdx.x;
  int lane = tid & 63, wv = tid >> 6;
  int wm = (wv >> 1) * 64, wn = (wv & 1) * 64;
  int l15 = lane & 15, quad = lane >> 4;
  int srow = tid >> 1, shalf = tid & 1;
  float4v acc[4][4] = {};
  for (int k0 = 0; k0 < 512; k0 += 32) {
    __syncthreads();
    {
      const half8* ga = (const half8*)(Ain + (size_t)(m0 + srow) * 512 + k0 + shalf * 16);
      const float4* gb = (const float4*)(w + (size_t)(n0 + srow) * 512 + k0 + shalf * 16);
      half8 ha0 = ga[0], ha1 = ga[1];
      float4 b0 = gb[0], b1 = gb[1], b2 = gb[2], b3 = gb[3];
      half8 hb0 = {(_Float16)b0.x, (_Float16)b0.y, (_Float16)b0.z, (_Float16)b0.w,
                   (_Float16)b1.x, (_Float16)b1.y, (_Float16)b1.z, (_Float16)b1.w};
      half8 hb1 = {(_Float16)b2.x, (_Float16)b2.y, (_Float16)b2.z, (_Float16)b2.w,
                   (_Float16)b3.x, (_Float16)b3.y, (_Float16)b3.z, (_Float16)b3.w};
      int lo = srow * 40 + shalf * 16;
      *(half8*)&As[lo] = ha0;
      *(half8*)&As[lo + 8] = ha1;
      *(half8*)&Bs[lo] = hb0;
      *(half8*)&Bs[lo + 8] = hb1;
    }
    __syncthreads();
    half8 a[4], b[4];
#pragma unroll
    for (int mt = 0; mt < 4; ++mt)
      a[mt] = *(const half8*)&As[(wm + mt * 16 + l15) * 40 + quad * 8];
#pragma unroll
    for (int nt = 0; nt < 4; ++nt)
      b[nt] = *(const half8*)&Bs[(wn + nt * 16 + l15) * 40 + quad * 8];
#pragma unroll
    for (int mt = 0; mt < 4; ++mt)
#pragma unroll
      for (int nt = 0; nt < 4; ++nt)
        acc[mt][nt] =
            __builtin_amdgcn_mfma_f32_16x16x32_f16(a[mt], b[nt], acc[mt][nt], 0, 0, 0);
  }
#pragma unroll
  for (int mt = 0; mt < 4; ++mt) {
#pragma unroll
    for (int r = 0; r < 4; ++r) {
      int row = m0 + wm + mt * 16 + quad * 4 + r;
      int b_ = row >> 10, n_ = row & 1023;
      float t = tm[b_ * 1024 + n_];
#pragma unroll
      for (int nt = 0; nt < 4; ++nt) {
        int co = n0 + wn + nt * 16 + l15;
        out[(size_t)row * 512 + co] = (acc[mt][nt][r] + bias[co]) * t;
      }
    }
  }
}

// ---------------------------------------------------------------------------
extern "C" void kernel_launch(void* const* d_in, const int* in_sizes, int n_in,
                              void* d_out, int out_size, void* d_ws, size_t ws_size,
                              hipStream_t stream) {
  const float* x      = (const float*)d_in[0];
  const float* tm     = (const float*)d_in[1];
  const float* qkv_w  = (const float*)d_in[2];
  const float* qkv_b  = (const float*)d_in[3];
  const float* proj_w = (const float*)d_in[4];
  const float* proj_b = (const float*)d_in[5];
  const float* dwc_w  = (const float*)d_in[6];
  const float* dwc_b  = (const float*)d_in[7];
  float* out = (float*)d_out;

  char* wsb = (char*)d_ws;
  __half* Qh  = (__half*)(wsb + 0);
  __half* Kh  = (__half*)(wsb + 2097152);
  __half* Vh  = (__half*)(wsb + 4194304);
  __half* VLh = (__half*)(wsb + 6291456);
  __half* QLh = (__half*)(wsb + 8388608);
  __half* KLh = (__half*)(wsb + 8650752);
  float*  LM  = (float*)(wsb + 8912896);
  float*  MU  = (float*)(wsb + 8913920);
  float*  RS  = (float*)(wsb + 8918016);
  float*  KTV = (float*)(wsb + 8922112);
  __half* CTX = (__half*)(wsb + 9446400);
  float*  XA  = (float*)(wsb + 9708544);
  float*  XB  = (float*)(wsb + 10757120);
  float*  PS  = (float*)(wsb + 9708544);  // overlays XA+XB after ctx

  char* ob = (char*)d_out;
  float*  Wf   = (float*)ob;
  __half* Pbuf = (__half*)ob;

  qkv_gemm<<<dim3(16, 12), 256, 0, stream>>>(x, qkv_w, qkv_b, tm, Qh, Kh, Vh);
  pool_kernel<<<dim3(16, 16), 256, 0, stream>>>(Qh, Kh, tm, QLh, KLh, LM);
  wbuild_kernel<<<dim3(2, 16), 256, 0, stream>>>(QLh, KLh, LM, Wf);
  nsinit_kernel<<<16, 256, 0, stream>>>(Wf, XA);
  float* Xc = XA;
  float* Xn = XB;
  for (int it = 0; it < 5; ++it) {
    ns_iter<<<dim3(8, 16), 256, 0, stream>>>(Wf, Xc, Xn);
    float* tswap = Xc; Xc = Xn; Xn = tswap;
  }
  hipMemsetAsync(KTV, 0, 131072 * sizeof(float), stream);
  ktv_fused<<<dim3(4, 16, 8), 256, 0, stream>>>(Kh, QLh, LM, Vh, KTV);
  ctx_kernel<<<dim3(32, 16), 256, 0, stream>>>(Xc, KTV, CTX);
  stats_partial<<<dim3(64, 16), 256, 0, stream>>>(Qh, KLh, LM, tm, PS, Pbuf);
  stats_final<<<4, 256, 0, stream>>>(PS, tm, MU, RS);
  vlocal_kernel<<<dim3(16, 16), 256, 0, stream>>>(Vh, dwc_w, dwc_b, tm, VLh);
  ga_fused<<<dim3(64, 16), 256, 0, stream>>>(Pbuf, MU, RS, CTX, tm, VLh);
  proj_gemm<<<dim3(16, 4), 256, 0, stream>>>(VLh, proj_w, proj_b, tm, out);
}

// Round 12
// 419.178 us; speedup vs baseline: 1.0999x; 1.0618x over previous
//
#include <hip/hip_runtime.h>
#include <hip/hip_bf16.h>
#include <hip/hip_fp16.h>

// B=2, N=1024, C=512, H=8, D=64, m=128, p=8
#define Hh 8
#define Bz 2
#define Nn 1024
#define Cc 512
#define Dd 64
#define Mm 128
#define NS_EPS 1e-4f
#define WHITE_EPS 1e-5f

__device__ __forceinline__ float h2f(__half v) { return __half2float(v); }
__device__ __forceinline__ __half f2h(float v) { return __float2half(v); }

typedef _Float16 half8 __attribute__((ext_vector_type(8)));
typedef float float4v __attribute__((ext_vector_type(4)));

// ---------------------------------------------------------------------------
// K1: QKV GEMM via MFMA f16. M=2048, N=1536, K=512. Block tile 128x128.
__global__ __launch_bounds__(256) void qkv_gemm(
    const float* __restrict__ x, const float* __restrict__ w,
    const float* __restrict__ bias, const float* __restrict__ tm,
    __half* __restrict__ Q, __half* __restrict__ K, __half* __restrict__ V) {
  __shared__ _Float16 As[128 * 40];
  __shared__ _Float16 Bs[128 * 40];
  int m0 = blockIdx.x * 128, n0 = blockIdx.y * 128;
  int tid = threadIdx.x;
  int lane = tid & 63, wv = tid >> 6;
  int wm = (wv >> 1) * 64, wn = (wv & 1) * 64;
  int l15 = lane & 15, quad = lane >> 4;
  int srow = tid >> 1, shalf = tid & 1;
  float4v acc[4][4] = {};
  for (int k0 = 0; k0 < 512; k0 += 32) {
    __syncthreads();
    {
      const float4* ga = (const float4*)(x + (size_t)(m0 + srow) * 512 + k0 + shalf * 16);
      const float4* gb = (const float4*)(w + (size_t)(n0 + srow) * 512 + k0 + shalf * 16);
      float4 a0 = ga[0], a1 = ga[1], a2 = ga[2], a3 = ga[3];
      float4 b0 = gb[0], b1 = gb[1], b2 = gb[2], b3 = gb[3];
      half8 ha0 = {(_Float16)a0.x, (_Float16)a0.y, (_Float16)a0.z, (_Float16)a0.w,
                   (_Float16)a1.x, (_Float16)a1.y, (_Float16)a1.z, (_Float16)a1.w};
      half8 ha1 = {(_Float16)a2.x, (_Float16)a2.y, (_Float16)a2.z, (_Float16)a2.w,
                   (_Float16)a3.x, (_Float16)a3.y, (_Float16)a3.z, (_Float16)a3.w};
      half8 hb0 = {(_Float16)b0.x, (_Float16)b0.y, (_Float16)b0.z, (_Float16)b0.w,
                   (_Float16)b1.x, (_Float16)b1.y, (_Float16)b1.z, (_Float16)b1.w};
      half8 hb1 = {(_Float16)b2.x, (_Float16)b2.y, (_Float16)b2.z, (_Float16)b2.w,
                   (_Float16)b3.x, (_Float16)b3.y, (_Float16)b3.z, (_Float16)b3.w};
      int lo = srow * 40 + shalf * 16;
      *(half8*)&As[lo] = ha0;
      *(half8*)&As[lo + 8] = ha1;
      *(half8*)&Bs[lo] = hb0;
      *(half8*)&Bs[lo + 8] = hb1;
    }
    __syncthreads();
    half8 a[4], b[4];
#pragma unroll
    for (int mt = 0; mt < 4; ++mt)
      a[mt] = *(const half8*)&As[(wm + mt * 16 + l15) * 40 + quad * 8];
#pragma unroll
    for (int nt = 0; nt < 4; ++nt)
      b[nt] = *(const half8*)&Bs[(wn + nt * 16 + l15) * 40 + quad * 8];
#pragma unroll
    for (int mt = 0; mt < 4; ++mt)
#pragma unroll
      for (int nt = 0; nt < 4; ++nt)
        acc[mt][nt] =
            __builtin_amdgcn_mfma_f32_16x16x32_f16(a[mt], b[nt], acc[mt][nt], 0, 0, 0);
  }
#pragma unroll
  for (int mt = 0; mt < 4; ++mt) {
#pragma unroll
    for (int r = 0; r < 4; ++r) {
      int row = m0 + wm + mt * 16 + quad * 4 + r;
      int b_ = row >> 10, n_ = row & 1023;
      float t = tm[b_ * 1024 + n_];
#pragma unroll
      for (int nt = 0; nt < 4; ++nt) {
        int c3 = n0 + wn + nt * 16 + l15;
        float v = (acc[mt][nt][r] + bias[c3]) * t;
        int sec = c3 >> 9, ch = c3 & 511;
        __half* dst = (sec == 0) ? Q : (sec == 1 ? K : V);
        dst[(size_t)b_ * (Nn * Cc) + (size_t)n_ * 512 + ch] = f2h(v);
      }
    }
  }
}

// ---------------------------------------------------------------------------
// K2: pool — block per (b,h,u-tile of 64). Coalesced row staging.
__global__ __launch_bounds__(256) void pool_kernel(
    const __half* __restrict__ Q, const __half* __restrict__ K,
    const float* __restrict__ tm, __half* __restrict__ QL,
    __half* __restrict__ KL, float* __restrict__ LM) {
  int ut = blockIdx.x;
  int bh = blockIdx.y;
  int b = bh >> 3, h = bh & 7;
  int u0 = ut * 64;
  int delta = u0 >> 9;
  int ch0 = u0 & 511;
  __shared__ float Qs[64][65];
  __shared__ float Ks[64][65];
  int tid = threadIdx.x;
  for (int e = tid; e < 4096; e += 256) {
    int d = e >> 6, uu = e & 63;
    int row = 2 * (h * 64 + d) + delta;
    size_t gi = (size_t)b * (Nn * Cc) + (size_t)row * 512 + ch0 + uu;
    Qs[d][uu] = h2f(Q[gi]);
    Ks[d][uu] = h2f(K[gi]);
  }
  __syncthreads();
  int d = tid & 63, s = tid >> 6;
#pragma unroll
  for (int jr = 0; jr < 2; ++jr) {
    int jl = s + 4 * jr;
    int j = ut * 8 + jl;
    float pm = 0.f, sq = 0.f, sk = 0.f;
#pragma unroll
    for (int i = 0; i < 8; ++i) {
      float t = tm[b * 1024 + 8 * j + i];
      pm += t;
      sq += Qs[d][8 * jl + i] * t;
      sk += Ks[d][8 * jl + i] * t;
    }
    pm *= 0.125f;
    float pms = fmaxf(pm, 1e-6f);
    size_t oi = ((size_t)bh * 128 + j) * 64 + d;
    QL[oi] = f2h(sq * 0.125f / pms);
    KL[oi] = f2h(sk * 0.125f / pms);
    if (h == 0 && d == 0) LM[b * 128 + j] = (pm > 0.f) ? 1.f : 0.f;
  }
}

// ---------------------------------------------------------------------------
// K3: W_eps[b,h,i,j] (f32, lives in d_out during NS)
__global__ __launch_bounds__(256) void wbuild_kernel(
    const __half* __restrict__ QL, const __half* __restrict__ KL,
    const float* __restrict__ LM, float* __restrict__ W) {
  int bh = blockIdx.y;
  int b = bh >> 3;
  int i0 = blockIdx.x * 64;
  __shared__ float ks[128][65];
  __shared__ float qs[64][65];
  int tid = threadIdx.x;
  const __half* klb = KL + (size_t)bh * (Mm * Dd);
  const __half* qlb = QL + (size_t)bh * (Mm * Dd);
  for (int e = tid; e < 128 * 64; e += 256) ks[e >> 6][e & 63] = h2f(klb[e]);
  for (int e = tid; e < 64 * 64; e += 256) qs[e >> 6][e & 63] = h2f(qlb[i0 * 64 + e]);
  __syncthreads();
  for (int e = tid; e < 64 * 128; e += 256) {
    int il = e >> 7, j = e & 127;
    int i = i0 + il;
    float s = 0.f;
#pragma unroll
    for (int d = 0; d < 64; ++d) s += fabsf(qs[il][d] - ks[j][d]);
    float wv = expf(-s * 0.25f);
    float pr = LM[b * Mm + i] * LM[b * Mm + j];
    float diag = (i == j) ? 1.f : 0.f;
    wv = wv * pr + diag * (1.f - pr) + diag * NS_EPS;
    W[(size_t)bh * (Mm * Mm) + i * 128 + j] = wv;
  }
}

// ---------------------------------------------------------------------------
// K4: X0 = 2/(fro+1e-8) * W^T  (f32)
__global__ __launch_bounds__(256) void nsinit_kernel(const float* __restrict__ W,
                                                     float* __restrict__ X) {
  int bh = blockIdx.x;
  const float* Wb = W + (size_t)bh * 16384;
  float* Xb = X + (size_t)bh * 16384;
  __shared__ float red[256];
  int tid = threadIdx.x;
  float s = 0.f;
  for (int e = tid; e < 16384; e += 256) { float wv = Wb[e]; s += wv * wv; }
  red[tid] = s;
  __syncthreads();
  for (int off = 128; off > 0; off >>= 1) {
    if (tid < off) red[tid] += red[tid + off];
    __syncthreads();
  }
  float scale = 2.f / (sqrtf(red[0]) + 1e-8f);
  for (int e = tid; e < 16384; e += 256) {
    int i = e >> 7, j = e & 127;
    Xb[e] = scale * Wb[j * 128 + i];
  }
}

// ---------------------------------------------------------------------------
// K5: ns_iter — Xn = Xc @ (2I - W @ Xc), 8 column-blocks of 16.
__global__ __launch_bounds__(256) void ns_iter(const float* __restrict__ W,
                                               const float* __restrict__ Xc,
                                               float* __restrict__ Xn) {
  int bh = blockIdx.y;
  int cb = blockIdx.x;  // 0..7
  const float* Wb = W + (size_t)bh * 16384;
  const float* Xb = Xc + (size_t)bh * 16384;
  float* Ob = Xn + (size_t)bh * 16384;
  __shared__ float Xs[128][17];
  __shared__ float Ts[128][17];
  __shared__ float St[128][33];
  int tid = threadIdx.x;
  int jc = tid & 15;
  int ibase = (tid >> 4) * 8;
  for (int e = tid; e < 2048; e += 256) {
    int k = e >> 4, j = e & 15;
    Xs[k][j] = Xb[(size_t)k * 128 + cb * 16 + j];
  }
  float acc[8];
#pragma unroll
  for (int r = 0; r < 8; ++r) acc[r] = 0.f;
  for (int kt = 0; kt < 4; ++kt) {
    __syncthreads();
    for (int e = tid; e < 4096; e += 256)
      St[e >> 5][e & 31] = Wb[(size_t)(e >> 5) * 128 + kt * 32 + (e & 31)];
    __syncthreads();
#pragma unroll 8
    for (int kk = 0; kk < 32; ++kk) {
      float xv = Xs[kt * 32 + kk][jc];
#pragma unroll
      for (int r = 0; r < 8; ++r) acc[r] += St[ibase + r][kk] * xv;
    }
  }
#pragma unroll
  for (int r = 0; r < 8; ++r) {
    int i = ibase + r;
    Ts[i][jc] = ((i == cb * 16 + jc) ? 2.f : 0.f) - acc[r];
  }
  float acc2[8];
#pragma unroll
  for (int r = 0; r < 8; ++r) acc2[r] = 0.f;
  for (int kt = 0; kt < 4; ++kt) {
    __syncthreads();
    for (int e = tid; e < 4096; e += 256)
      St[e >> 5][e & 31] = Xb[(size_t)(e >> 5) * 128 + kt * 32 + (e & 31)];
    __syncthreads();
#pragma unroll 8
    for (int kk = 0; kk < 32; ++kk) {
      float tv = Ts[kt * 32 + kk][jc];
#pragma unroll
      for (int r = 0; r < 8; ++r) acc2[r] += St[ibase + r][kk] * tv;
    }
  }
#pragma unroll
  for (int r = 0; r < 8; ++r)
    Ob[(size_t)(ibase + r) * 128 + cb * 16 + jc] = acc2[r];
}

// ---------------------------------------------------------------------------
// K7: ktv v6 — fused C_k + K^T V. Non-atomic: each (jt,bh,nc) block writes
// its partial to KTVp[nc][bh][j][d] (in d_out, dead region during this phase).
__global__ __launch_bounds__(256) void ktv_fused(
    const __half* __restrict__ K, const __half* __restrict__ QL,
    const float* __restrict__ LM, const __half* __restrict__ V,
    float* __restrict__ KTVp) {
  int jt = blockIdx.x;   // 4 (32 j each)
  int bh = blockIdx.y;   // 16
  int nc = blockIdx.z;   // 8 (128 n each)
  int b = bh >> 3, h = bh & 7;
  int j0 = jt * 32;
  __shared__ __align__(16) float qls[32 * 68];
  __shared__ __align__(16) float Ks[32 * 68];
  __shared__ __align__(16) float Vs[32 * 68];
  __shared__ float P[32 * 36];
  int tid = threadIdx.x;
  int sr = tid >> 3, sd8 = (tid & 7) * 8;
  {
    half8 q = *(const half8*)(QL + (size_t)bh * 8192 + (size_t)(j0 + sr) * 64 + sd8);
    float4 f0 = {(float)q[0], (float)q[1], (float)q[2], (float)q[3]};
    float4 f1 = {(float)q[4], (float)q[5], (float)q[6], (float)q[7]};
    *(float4*)&qls[sr * 68 + sd8] = f0;
    *(float4*)&qls[sr * 68 + sd8 + 4] = f1;
  }
  int jq = tid & 15, nq = tid >> 4;   // L1: j = jq*2(+1), n = nq*2(+1)
  int dq2 = tid & 7, jl = tid >> 3;   // PV: d8 = dq2*8, j = jl
  float acc[8] = {};
  for (int nt = 0; nt < 4; ++nt) {
    int n0 = nc * 128 + nt * 32;
    __syncthreads();
    {
      size_t gi = (size_t)b * (Nn * Cc) + (size_t)(n0 + sr) * 512 + h * 64 + sd8;
      half8 kv = *(const half8*)(K + gi);
      half8 vv = *(const half8*)(V + gi);
      float4 k0 = {(float)kv[0], (float)kv[1], (float)kv[2], (float)kv[3]};
      float4 k1 = {(float)kv[4], (float)kv[5], (float)kv[6], (float)kv[7]};
      float4 v0 = {(float)vv[0], (float)vv[1], (float)vv[2], (float)vv[3]};
      float4 v1 = {(float)vv[4], (float)vv[5], (float)vv[6], (float)vv[7]};
      *(float4*)&Ks[sr * 68 + sd8] = k0;
      *(float4*)&Ks[sr * 68 + sd8 + 4] = k1;
      *(float4*)&Vs[sr * 68 + sd8] = v0;
      *(float4*)&Vs[sr * 68 + sd8 + 4] = v1;
    }
    __syncthreads();
    {
      const float4* q0p = (const float4*)&qls[(jq * 2) * 68];
      const float4* q1p = (const float4*)&qls[(jq * 2 + 1) * 68];
      const float4* k0p = (const float4*)&Ks[(nq * 2) * 68];
      const float4* k1p = (const float4*)&Ks[(nq * 2 + 1) * 68];
      float s00 = 0.f, s01 = 0.f, s10 = 0.f, s11 = 0.f;
#pragma unroll
      for (int i = 0; i < 16; ++i) {
        int dq = (i + tid) & 15;
        float4 q0 = q0p[dq], q1 = q1p[dq];
        float4 k0 = k0p[dq], k1 = k1p[dq];
        s00 += fabsf(q0.x - k0.x) + fabsf(q0.y - k0.y) + fabsf(q0.z - k0.z) + fabsf(q0.w - k0.w);
        s01 += fabsf(q0.x - k1.x) + fabsf(q0.y - k1.y) + fabsf(q0.z - k1.z) + fabsf(q0.w - k1.w);
        s10 += fabsf(q1.x - k0.x) + fabsf(q1.y - k0.y) + fabsf(q1.z - k0.z) + fabsf(q1.w - k0.w);
        s11 += fabsf(q1.x - k1.x) + fabsf(q1.y - k1.y) + fabsf(q1.z - k1.z) + fabsf(q1.w - k1.w);
      }
      P[(nq * 2) * 36 + jq * 2] = expf(-s00 * 0.25f);
      P[(nq * 2) * 36 + jq * 2 + 1] = expf(-s10 * 0.25f);
      P[(nq * 2 + 1) * 36 + jq * 2] = expf(-s01 * 0.25f);
      P[(nq * 2 + 1) * 36 + jq * 2 + 1] = expf(-s11 * 0.25f);
    }
    __syncthreads();
    {
#pragma unroll 4
      for (int n = 0; n < 32; ++n) {
        float p = P[n * 36 + jl];
        float4 v0 = *(const float4*)&Vs[n * 68 + dq2 * 8];
        float4 v1 = *(const float4*)&Vs[n * 68 + dq2 * 8 + 4];
        acc[0] += p * v0.x; acc[1] += p * v0.y; acc[2] += p * v0.z; acc[3] += p * v0.w;
        acc[4] += p * v1.x; acc[5] += p * v1.y; acc[6] += p * v1.z; acc[7] += p * v1.w;
      }
    }
  }
  {
    float lm = LM[b * 128 + j0 + jl];
    float* dst = &KTVp[((size_t)nc * 16 + bh) * 8192 + (size_t)(j0 + jl) * 64 + dq2 * 8];
    float4 o0 = {acc[0] * lm, acc[1] * lm, acc[2] * lm, acc[3] * lm};
    float4 o1 = {acc[4] * lm, acc[5] * lm, acc[6] * lm, acc[7] * lm};
    *(float4*)dst = o0;
    *(float4*)(dst + 4) = o1;
  }
}

// ---------------------------------------------------------------------------
// K7b: ktv_reduce — KTV[bh][j][d] = sum_nc KTVp[nc][bh][j][d]. float4 lanes.
__global__ __launch_bounds__(256) void ktv_reduce(const float* __restrict__ KTVp,
                                                  float* __restrict__ KTV) {
  int idx = blockIdx.x * 256 + threadIdx.x;  // over 32768 float4s
  const float4* src = (const float4*)KTVp;
  float4 s = src[idx];
#pragma unroll
  for (int nc = 1; nc < 8; ++nc) {
    float4 v = src[(size_t)nc * 32768 + idx];
    s.x += v.x; s.y += v.y; s.z += v.z; s.w += v.w;
  }
  ((float4*)KTV)[idx] = s;
}

// ---------------------------------------------------------------------------
// K8: CTX[bh,i,d] = sum_j X[bh,i,j] * KTV[bh,j,d]  (f32 in, f16 out)
__global__ __launch_bounds__(256) void ctx_kernel(const float* __restrict__ X,
                                                  const float* __restrict__ KTV,
                                                  __half* __restrict__ CTX) {
  int bh = blockIdx.y;
  int i = blockIdx.x * 4 + (threadIdx.x >> 6);
  int d = threadIdx.x & 63;
  const float* wb = X + (size_t)bh * 16384 + (size_t)i * 128;
  const float* kb = KTV + (size_t)bh * 8192 + d;
  float acc = 0.f;
#pragma unroll 4
  for (int jj = 0; jj < 128; ++jj) acc += wb[jj] * kb[(size_t)jj * 64];
  CTX[(size_t)bh * 8192 + (size_t)i * 64 + d] = f2h(acc);
}

// ---------------------------------------------------------------------------
// K9: stats_partial v3 — float4 LDS reads, 2j x 4n register tile.
__global__ __launch_bounds__(256) void stats_partial(
    const __half* __restrict__ Q, const __half* __restrict__ KL,
    const float* __restrict__ LM, const float* __restrict__ tm,
    float* __restrict__ PS, __half* __restrict__ Pbuf) {
  int nt = blockIdx.x;   // 64
  int bh = blockIdx.y;   // 16
  int b = bh >> 3, h = bh & 7;
  int n0 = nt * 16;
  __shared__ __align__(16) float kls[128 * 68];
  __shared__ __align__(16) float qs[16 * 68];
  __shared__ __half ps[16 * 132];
  __shared__ float part[128 * 12];
  int tid = threadIdx.x;
  for (int e = tid; e < 8192; e += 256)
    kls[(e >> 6) * 68 + (e & 63)] = h2f(KL[(size_t)bh * 8192 + e]);
  for (int e = tid; e < 1024; e += 256)
    qs[(e >> 6) * 68 + (e & 63)] =
        h2f(Q[(size_t)b * (Nn * Cc) + (size_t)(n0 + (e >> 6)) * 512 + h * 64 + (e & 63)]);
  __syncthreads();
  int jg = tid & 63, ng = tid >> 6;
  int j = jg * 2;
  const float4* kA = (const float4*)&kls[j * 68];
  const float4* kB = (const float4*)&kls[(j + 1) * 68];
  float sA[4] = {}, sB[4] = {};
#pragma unroll
  for (int i = 0; i < 16; ++i) {
    int dq = (i + jg) & 15;
    float4 ka = kA[dq];
    float4 kb = kB[dq];
#pragma unroll
    for (int r = 0; r < 4; ++r) {
      float4 qv = *(const float4*)&qs[(ng * 4 + r) * 68 + dq * 4];
      sA[r] += fabsf(qv.x - ka.x) + fabsf(qv.y - ka.y) + fabsf(qv.z - ka.z) + fabsf(qv.w - ka.w);
      sB[r] += fabsf(qv.x - kb.x) + fabsf(qv.y - kb.y) + fabsf(qv.z - kb.z) + fabsf(qv.w - kb.w);
    }
  }
  float lmA = LM[b * 128 + j], lmB = LM[b * 128 + j + 1];
  float a1 = 0.f, a2 = 0.f, a3 = 0.f, b1 = 0.f, b2 = 0.f, b3 = 0.f;
#pragma unroll
  for (int r = 0; r < 4; ++r) {
    int nn = ng * 4 + r;
    float t = tm[b * 1024 + n0 + nn];
    float xa = expf(-sA[r] * 0.25f) * lmA;
    float xb = expf(-sB[r] * 0.25f) * lmB;
    ps[nn * 132 + j] = f2h(xa);
    ps[nn * 132 + j + 1] = f2h(xb);
    float xta = xa * t, xtb = xb * t;
    a1 += xta; a2 += xta * xta; a3 += xta * t;
    b1 += xtb; b2 += xtb * xtb; b3 += xtb * t;
  }
  part[j * 12 + ng * 3 + 0] = a1;
  part[j * 12 + ng * 3 + 1] = a2;
  part[j * 12 + ng * 3 + 2] = a3;
  part[(j + 1) * 12 + ng * 3 + 0] = b1;
  part[(j + 1) * 12 + ng * 3 + 1] = b2;
  part[(j + 1) * 12 + ng * 3 + 2] = b3;
  __syncthreads();
  for (int e = tid; e < 2048; e += 256)
    Pbuf[((size_t)bh * 1024 + n0 + (e >> 7)) * 128 + (e & 127)] =
        ps[(e >> 7) * 132 + (e & 127)];
  if (tid < 128) {
    float s1 = part[tid * 12 + 0] + part[tid * 12 + 3] + part[tid * 12 + 6] + part[tid * 12 + 9];
    float s2 = part[tid * 12 + 1] + part[tid * 12 + 4] + part[tid * 12 + 7] + part[tid * 12 + 10];
    float s3 = part[tid * 12 + 2] + part[tid * 12 + 5] + part[tid * 12 + 8] + part[tid * 12 + 11];
    size_t base = ((size_t)(b * 64 + nt) * 8 + h) * 384 + tid * 3;
    PS[base] = s1; PS[base + 1] = s2; PS[base + 2] = s3;
  }
}

// ---------------------------------------------------------------------------
// K10: stats_final — reduce PS over 128 (b,nt) tiles per (h,j).
__global__ __launch_bounds__(256) void stats_final(const float* __restrict__ PS,
                                                   const float* __restrict__ tm,
                                                   float* __restrict__ MU,
                                                   float* __restrict__ RS) {
  __shared__ float red[256][2];
  __shared__ float ts0, ts1;
  int tid = threadIdx.x;
  float a = 0.f, c = 0.f;
  for (int i = tid; i < 2048; i += 256) { float t = tm[i]; a += t; c += t * t; }
  red[tid][0] = a; red[tid][1] = c;
  __syncthreads();
  for (int off = 128; off > 0; off >>= 1) {
    if (tid < off) { red[tid][0] += red[tid + off][0]; red[tid][1] += red[tid + off][1]; }
    __syncthreads();
  }
  if (tid == 0) { ts0 = red[0][0]; ts1 = red[0][1]; }
  __syncthreads();
  int hj = blockIdx.x * 256 + tid;
  int h = hj >> 7, j = hj & 127;
  float s1 = 0.f, s2 = 0.f, s3 = 0.f;
  for (int bnt = 0; bnt < 128; ++bnt) {
    const float* p = PS + ((size_t)bnt * 8 + h) * 384 + j * 3;
    s1 += p[0]; s2 += p[1]; s3 += p[2];
  }
  float valid = fmaxf(ts0, 1.f);
  float mu = s1 / valid;
  float var = (s2 - 2.f * mu * s3 + mu * mu * ts1) / valid;
  var = fmaxf(var, 0.f);
  MU[hj] = mu;
  RS[hj] = rsqrtf(var + WHITE_EPS);
}

// ---------------------------------------------------------------------------
// K11: vlocal — LDS-tiled scrambled depthwise conv.
__global__ __launch_bounds__(256) void vlocal_kernel(
    const __half* __restrict__ V, const float* __restrict__ dwc_w,
    const float* __restrict__ dwc_b, const float* __restrict__ tm,
    __half* __restrict__ VL) {
  int t0 = blockIdx.x * 64;
  int ct = blockIdx.y & 7, b = blockIdx.y >> 3;
  int c0 = ct * 64;
  __shared__ float vs[64][67];
  int tid = threadIdx.x;
  for (int e = tid; e < 64 * 66; e += 256) {
    int cl = e / 66, uu = e % 66;
    int u = t0 - 1 + uu;
    float val = 0.f;
    if (u >= 0 && u < 1024) {
      int c = c0 + cl;
      int n = 2 * c + (u >> 9), ch = u & 511;
      val = h2f(V[(size_t)b * (Nn * Cc) + (size_t)n * 512 + ch]);
    }
    vs[cl][uu] = val;
  }
  __syncthreads();
  int cl = tid & 63;
  int c = c0 + cl;
  float w0 = dwc_w[c * 3], w1 = dwc_w[c * 3 + 1], w2 = dwc_w[c * 3 + 2];
  float bb = dwc_b[c];
  int tg = tid >> 6;
#pragma unroll
  for (int i = 0; i < 16; ++i) {
    int tl = tg * 16 + i;
    int t = t0 + tl;
    float acc = bb + w0 * vs[cl][tl] + w1 * vs[cl][tl + 1] + w2 * vs[cl][tl + 2];
    VL[(size_t)b * (Nn * Cc) + (size_t)t * 512 + c] = f2h(acc * tm[b * 1024 + t]);
  }
}

// ---------------------------------------------------------------------------
// K12: ga — load precomputed P, whiten, @context, accumulate into VL.
__global__ __launch_bounds__(256) void ga_fused(
    const __half* __restrict__ Pbuf, const float* __restrict__ MU,
    const float* __restrict__ RS, const __half* __restrict__ CTXg,
    const float* __restrict__ tm, __half* __restrict__ VL) {
  int bh = blockIdx.y;
  int b = bh >> 3, h = bh & 7;
  int n0 = blockIdx.x * 16;
  __shared__ __half Ps[16][130];
  __shared__ __align__(16) __half2 ctx2[128][32];
  __shared__ float musr[128][2];
  int tid = threadIdx.x;
  for (int e = tid; e < 2048; e += 256)
    Ps[e >> 7][e & 127] = Pbuf[((size_t)bh * 1024 + n0 + (e >> 7)) * 128 + (e & 127)];
  {
    const __half2* cg = (const __half2*)(CTXg + (size_t)bh * 8192);
    for (int e = tid; e < 4096; e += 256) ctx2[e >> 5][e & 31] = cg[e];
  }
  if (tid < 128) { musr[tid][0] = MU[h * 128 + tid]; musr[tid][1] = RS[h * 128 + tid]; }
  __syncthreads();
  int nn = tid >> 4, dq = tid & 15;
  float a0 = 0.f, a1 = 0.f, a2 = 0.f, a3 = 0.f;
#pragma unroll 4
  for (int j = 0; j < 128; ++j) {
    float pj = (h2f(Ps[nn][j]) - musr[j][0]) * musr[j][1];
    uint2 cc = *(const uint2*)&ctx2[j][dq * 2];
    __half2 c01 = __builtin_bit_cast(__half2, cc.x);
    __half2 c23 = __builtin_bit_cast(__half2, cc.y);
    a0 += pj * h2f(c01.x); a1 += pj * h2f(c01.y);
    a2 += pj * h2f(c23.x); a3 += pj * h2f(c23.y);
  }
  float t = tm[b * 1024 + n0 + nn];
  float t2 = t * t;
  size_t base = (size_t)b * (Nn * Cc) + (size_t)(n0 + nn) * 512 + h * 64 + dq * 4;
  VL[base] = f2h(h2f(VL[base]) + t2 * a0);
  VL[base + 1] = f2h(h2f(VL[base + 1]) + t2 * a1);
  VL[base + 2] = f2h(h2f(VL[base + 2]) + t2 * a2);
  VL[base + 3] = f2h(h2f(VL[base + 3]) + t2 * a3);
}

// ---------------------------------------------------------------------------
// K13: proj via MFMA f16. M=2048, N=512, K=512.
__global__ __launch_bounds__(256) void proj_gemm(
    const __half* __restrict__ Ain, const float* __restrict__ w,
    const float* __restrict__ bias, const float* __restrict__ tm,
    float* __restrict__ out) {
  __shared__ _Float16 As[128 * 40];
  __shared__ _Float16 Bs[128 * 40];
  int m0 = blockIdx.x * 128, n0 = blockIdx.y * 128;
  int tid = threadIdx.x;
  int lane = tid & 63, wv = tid >> 6;
  int wm = (wv >> 1) * 64, wn = (wv & 1) * 64;
  int l15 = lane & 15, quad = lane >> 4;
  int srow = tid >> 1, shalf = tid & 1;
  float4v acc[4][4] = {};
  for (int k0 = 0; k0 < 512; k0 += 32) {
    __syncthreads();
    {
      const half8* ga = (const half8*)(Ain + (size_t)(m0 + srow) * 512 + k0 + shalf * 16);
      const float4* gb = (const float4*)(w + (size_t)(n0 + srow) * 512 + k0 + shalf * 16);
      half8 ha0 = ga[0], ha1 = ga[1];
      float4 b0 = gb[0], b1 = gb[1], b2 = gb[2], b3 = gb[3];
      half8 hb0 = {(_Float16)b0.x, (_Float16)b0.y, (_Float16)b0.z, (_Float16)b0.w,
                   (_Float16)b1.x, (_Float16)b1.y, (_Float16)b1.z, (_Float16)b1.w};
      half8 hb1 = {(_Float16)b2.x, (_Float16)b2.y, (_Float16)b2.z, (_Float16)b2.w,
                   (_Float16)b3.x, (_Float16)b3.y, (_Float16)b3.z, (_Float16)b3.w};
      int lo = srow * 40 + shalf * 16;
      *(half8*)&As[lo] = ha0;
      *(half8*)&As[lo + 8] = ha1;
      *(half8*)&Bs[lo] = hb0;
      *(half8*)&Bs[lo + 8] = hb1;
    }
    __syncthreads();
    half8 a[4], b[4];
#pragma unroll
    for (int mt = 0; mt < 4; ++mt)
      a[mt] = *(const half8*)&As[(wm + mt * 16 + l15) * 40 + quad * 8];
#pragma unroll
    for (int nt = 0; nt < 4; ++nt)
      b[nt] = *(const half8*)&Bs[(wn + nt * 16 + l15) * 40 + quad * 8];
#pragma unroll
    for (int mt = 0; mt < 4; ++mt)
#pragma unroll
      for (int nt = 0; nt < 4; ++nt)
        acc[mt][nt] =
            __builtin_amdgcn_mfma_f32_16x16x32_f16(a[mt], b[nt], acc[mt][nt], 0, 0, 0);
  }
#pragma unroll
  for (int mt = 0; mt < 4; ++mt) {
#pragma unroll
    for (int r = 0; r < 4; ++r) {
      int row = m0 + wm + mt * 16 + quad * 4 + r;
      int b_ = row >> 10, n_ = row & 1023;
      float t = tm[b_ * 1024 + n_];
#pragma unroll
      for (int nt = 0; nt < 4; ++nt) {
        int co = n0 + wn + nt * 16 + l15;
        out[(size_t)row * 512 + co] = (acc[mt][nt][r] + bias[co]) * t;
      }
    }
  }
}

// ---------------------------------------------------------------------------
// d_ws 11.26 MiB (proven). d_out (4 MiB): Wf f32 (NS) -> KTVp f32 partials
// (ktv) -> Pbuf f16 (stats->ga) -> final f32 output. No lifetime overlaps.
extern "C" void kernel_launch(void* const* d_in, const int* in_sizes, int n_in,
                              void* d_out, int out_size, void* d_ws, size_t ws_size,
                              hipStream_t stream) {
  const float* x      = (const float*)d_in[0];
  const float* tm     = (const float*)d_in[1];
  const float* qkv_w  = (const float*)d_in[2];
  const float* qkv_b  = (const float*)d_in[3];
  const float* proj_w = (const float*)d_in[4];
  const float* proj_b = (const float*)d_in[5];
  const float* dwc_w  = (const float*)d_in[6];
  const float* dwc_b  = (const float*)d_in[7];
  float* out = (float*)d_out;

  char* wsb = (char*)d_ws;
  __half* Qh  = (__half*)(wsb + 0);
  __half* Kh  = (__half*)(wsb + 2097152);
  __half* Vh  = (__half*)(wsb + 4194304);
  __half* VLh = (__half*)(wsb + 6291456);
  __half* QLh = (__half*)(wsb + 8388608);
  __half* KLh = (__half*)(wsb + 8650752);
  float*  LM  = (float*)(wsb + 8912896);
  float*  MU  = (float*)(wsb + 8913920);
  float*  RS  = (float*)(wsb + 8918016);
  float*  KTV = (float*)(wsb + 8922112);
  __half* CTX = (__half*)(wsb + 9446400);
  float*  XA  = (float*)(wsb + 9708544);
  float*  XB  = (float*)(wsb + 10757120);
  float*  PS  = (float*)(wsb + 9708544);  // overlays XA+XB after ctx

  char* ob = (char*)d_out;
  float*  Wf   = (float*)ob;     // NS phase
  float*  KTVp = (float*)ob;     // ktv partials (4 MiB, after NS)
  __half* Pbuf = (__half*)ob;    // stats->ga phase

  qkv_gemm<<<dim3(16, 12), 256, 0, stream>>>(x, qkv_w, qkv_b, tm, Qh, Kh, Vh);
  pool_kernel<<<dim3(16, 16), 256, 0, stream>>>(Qh, Kh, tm, QLh, KLh, LM);
  wbuild_kernel<<<dim3(2, 16), 256, 0, stream>>>(QLh, KLh, LM, Wf);
  nsinit_kernel<<<16, 256, 0, stream>>>(Wf, XA);
  float* Xc = XA;
  float* Xn = XB;
  for (int it = 0; it < 5; ++it) {
    ns_iter<<<dim3(8, 16), 256, 0, stream>>>(Wf, Xc, Xn);
    float* tswap = Xc; Xc = Xn; Xn = tswap;
  }
  ktv_fused<<<dim3(4, 16, 8), 256, 0, stream>>>(Kh, QLh, LM, Vh, KTVp);
  ktv_reduce<<<128, 256, 0, stream>>>(KTVp, KTV);
  ctx_kernel<<<dim3(32, 16), 256, 0, stream>>>(Xc, KTV, CTX);
  stats_partial<<<dim3(64, 16), 256, 0, stream>>>(Qh, KLh, LM, tm, PS, Pbuf);
  stats_final<<<4, 256, 0, stream>>>(PS, tm, MU, RS);
  vlocal_kernel<<<dim3(16, 16), 256, 0, stream>>>(Vh, dwc_w, dwc_b, tm, VLh);
  ga_fused<<<dim3(64, 16), 256, 0, stream>>>(Pbuf, MU, RS, CTX, tm, VLh);
  proj_gemm<<<dim3(16, 4), 256, 0, stream>>>(VLh, proj_w, proj_b, tm, out);
}

// Round 13
// 417.526 us; speedup vs baseline: 1.1043x; 1.0040x over previous
//
#include <hip/hip_runtime.h>
#include <hip/hip_bf16.h>
#include <hip/hip_fp16.h>

// B=2, N=1024, C=512, H=8, D=64, m=128, p=8
#define Hh 8
#define Bz 2
#define Nn 1024
#define Cc 512
#define Dd 64
#define Mm 128
#define NS_EPS 1e-4f
#define WHITE_EPS 1e-5f

__device__ __forceinline__ float h2f(__half v) { return __half2float(v); }
__device__ __forceinline__ __half f2h(float v) { return __float2half(v); }

typedef _Float16 half8 __attribute__((ext_vector_type(8)));
typedef float float4v __attribute__((ext_vector_type(4)));

// ---------------------------------------------------------------------------
// K1: QKV GEMM via MFMA f16. M=2048, N=1536, K=512. Block tile 128x128.
__global__ __launch_bounds__(256) void qkv_gemm(
    const float* __restrict__ x, const float* __restrict__ w,
    const float* __restrict__ bias, const float* __restrict__ tm,
    __half* __restrict__ Q, __half* __restrict__ K, __half* __restrict__ V) {
  __shared__ _Float16 As[128 * 40];
  __shared__ _Float16 Bs[128 * 40];
  int m0 = blockIdx.x * 128, n0 = blockIdx.y * 128;
  int tid = threadIdx.x;
  int lane = tid & 63, wv = tid >> 6;
  int wm = (wv >> 1) * 64, wn = (wv & 1) * 64;
  int l15 = lane & 15, quad = lane >> 4;
  int srow = tid >> 1, shalf = tid & 1;
  float4v acc[4][4] = {};
  for (int k0 = 0; k0 < 512; k0 += 32) {
    __syncthreads();
    {
      const float4* ga = (const float4*)(x + (size_t)(m0 + srow) * 512 + k0 + shalf * 16);
      const float4* gb = (const float4*)(w + (size_t)(n0 + srow) * 512 + k0 + shalf * 16);
      float4 a0 = ga[0], a1 = ga[1], a2 = ga[2], a3 = ga[3];
      float4 b0 = gb[0], b1 = gb[1], b2 = gb[2], b3 = gb[3];
      half8 ha0 = {(_Float16)a0.x, (_Float16)a0.y, (_Float16)a0.z, (_Float16)a0.w,
                   (_Float16)a1.x, (_Float16)a1.y, (_Float16)a1.z, (_Float16)a1.w};
      half8 ha1 = {(_Float16)a2.x, (_Float16)a2.y, (_Float16)a2.z, (_Float16)a2.w,
                   (_Float16)a3.x, (_Float16)a3.y, (_Float16)a3.z, (_Float16)a3.w};
      half8 hb0 = {(_Float16)b0.x, (_Float16)b0.y, (_Float16)b0.z, (_Float16)b0.w,
                   (_Float16)b1.x, (_Float16)b1.y, (_Float16)b1.z, (_Float16)b1.w};
      half8 hb1 = {(_Float16)b2.x, (_Float16)b2.y, (_Float16)b2.z, (_Float16)b2.w,
                   (_Float16)b3.x, (_Float16)b3.y, (_Float16)b3.z, (_Float16)b3.w};
      int lo = srow * 40 + shalf * 16;
      *(half8*)&As[lo] = ha0;
      *(half8*)&As[lo + 8] = ha1;
      *(half8*)&Bs[lo] = hb0;
      *(half8*)&Bs[lo + 8] = hb1;
    }
    __syncthreads();
    half8 a[4], b[4];
#pragma unroll
    for (int mt = 0; mt < 4; ++mt)
      a[mt] = *(const half8*)&As[(wm + mt * 16 + l15) * 40 + quad * 8];
#pragma unroll
    for (int nt = 0; nt < 4; ++nt)
      b[nt] = *(const half8*)&Bs[(wn + nt * 16 + l15) * 40 + quad * 8];
#pragma unroll
    for (int mt = 0; mt < 4; ++mt)
#pragma unroll
      for (int nt = 0; nt < 4; ++nt)
        acc[mt][nt] =
            __builtin_amdgcn_mfma_f32_16x16x32_f16(a[mt], b[nt], acc[mt][nt], 0, 0, 0);
  }
#pragma unroll
  for (int mt = 0; mt < 4; ++mt) {
#pragma unroll
    for (int r = 0; r < 4; ++r) {
      int row = m0 + wm + mt * 16 + quad * 4 + r;
      int b_ = row >> 10, n_ = row & 1023;
      float t = tm[b_ * 1024 + n_];
#pragma unroll
      for (int nt = 0; nt < 4; ++nt) {
        int c3 = n0 + wn + nt * 16 + l15;
        float v = (acc[mt][nt][r] + bias[c3]) * t;
        int sec = c3 >> 9, ch = c3 & 511;
        __half* dst = (sec == 0) ? Q : (sec == 1 ? K : V);
        dst[(size_t)b_ * (Nn * Cc) + (size_t)n_ * 512 + ch] = f2h(v);
      }
    }
  }
}

// ---------------------------------------------------------------------------
// K2: pool — block per (b,h,u-tile of 64). Coalesced row staging.
__global__ __launch_bounds__(256) void pool_kernel(
    const __half* __restrict__ Q, const __half* __restrict__ K,
    const float* __restrict__ tm, __half* __restrict__ QL,
    __half* __restrict__ KL, float* __restrict__ LM) {
  int ut = blockIdx.x;
  int bh = blockIdx.y;
  int b = bh >> 3, h = bh & 7;
  int u0 = ut * 64;
  int delta = u0 >> 9;
  int ch0 = u0 & 511;
  __shared__ float Qs[64][65];
  __shared__ float Ks[64][65];
  int tid = threadIdx.x;
  for (int e = tid; e < 4096; e += 256) {
    int d = e >> 6, uu = e & 63;
    int row = 2 * (h * 64 + d) + delta;
    size_t gi = (size_t)b * (Nn * Cc) + (size_t)row * 512 + ch0 + uu;
    Qs[d][uu] = h2f(Q[gi]);
    Ks[d][uu] = h2f(K[gi]);
  }
  __syncthreads();
  int d = tid & 63, s = tid >> 6;
#pragma unroll
  for (int jr = 0; jr < 2; ++jr) {
    int jl = s + 4 * jr;
    int j = ut * 8 + jl;
    float pm = 0.f, sq = 0.f, sk = 0.f;
#pragma unroll
    for (int i = 0; i < 8; ++i) {
      float t = tm[b * 1024 + 8 * j + i];
      pm += t;
      sq += Qs[d][8 * jl + i] * t;
      sk += Ks[d][8 * jl + i] * t;
    }
    pm *= 0.125f;
    float pms = fmaxf(pm, 1e-6f);
    size_t oi = ((size_t)bh * 128 + j) * 64 + d;
    QL[oi] = f2h(sq * 0.125f / pms);
    KL[oi] = f2h(sk * 0.125f / pms);
    if (h == 0 && d == 0) LM[b * 128 + j] = (pm > 0.f) ? 1.f : 0.f;
  }
}

// ---------------------------------------------------------------------------
// K3: W_eps[b,h,i,j] (f32, lives in d_out during NS)
__global__ __launch_bounds__(256) void wbuild_kernel(
    const __half* __restrict__ QL, const __half* __restrict__ KL,
    const float* __restrict__ LM, float* __restrict__ W) {
  int bh = blockIdx.y;
  int b = bh >> 3;
  int i0 = blockIdx.x * 64;
  __shared__ float ks[128][65];
  __shared__ float qs[64][65];
  int tid = threadIdx.x;
  const __half* klb = KL + (size_t)bh * (Mm * Dd);
  const __half* qlb = QL + (size_t)bh * (Mm * Dd);
  for (int e = tid; e < 128 * 64; e += 256) ks[e >> 6][e & 63] = h2f(klb[e]);
  for (int e = tid; e < 64 * 64; e += 256) qs[e >> 6][e & 63] = h2f(qlb[i0 * 64 + e]);
  __syncthreads();
  for (int e = tid; e < 64 * 128; e += 256) {
    int il = e >> 7, j = e & 127;
    int i = i0 + il;
    float s = 0.f;
#pragma unroll
    for (int d = 0; d < 64; ++d) s += fabsf(qs[il][d] - ks[j][d]);
    float wv = expf(-s * 0.25f);
    float pr = LM[b * Mm + i] * LM[b * Mm + j];
    float diag = (i == j) ? 1.f : 0.f;
    wv = wv * pr + diag * (1.f - pr) + diag * NS_EPS;
    W[(size_t)bh * (Mm * Mm) + i * 128 + j] = wv;
  }
}

// ---------------------------------------------------------------------------
// K4: X0 = 2/(fro+1e-8) * W^T  (f32)
__global__ __launch_bounds__(256) void nsinit_kernel(const float* __restrict__ W,
                                                     float* __restrict__ X) {
  int bh = blockIdx.x;
  const float* Wb = W + (size_t)bh * 16384;
  float* Xb = X + (size_t)bh * 16384;
  __shared__ float red[256];
  int tid = threadIdx.x;
  float s = 0.f;
  for (int e = tid; e < 16384; e += 256) { float wv = Wb[e]; s += wv * wv; }
  red[tid] = s;
  __syncthreads();
  for (int off = 128; off > 0; off >>= 1) {
    if (tid < off) red[tid] += red[tid + off];
    __syncthreads();
  }
  float scale = 2.f / (sqrtf(red[0]) + 1e-8f);
  for (int e = tid; e < 16384; e += 256) {
    int i = e >> 7, j = e & 127;
    Xb[e] = scale * Wb[j * 128 + i];
  }
}

// ---------------------------------------------------------------------------
// K5: ns_iter — Xn = Xc @ (2I - W @ Xc), 8 column-blocks of 16.
__global__ __launch_bounds__(256) void ns_iter(const float* __restrict__ W,
                                               const float* __restrict__ Xc,
                                               float* __restrict__ Xn) {
  int bh = blockIdx.y;
  int cb = blockIdx.x;  // 0..7
  const float* Wb = W + (size_t)bh * 16384;
  const float* Xb = Xc + (size_t)bh * 16384;
  float* Ob = Xn + (size_t)bh * 16384;
  __shared__ float Xs[128][17];
  __shared__ float Ts[128][17];
  __shared__ float St[128][33];
  int tid = threadIdx.x;
  int jc = tid & 15;
  int ibase = (tid >> 4) * 8;
  for (int e = tid; e < 2048; e += 256) {
    int k = e >> 4, j = e & 15;
    Xs[k][j] = Xb[(size_t)k * 128 + cb * 16 + j];
  }
  float acc[8];
#pragma unroll
  for (int r = 0; r < 8; ++r) acc[r] = 0.f;
  for (int kt = 0; kt < 4; ++kt) {
    __syncthreads();
    for (int e = tid; e < 4096; e += 256)
      St[e >> 5][e & 31] = Wb[(size_t)(e >> 5) * 128 + kt * 32 + (e & 31)];
    __syncthreads();
#pragma unroll 8
    for (int kk = 0; kk < 32; ++kk) {
      float xv = Xs[kt * 32 + kk][jc];
#pragma unroll
      for (int r = 0; r < 8; ++r) acc[r] += St[ibase + r][kk] * xv;
    }
  }
#pragma unroll
  for (int r = 0; r < 8; ++r) {
    int i = ibase + r;
    Ts[i][jc] = ((i == cb * 16 + jc) ? 2.f : 0.f) - acc[r];
  }
  float acc2[8];
#pragma unroll
  for (int r = 0; r < 8; ++r) acc2[r] = 0.f;
  for (int kt = 0; kt < 4; ++kt) {
    __syncthreads();
    for (int e = tid; e < 4096; e += 256)
      St[e >> 5][e & 31] = Xb[(size_t)(e >> 5) * 128 + kt * 32 + (e & 31)];
    __syncthreads();
#pragma unroll 8
    for (int kk = 0; kk < 32; ++kk) {
      float tv = Ts[kt * 32 + kk][jc];
#pragma unroll
      for (int r = 0; r < 8; ++r) acc2[r] += St[ibase + r][kk] * tv;
    }
  }
#pragma unroll
  for (int r = 0; r < 8; ++r)
    Ob[(size_t)(ibase + r) * 128 + cb * 16 + jc] = acc2[r];
}

// ---------------------------------------------------------------------------
// K7: ktv — fused C_k + K^T V. Non-atomic partials to KTVp[nc][bh][j][d].
__global__ __launch_bounds__(256) void ktv_fused(
    const __half* __restrict__ K, const __half* __restrict__ QL,
    const float* __restrict__ LM, const __half* __restrict__ V,
    float* __restrict__ KTVp) {
  int jt = blockIdx.x;   // 4 (32 j each)
  int bh = blockIdx.y;   // 16
  int nc = blockIdx.z;   // 8 (128 n each)
  int b = bh >> 3, h = bh & 7;
  int j0 = jt * 32;
  __shared__ __align__(16) float qls[32 * 68];
  __shared__ __align__(16) float Ks[32 * 68];
  __shared__ __align__(16) float Vs[32 * 68];
  __shared__ float P[32 * 36];
  int tid = threadIdx.x;
  int sr = tid >> 3, sd8 = (tid & 7) * 8;
  {
    half8 q = *(const half8*)(QL + (size_t)bh * 8192 + (size_t)(j0 + sr) * 64 + sd8);
    float4 f0 = {(float)q[0], (float)q[1], (float)q[2], (float)q[3]};
    float4 f1 = {(float)q[4], (float)q[5], (float)q[6], (float)q[7]};
    *(float4*)&qls[sr * 68 + sd8] = f0;
    *(float4*)&qls[sr * 68 + sd8 + 4] = f1;
  }
  int jq = tid & 15, nq = tid >> 4;
  int dq2 = tid & 7, jl = tid >> 3;
  float acc[8] = {};
  for (int nt = 0; nt < 4; ++nt) {
    int n0 = nc * 128 + nt * 32;
    __syncthreads();
    {
      size_t gi = (size_t)b * (Nn * Cc) + (size_t)(n0 + sr) * 512 + h * 64 + sd8;
      half8 kv = *(const half8*)(K + gi);
      half8 vv = *(const half8*)(V + gi);
      float4 k0 = {(float)kv[0], (float)kv[1], (float)kv[2], (float)kv[3]};
      float4 k1 = {(float)kv[4], (float)kv[5], (float)kv[6], (float)kv[7]};
      float4 v0 = {(float)vv[0], (float)vv[1], (float)vv[2], (float)vv[3]};
      float4 v1 = {(float)vv[4], (float)vv[5], (float)vv[6], (float)vv[7]};
      *(float4*)&Ks[sr * 68 + sd8] = k0;
      *(float4*)&Ks[sr * 68 + sd8 + 4] = k1;
      *(float4*)&Vs[sr * 68 + sd8] = v0;
      *(float4*)&Vs[sr * 68 + sd8 + 4] = v1;
    }
    __syncthreads();
    {
      const float4* q0p = (const float4*)&qls[(jq * 2) * 68];
      const float4* q1p = (const float4*)&qls[(jq * 2 + 1) * 68];
      const float4* k0p = (const float4*)&Ks[(nq * 2) * 68];
      const float4* k1p = (const float4*)&Ks[(nq * 2 + 1) * 68];
      float s00 = 0.f, s01 = 0.f, s10 = 0.f, s11 = 0.f;
#pragma unroll
      for (int i = 0; i < 16; ++i) {
        int dq = (i + tid) & 15;
        float4 q0 = q0p[dq], q1 = q1p[dq];
        float4 k0 = k0p[dq], k1 = k1p[dq];
        s00 += fabsf(q0.x - k0.x) + fabsf(q0.y - k0.y) + fabsf(q0.z - k0.z) + fabsf(q0.w - k0.w);
        s01 += fabsf(q0.x - k1.x) + fabsf(q0.y - k1.y) + fabsf(q0.z - k1.z) + fabsf(q0.w - k1.w);
        s10 += fabsf(q1.x - k0.x) + fabsf(q1.y - k0.y) + fabsf(q1.z - k0.z) + fabsf(q1.w - k0.w);
        s11 += fabsf(q1.x - k1.x) + fabsf(q1.y - k1.y) + fabsf(q1.z - k1.z) + fabsf(q1.w - k1.w);
      }
      P[(nq * 2) * 36 + jq * 2] = expf(-s00 * 0.25f);
      P[(nq * 2) * 36 + jq * 2 + 1] = expf(-s10 * 0.25f);
      P[(nq * 2 + 1) * 36 + jq * 2] = expf(-s01 * 0.25f);
      P[(nq * 2 + 1) * 36 + jq * 2 + 1] = expf(-s11 * 0.25f);
    }
    __syncthreads();
    {
#pragma unroll 4
      for (int n = 0; n < 32; ++n) {
        float p = P[n * 36 + jl];
        float4 v0 = *(const float4*)&Vs[n * 68 + dq2 * 8];
        float4 v1 = *(const float4*)&Vs[n * 68 + dq2 * 8 + 4];
        acc[0] += p * v0.x; acc[1] += p * v0.y; acc[2] += p * v0.z; acc[3] += p * v0.w;
        acc[4] += p * v1.x; acc[5] += p * v1.y; acc[6] += p * v1.z; acc[7] += p * v1.w;
      }
    }
  }
  {
    float lm = LM[b * 128 + j0 + jl];
    float* dst = &KTVp[((size_t)nc * 16 + bh) * 8192 + (size_t)(j0 + jl) * 64 + dq2 * 8];
    float4 o0 = {acc[0] * lm, acc[1] * lm, acc[2] * lm, acc[3] * lm};
    float4 o1 = {acc[4] * lm, acc[5] * lm, acc[6] * lm, acc[7] * lm};
    *(float4*)dst = o0;
    *(float4*)(dst + 4) = o1;
  }
}

// ---------------------------------------------------------------------------
// K8: ctx v2 — fused nc-reduction of KTVp (LDS) + CTX = X @ KTV.
// Grid (8, 16): block = (i-tile of 16, bh).
__global__ __launch_bounds__(256) void ctx_kernel(const float* __restrict__ X,
                                                  const float* __restrict__ KTVp,
                                                  __half* __restrict__ CTX) {
  int it = blockIdx.x;  // 0..7
  int bh = blockIdx.y;  // 16
  int i0 = it * 16;
  __shared__ __align__(16) float KTVs[8192];  // [j*64+d]
  __shared__ float Xs[16][132];
  int tid = threadIdx.x;
  const float4* src = (const float4*)KTVp;
  for (int e = tid; e < 2048; e += 256) {
    float4 s = src[(size_t)bh * 2048 + e];
#pragma unroll
    for (int nc = 1; nc < 8; ++nc) {
      float4 v = src[((size_t)nc * 16 + bh) * 2048 + e];
      s.x += v.x; s.y += v.y; s.z += v.z; s.w += v.w;
    }
    *(float4*)&KTVs[e * 4] = s;
  }
  for (int e = tid; e < 2048; e += 256)
    Xs[e >> 7][e & 127] = X[(size_t)bh * 16384 + (size_t)(i0 + (e >> 7)) * 128 + (e & 127)];
  __syncthreads();
  int il = tid >> 4, dg = tid & 15;
  float a0 = 0.f, a1 = 0.f, a2 = 0.f, a3 = 0.f;
#pragma unroll 4
  for (int j = 0; j < 128; ++j) {
    float xv = Xs[il][j];
    float4 kv = *(const float4*)&KTVs[j * 64 + dg * 4];
    a0 += xv * kv.x; a1 += xv * kv.y; a2 += xv * kv.z; a3 += xv * kv.w;
  }
  size_t ob = (size_t)bh * 8192 + (size_t)(i0 + il) * 64 + dg * 4;
  CTX[ob] = f2h(a0);
  CTX[ob + 1] = f2h(a1);
  CTX[ob + 2] = f2h(a2);
  CTX[ob + 3] = f2h(a3);
}

// ---------------------------------------------------------------------------
// K9: stats_partial v3 — float4 LDS reads, 2j x 4n register tile.
__global__ __launch_bounds__(256) void stats_partial(
    const __half* __restrict__ Q, const __half* __restrict__ KL,
    const float* __restrict__ LM, const float* __restrict__ tm,
    float* __restrict__ PS, __half* __restrict__ Pbuf) {
  int nt = blockIdx.x;   // 64
  int bh = blockIdx.y;   // 16
  int b = bh >> 3, h = bh & 7;
  int n0 = nt * 16;
  __shared__ __align__(16) float kls[128 * 68];
  __shared__ __align__(16) float qs[16 * 68];
  __shared__ __half ps[16 * 132];
  __shared__ float part[128 * 12];
  int tid = threadIdx.x;
  for (int e = tid; e < 8192; e += 256)
    kls[(e >> 6) * 68 + (e & 63)] = h2f(KL[(size_t)bh * 8192 + e]);
  for (int e = tid; e < 1024; e += 256)
    qs[(e >> 6) * 68 + (e & 63)] =
        h2f(Q[(size_t)b * (Nn * Cc) + (size_t)(n0 + (e >> 6)) * 512 + h * 64 + (e & 63)]);
  __syncthreads();
  int jg = tid & 63, ng = tid >> 6;
  int j = jg * 2;
  const float4* kA = (const float4*)&kls[j * 68];
  const float4* kB = (const float4*)&kls[(j + 1) * 68];
  float sA[4] = {}, sB[4] = {};
#pragma unroll
  for (int i = 0; i < 16; ++i) {
    int dq = (i + jg) & 15;
    float4 ka = kA[dq];
    float4 kb = kB[dq];
#pragma unroll
    for (int r = 0; r < 4; ++r) {
      float4 qv = *(const float4*)&qs[(ng * 4 + r) * 68 + dq * 4];
      sA[r] += fabsf(qv.x - ka.x) + fabsf(qv.y - ka.y) + fabsf(qv.z - ka.z) + fabsf(qv.w - ka.w);
      sB[r] += fabsf(qv.x - kb.x) + fabsf(qv.y - kb.y) + fabsf(qv.z - kb.z) + fabsf(qv.w - kb.w);
    }
  }
  float lmA = LM[b * 128 + j], lmB = LM[b * 128 + j + 1];
  float a1 = 0.f, a2 = 0.f, a3 = 0.f, b1 = 0.f, b2 = 0.f, b3 = 0.f;
#pragma unroll
  for (int r = 0; r < 4; ++r) {
    int nn = ng * 4 + r;
    float t = tm[b * 1024 + n0 + nn];
    float xa = expf(-sA[r] * 0.25f) * lmA;
    float xb = expf(-sB[r] * 0.25f) * lmB;
    ps[nn * 132 + j] = f2h(xa);
    ps[nn * 132 + j + 1] = f2h(xb);
    float xta = xa * t, xtb = xb * t;
    a1 += xta; a2 += xta * xta; a3 += xta * t;
    b1 += xtb; b2 += xtb * xtb; b3 += xtb * t;
  }
  part[j * 12 + ng * 3 + 0] = a1;
  part[j * 12 + ng * 3 + 1] = a2;
  part[j * 12 + ng * 3 + 2] = a3;
  part[(j + 1) * 12 + ng * 3 + 0] = b1;
  part[(j + 1) * 12 + ng * 3 + 1] = b2;
  part[(j + 1) * 12 + ng * 3 + 2] = b3;
  __syncthreads();
  for (int e = tid; e < 2048; e += 256)
    Pbuf[((size_t)bh * 1024 + n0 + (e >> 7)) * 128 + (e & 127)] =
        ps[(e >> 7) * 132 + (e & 127)];
  if (tid < 128) {
    float s1 = part[tid * 12 + 0] + part[tid * 12 + 3] + part[tid * 12 + 6] + part[tid * 12 + 9];
    float s2 = part[tid * 12 + 1] + part[tid * 12 + 4] + part[tid * 12 + 7] + part[tid * 12 + 10];
    float s3 = part[tid * 12 + 2] + part[tid * 12 + 5] + part[tid * 12 + 8] + part[tid * 12 + 11];
    size_t base = ((size_t)(b * 64 + nt) * 8 + h) * 384 + tid * 3;
    PS[base] = s1; PS[base + 1] = s2; PS[base + 2] = s3;
  }
}

// ---------------------------------------------------------------------------
// K10: stats_final — reduce PS over 128 (b,nt) tiles per (h,j).
__global__ __launch_bounds__(256) void stats_final(const float* __restrict__ PS,
                                                   const float* __restrict__ tm,
                                                   float* __restrict__ MU,
                                                   float* __restrict__ RS) {
  __shared__ float red[256][2];
  __shared__ float ts0, ts1;
  int tid = threadIdx.x;
  float a = 0.f, c = 0.f;
  for (int i = tid; i < 2048; i += 256) { float t = tm[i]; a += t; c += t * t; }
  red[tid][0] = a; red[tid][1] = c;
  __syncthreads();
  for (int off = 128; off > 0; off >>= 1) {
    if (tid < off) { red[tid][0] += red[tid + off][0]; red[tid][1] += red[tid + off][1]; }
    __syncthreads();
  }
  if (tid == 0) { ts0 = red[0][0]; ts1 = red[0][1]; }
  __syncthreads();
  int hj = blockIdx.x * 256 + tid;
  int h = hj >> 7, j = hj & 127;
  float s1 = 0.f, s2 = 0.f, s3 = 0.f;
  for (int bnt = 0; bnt < 128; ++bnt) {
    const float* p = PS + ((size_t)bnt * 8 + h) * 384 + j * 3;
    s1 += p[0]; s2 += p[1]; s3 += p[2];
  }
  float valid = fmaxf(ts0, 1.f);
  float mu = s1 / valid;
  float var = (s2 - 2.f * mu * s3 + mu * mu * ts1) / valid;
  var = fmaxf(var, 0.f);
  MU[hj] = mu;
  RS[hj] = rsqrtf(var + WHITE_EPS);
}

// ---------------------------------------------------------------------------
// K12: ga v3 — P whiten @ context + inline scrambled depthwise conv; writes
// VL once (no read-modify-write, vlocal kernel eliminated).
__global__ __launch_bounds__(256) void ga_fused(
    const __half* __restrict__ Pbuf, const float* __restrict__ MU,
    const float* __restrict__ RS, const __half* __restrict__ CTXg,
    const __half* __restrict__ V, const float* __restrict__ dwc_w,
    const float* __restrict__ dwc_b, const float* __restrict__ tm,
    __half* __restrict__ VL) {
  int bh = blockIdx.y;
  int b = bh >> 3, h = bh & 7;
  int n0 = blockIdx.x * 16;
  __shared__ __half Ps[16][130];
  __shared__ __align__(16) __half2 ctx2[128][32];
  __shared__ float musr[128][2];
  int tid = threadIdx.x;
  for (int e = tid; e < 2048; e += 256)
    Ps[e >> 7][e & 127] = Pbuf[((size_t)bh * 1024 + n0 + (e >> 7)) * 128 + (e & 127)];
  {
    const __half2* cg = (const __half2*)(CTXg + (size_t)bh * 8192);
    for (int e = tid; e < 4096; e += 256) ctx2[e >> 5][e & 31] = cg[e];
  }
  if (tid < 128) { musr[tid][0] = MU[h * 128 + tid]; musr[tid][1] = RS[h * 128 + tid]; }
  __syncthreads();
  int nn = tid >> 4, dq = tid & 15;
  float a0 = 0.f, a1 = 0.f, a2 = 0.f, a3 = 0.f;
#pragma unroll 4
  for (int j = 0; j < 128; ++j) {
    float pj = (h2f(Ps[nn][j]) - musr[j][0]) * musr[j][1];
    uint2 cc = *(const uint2*)&ctx2[j][dq * 2];
    __half2 c01 = __builtin_bit_cast(__half2, cc.x);
    __half2 c23 = __builtin_bit_cast(__half2, cc.y);
    a0 += pj * h2f(c01.x); a1 += pj * h2f(c01.y);
    a2 += pj * h2f(c23.x); a3 += pj * h2f(c23.y);
  }
  int t = n0 + nn;
  float tmv = tm[b * 1024 + t];
  float t2 = tmv * tmv;
  float acc[4] = {a0 * t2, a1 * t2, a2 * t2, a3 * t2};
  // inline vlocal for (t, c = h*64+dq*4+q)
#pragma unroll
  for (int q = 0; q < 4; ++q) {
    int c = h * 64 + dq * 4 + q;
    float vacc = dwc_b[c];
#pragma unroll
    for (int k = 0; k < 3; ++k) {
      int u = t - 1 + k;
      if (u >= 0 && u < 1024) {
        int n = 2 * c + (u >> 9), ch = u & 511;
        vacc += dwc_w[c * 3 + k] * h2f(V[(size_t)b * (Nn * Cc) + (size_t)n * 512 + ch]);
      }
    }
    acc[q] += vacc * tmv;
  }
  size_t base = (size_t)b * (Nn * Cc) + (size_t)t * 512 + h * 64 + dq * 4;
  VL[base] = f2h(acc[0]);
  VL[base + 1] = f2h(acc[1]);
  VL[base + 2] = f2h(acc[2]);
  VL[base + 3] = f2h(acc[3]);
}

// ---------------------------------------------------------------------------
// K13: proj via MFMA f16. M=2048, N=512, K=512.
__global__ __launch_bounds__(256) void proj_gemm(
    const __half* __restrict__ Ain, const float* __restrict__ w,
    const float* __restrict__ bias, const float* __restrict__ tm,
    float* __restrict__ out) {
  __shared__ _Float16 As[128 * 40];
  __shared__ _Float16 Bs[128 * 40];
  int m0 = blockIdx.x * 128, n0 = blockIdx.y * 128;
  int tid = threadIdx.x;
  int lane = tid & 63, wv = tid >> 6;
  int wm = (wv >> 1) * 64, wn = (wv & 1) * 64;
  int l15 = lane & 15, quad = lane >> 4;
  int srow = tid >> 1, shalf = tid & 1;
  float4v acc[4][4] = {};
  for (int k0 = 0; k0 < 512; k0 += 32) {
    __syncthreads();
    {
      const half8* ga = (const half8*)(Ain + (size_t)(m0 + srow) * 512 + k0 + shalf * 16);
      const float4* gb = (const float4*)(w + (size_t)(n0 + srow) * 512 + k0 + shalf * 16);
      half8 ha0 = ga[0], ha1 = ga[1];
      float4 b0 = gb[0], b1 = gb[1], b2 = gb[2], b3 = gb[3];
      half8 hb0 = {(_Float16)b0.x, (_Float16)b0.y, (_Float16)b0.z, (_Float16)b0.w,
                   (_Float16)b1.x, (_Float16)b1.y, (_Float16)b1.z, (_Float16)b1.w};
      half8 hb1 = {(_Float16)b2.x, (_Float16)b2.y, (_Float16)b2.z, (_Float16)b2.w,
                   (_Float16)b3.x, (_Float16)b3.y, (_Float16)b3.z, (_Float16)b3.w};
      int lo = srow * 40 + shalf * 16;
      *(half8*)&As[lo] = ha0;
      *(half8*)&As[lo + 8] = ha1;
      *(half8*)&Bs[lo] = hb0;
      *(half8*)&Bs[lo + 8] = hb1;
    }
    __syncthreads();
    half8 a[4], b[4];
#pragma unroll
    for (int mt = 0; mt < 4; ++mt)
      a[mt] = *(const half8*)&As[(wm + mt * 16 + l15) * 40 + quad * 8];
#pragma unroll
    for (int nt = 0; nt < 4; ++nt)
      b[nt] = *(const half8*)&Bs[(wn + nt * 16 + l15) * 40 + quad * 8];
#pragma unroll
    for (int mt = 0; mt < 4; ++mt)
#pragma unroll
      for (int nt = 0; nt < 4; ++nt)
        acc[mt][nt] =
            __builtin_amdgcn_mfma_f32_16x16x32_f16(a[mt], b[nt], acc[mt][nt], 0, 0, 0);
  }
#pragma unroll
  for (int mt = 0; mt < 4; ++mt) {
#pragma unroll
    for (int r = 0; r < 4; ++r) {
      int row = m0 + wm + mt * 16 + quad * 4 + r;
      int b_ = row >> 10, n_ = row & 1023;
      float t = tm[b_ * 1024 + n_];
#pragma unroll
      for (int nt = 0; nt < 4; ++nt) {
        int co = n0 + wn + nt * 16 + l15;
        out[(size_t)row * 512 + co] = (acc[mt][nt][r] + bias[co]) * t;
      }
    }
  }
}

// ---------------------------------------------------------------------------
// d_ws 11.26 MiB (proven). d_out (4 MiB): Wf f32 (NS) -> KTVp f32 partials
// (ktv->ctx) -> Pbuf f16 (stats->ga) -> final f32 output. Stream-ordered.
extern "C" void kernel_launch(void* const* d_in, const int* in_sizes, int n_in,
                              void* d_out, int out_size, void* d_ws, size_t ws_size,
                              hipStream_t stream) {
  const float* x      = (const float*)d_in[0];
  const float* tm     = (const float*)d_in[1];
  const float* qkv_w  = (const float*)d_in[2];
  const float* qkv_b  = (const float*)d_in[3];
  const float* proj_w = (const float*)d_in[4];
  const float* proj_b = (const float*)d_in[5];
  const float* dwc_w  = (const float*)d_in[6];
  const float* dwc_b  = (const float*)d_in[7];
  float* out = (float*)d_out;

  char* wsb = (char*)d_ws;
  __half* Qh  = (__half*)(wsb + 0);
  __half* Kh  = (__half*)(wsb + 2097152);
  __half* Vh  = (__half*)(wsb + 4194304);
  __half* VLh = (__half*)(wsb + 6291456);
  __half* QLh = (__half*)(wsb + 8388608);
  __half* KLh = (__half*)(wsb + 8650752);
  float*  LM  = (float*)(wsb + 8912896);
  float*  MU  = (float*)(wsb + 8913920);
  float*  RS  = (float*)(wsb + 8918016);
  __half* CTX = (__half*)(wsb + 9446400);
  float*  XA  = (float*)(wsb + 9708544);
  float*  XB  = (float*)(wsb + 10757120);
  float*  PS  = (float*)(wsb + 9708544);  // overlays XA+XB after ctx

  char* ob = (char*)d_out;
  float*  Wf   = (float*)ob;     // NS phase
  float*  KTVp = (float*)ob;     // ktv partials (4 MiB, after NS)
  __half* Pbuf = (__half*)ob;    // stats->ga phase

  qkv_gemm<<<dim3(16, 12), 256, 0, stream>>>(x, qkv_w, qkv_b, tm, Qh, Kh, Vh);
  pool_kernel<<<dim3(16, 16), 256, 0, stream>>>(Qh, Kh, tm, QLh, KLh, LM);
  wbuild_kernel<<<dim3(2, 16), 256, 0, stream>>>(QLh, KLh, LM, Wf);
  nsinit_kernel<<<16, 256, 0, stream>>>(Wf, XA);
  float* Xc = XA;
  float* Xn = XB;
  for (int it = 0; it < 5; ++it) {
    ns_iter<<<dim3(8, 16), 256, 0, stream>>>(Wf, Xc, Xn);
    float* tswap = Xc; Xc = Xn; Xn = tswap;
  }
  ktv_fused<<<dim3(4, 16, 8), 256, 0, stream>>>(Kh, QLh, LM, Vh, KTVp);
  ctx_kernel<<<dim3(8, 16), 256, 0, stream>>>(Xc, KTVp, CTX);
  stats_partial<<<dim3(64, 16), 256, 0, stream>>>(Qh, KLh, LM, tm, PS, Pbuf);
  stats_final<<<4, 256, 0, stream>>>(PS, tm, MU, RS);
  ga_fused<<<dim3(64, 16), 256, 0, stream>>>(Pbuf, MU, RS, CTX, Vh, dwc_w, dwc_b, tm, VLh);
  proj_gemm<<<dim3(16, 4), 256, 0, stream>>>(VLh, proj_w, proj_b, tm, out);
}

// Round 14
// 277.652 us; speedup vs baseline: 1.6606x; 1.5038x over previous
//
#include <hip/hip_runtime.h>
#include <hip/hip_bf16.h>
#include <hip/hip_fp16.h>

// B=2, N=1024, C=512, H=8, D=64, m=128, p=8
#define Hh 8
#define Bz 2
#define Nn 1024
#define Cc 512
#define Dd 64
#define Mm 128
#define NS_EPS 1e-4f
#define WHITE_EPS 1e-5f

__device__ __forceinline__ float h2f(__half v) { return __half2float(v); }
__device__ __forceinline__ __half f2h(float v) { return __float2half(v); }

typedef _Float16 half8 __attribute__((ext_vector_type(8)));
typedef float float4v __attribute__((ext_vector_type(4)));

// ---------------------------------------------------------------------------
// K1: QKV GEMM via MFMA f16. M=2048, N=1536, K=512. Block tile 128x128.
__global__ __launch_bounds__(256) void qkv_gemm(
    const float* __restrict__ x, const float* __restrict__ w,
    const float* __restrict__ bias, const float* __restrict__ tm,
    __half* __restrict__ Q, __half* __restrict__ K, __half* __restrict__ V) {
  __shared__ _Float16 As[128 * 40];
  __shared__ _Float16 Bs[128 * 40];
  int m0 = blockIdx.x * 128, n0 = blockIdx.y * 128;
  int tid = threadIdx.x;
  int lane = tid & 63, wv = tid >> 6;
  int wm = (wv >> 1) * 64, wn = (wv & 1) * 64;
  int l15 = lane & 15, quad = lane >> 4;
  int srow = tid >> 1, shalf = tid & 1;
  float4v acc[4][4] = {};
  for (int k0 = 0; k0 < 512; k0 += 32) {
    __syncthreads();
    {
      const float4* ga = (const float4*)(x + (size_t)(m0 + srow) * 512 + k0 + shalf * 16);
      const float4* gb = (const float4*)(w + (size_t)(n0 + srow) * 512 + k0 + shalf * 16);
      float4 a0 = ga[0], a1 = ga[1], a2 = ga[2], a3 = ga[3];
      float4 b0 = gb[0], b1 = gb[1], b2 = gb[2], b3 = gb[3];
      half8 ha0 = {(_Float16)a0.x, (_Float16)a0.y, (_Float16)a0.z, (_Float16)a0.w,
                   (_Float16)a1.x, (_Float16)a1.y, (_Float16)a1.z, (_Float16)a1.w};
      half8 ha1 = {(_Float16)a2.x, (_Float16)a2.y, (_Float16)a2.z, (_Float16)a2.w,
                   (_Float16)a3.x, (_Float16)a3.y, (_Float16)a3.z, (_Float16)a3.w};
      half8 hb0 = {(_Float16)b0.x, (_Float16)b0.y, (_Float16)b0.z, (_Float16)b0.w,
                   (_Float16)b1.x, (_Float16)b1.y, (_Float16)b1.z, (_Float16)b1.w};
      half8 hb1 = {(_Float16)b2.x, (_Float16)b2.y, (_Float16)b2.z, (_Float16)b2.w,
                   (_Float16)b3.x, (_Float16)b3.y, (_Float16)b3.z, (_Float16)b3.w};
      int lo = srow * 40 + shalf * 16;
      *(half8*)&As[lo] = ha0;
      *(half8*)&As[lo + 8] = ha1;
      *(half8*)&Bs[lo] = hb0;
      *(half8*)&Bs[lo + 8] = hb1;
    }
    __syncthreads();
    half8 a[4], b[4];
#pragma unroll
    for (int mt = 0; mt < 4; ++mt)
      a[mt] = *(const half8*)&As[(wm + mt * 16 + l15) * 40 + quad * 8];
#pragma unroll
    for (int nt = 0; nt < 4; ++nt)
      b[nt] = *(const half8*)&Bs[(wn + nt * 16 + l15) * 40 + quad * 8];
#pragma unroll
    for (int mt = 0; mt < 4; ++mt)
#pragma unroll
      for (int nt = 0; nt < 4; ++nt)
        acc[mt][nt] =
            __builtin_amdgcn_mfma_f32_16x16x32_f16(a[mt], b[nt], acc[mt][nt], 0, 0, 0);
  }
#pragma unroll
  for (int mt = 0; mt < 4; ++mt) {
#pragma unroll
    for (int r = 0; r < 4; ++r) {
      int row = m0 + wm + mt * 16 + quad * 4 + r;
      int b_ = row >> 10, n_ = row & 1023;
      float t = tm[b_ * 1024 + n_];
#pragma unroll
      for (int nt = 0; nt < 4; ++nt) {
        int c3 = n0 + wn + nt * 16 + l15;
        float v = (acc[mt][nt][r] + bias[c3]) * t;
        int sec = c3 >> 9, ch = c3 & 511;
        __half* dst = (sec == 0) ? Q : (sec == 1 ? K : V);
        dst[(size_t)b_ * (Nn * Cc) + (size_t)n_ * 512 + ch] = f2h(v);
      }
    }
  }
}

// ---------------------------------------------------------------------------
// K2: pool — block per (b,h,u-tile of 64). Coalesced row staging.
__global__ __launch_bounds__(256) void pool_kernel(
    const __half* __restrict__ Q, const __half* __restrict__ K,
    const float* __restrict__ tm, __half* __restrict__ QL,
    __half* __restrict__ KL, float* __restrict__ LM) {
  int ut = blockIdx.x;
  int bh = blockIdx.y;
  int b = bh >> 3, h = bh & 7;
  int u0 = ut * 64;
  int delta = u0 >> 9;
  int ch0 = u0 & 511;
  __shared__ float Qs[64][65];
  __shared__ float Ks[64][65];
  int tid = threadIdx.x;
  for (int e = tid; e < 4096; e += 256) {
    int d = e >> 6, uu = e & 63;
    int row = 2 * (h * 64 + d) + delta;
    size_t gi = (size_t)b * (Nn * Cc) + (size_t)row * 512 + ch0 + uu;
    Qs[d][uu] = h2f(Q[gi]);
    Ks[d][uu] = h2f(K[gi]);
  }
  __syncthreads();
  int d = tid & 63, s = tid >> 6;
#pragma unroll
  for (int jr = 0; jr < 2; ++jr) {
    int jl = s + 4 * jr;
    int j = ut * 8 + jl;
    float pm = 0.f, sq = 0.f, sk = 0.f;
#pragma unroll
    for (int i = 0; i < 8; ++i) {
      float t = tm[b * 1024 + 8 * j + i];
      pm += t;
      sq += Qs[d][8 * jl + i] * t;
      sk += Ks[d][8 * jl + i] * t;
    }
    pm *= 0.125f;
    float pms = fmaxf(pm, 1e-6f);
    size_t oi = ((size_t)bh * 128 + j) * 64 + d;
    QL[oi] = f2h(sq * 0.125f / pms);
    KL[oi] = f2h(sk * 0.125f / pms);
    if (h == 0 && d == 0) LM[b * 128 + j] = (pm > 0.f) ? 1.f : 0.f;
  }
}

// ---------------------------------------------------------------------------
// K3: W_eps[b,h,i,j] (f32, lives in d_out during NS)
__global__ __launch_bounds__(256) void wbuild_kernel(
    const __half* __restrict__ QL, const __half* __restrict__ KL,
    const float* __restrict__ LM, float* __restrict__ W) {
  int bh = blockIdx.y;
  int b = bh >> 3;
  int i0 = blockIdx.x * 64;
  __shared__ float ks[128][65];
  __shared__ float qs[64][65];
  int tid = threadIdx.x;
  const __half* klb = KL + (size_t)bh * (Mm * Dd);
  const __half* qlb = QL + (size_t)bh * (Mm * Dd);
  for (int e = tid; e < 128 * 64; e += 256) ks[e >> 6][e & 63] = h2f(klb[e]);
  for (int e = tid; e < 64 * 64; e += 256) qs[e >> 6][e & 63] = h2f(qlb[i0 * 64 + e]);
  __syncthreads();
  for (int e = tid; e < 64 * 128; e += 256) {
    int il = e >> 7, j = e & 127;
    int i = i0 + il;
    float s = 0.f;
#pragma unroll
    for (int d = 0; d < 64; ++d) s += fabsf(qs[il][d] - ks[j][d]);
    float wv = expf(-s * 0.25f);
    float pr = LM[b * Mm + i] * LM[b * Mm + j];
    float diag = (i == j) ? 1.f : 0.f;
    wv = wv * pr + diag * (1.f - pr) + diag * NS_EPS;
    W[(size_t)bh * (Mm * Mm) + i * 128 + j] = wv;
  }
}

// ---------------------------------------------------------------------------
// K4: ns_solve — entire Newton-Schulz in one launch. One block per bh.
// All state in LDS: Ws (W f16), Xa (X[i][k]), Xb (X^T[j][k]), Tt (T^T[j][k]).
// X0 = 2/(fro+1e-8) * W^T; 5x { T = 2I - W@X; X = X@T } via MFMA f16.
__global__ __launch_bounds__(256) void ns_solve(const float* __restrict__ Wg,
                                                float* __restrict__ Xout) {
  int bh = blockIdx.x;
  __shared__ _Float16 Ws[128 * 136];
  __shared__ _Float16 Xa[128 * 136];
  __shared__ _Float16 Xb[128 * 136];
  __shared__ _Float16 Tt[128 * 136];
  __shared__ float red[256];
  int tid = threadIdx.x;
  const float* Wb = Wg + (size_t)bh * 16384;
  float fro = 0.f;
  for (int e = tid; e < 16384; e += 256) {
    float wv = Wb[e];
    Ws[(e >> 7) * 136 + (e & 127)] = (_Float16)wv;
    fro += wv * wv;
  }
  red[tid] = fro;
  __syncthreads();
  for (int off = 128; off > 0; off >>= 1) {
    if (tid < off) red[tid] += red[tid + off];
    __syncthreads();
  }
  float scale = 2.f / (sqrtf(red[0]) + 1e-8f);
  // X0 = scale * W^T : Xa[i][k] = scale*W[k][i], Xb[j][k] = scale*W[j][k]
  for (int e = tid; e < 16384; e += 256) {
    int i = e >> 7, k = e & 127;
    Xa[i * 136 + k] = (_Float16)(scale * (float)Ws[k * 136 + i]);
    Xb[i * 136 + k] = (_Float16)(scale * (float)Ws[i * 136 + k]);
  }
  __syncthreads();
  int lane = tid & 63, wv_ = tid >> 6;
  int wm = (wv_ >> 1) * 64, wn = (wv_ & 1) * 64;
  int l15 = lane & 15, quad = lane >> 4;
  for (int it = 0; it < 5; ++it) {
    // mm1: T = 2I - Ws @ X   (A = Ws[i][k], B = Xb[j][k]); Tt[j][i] = T[i][j]
    {
      float4v acc[4][4] = {};
#pragma unroll
      for (int kt = 0; kt < 4; ++kt) {
        half8 a[4], b[4];
#pragma unroll
        for (int mt = 0; mt < 4; ++mt)
          a[mt] = *(const half8*)&Ws[(wm + mt * 16 + l15) * 136 + kt * 32 + quad * 8];
#pragma unroll
        for (int nt = 0; nt < 4; ++nt)
          b[nt] = *(const half8*)&Xb[(wn + nt * 16 + l15) * 136 + kt * 32 + quad * 8];
#pragma unroll
        for (int mt = 0; mt < 4; ++mt)
#pragma unroll
          for (int nt = 0; nt < 4; ++nt)
            acc[mt][nt] =
                __builtin_amdgcn_mfma_f32_16x16x32_f16(a[mt], b[nt], acc[mt][nt], 0, 0, 0);
      }
#pragma unroll
      for (int mt = 0; mt < 4; ++mt)
#pragma unroll
        for (int r = 0; r < 4; ++r) {
          int i = wm + mt * 16 + quad * 4 + r;
#pragma unroll
          for (int nt = 0; nt < 4; ++nt) {
            int j = wn + nt * 16 + l15;
            Tt[j * 136 + i] = (_Float16)(((i == j) ? 2.f : 0.f) - acc[mt][nt][r]);
          }
        }
    }
    __syncthreads();  // Tt complete before mm2 reads
    // mm2: Xn = Xa @ T   (A = Xa[i][k], B = Tt[j][k])
    {
      float4v acc[4][4] = {};
#pragma unroll
      for (int kt = 0; kt < 4; ++kt) {
        half8 a[4], b[4];
#pragma unroll
        for (int mt = 0; mt < 4; ++mt)
          a[mt] = *(const half8*)&Xa[(wm + mt * 16 + l15) * 136 + kt * 32 + quad * 8];
#pragma unroll
        for (int nt = 0; nt < 4; ++nt)
          b[nt] = *(const half8*)&Tt[(wn + nt * 16 + l15) * 136 + kt * 32 + quad * 8];
#pragma unroll
        for (int mt = 0; mt < 4; ++mt)
#pragma unroll
          for (int nt = 0; nt < 4; ++nt)
            acc[mt][nt] =
                __builtin_amdgcn_mfma_f32_16x16x32_f16(a[mt], b[nt], acc[mt][nt], 0, 0, 0);
      }
      __syncthreads();  // all mm2 reads of Xa done before overwrite
#pragma unroll
      for (int mt = 0; mt < 4; ++mt)
#pragma unroll
        for (int r = 0; r < 4; ++r) {
          int i = wm + mt * 16 + quad * 4 + r;
#pragma unroll
          for (int nt = 0; nt < 4; ++nt) {
            int j = wn + nt * 16 + l15;
            _Float16 v = (_Float16)acc[mt][nt][r];
            Xa[i * 136 + j] = v;
            Xb[j * 136 + i] = v;
          }
        }
    }
    __syncthreads();  // Xa/Xb updated before next iteration reads
  }
  for (int e = tid; e < 16384; e += 256)
    Xout[(size_t)bh * 16384 + e] = (float)Xa[(e >> 7) * 136 + (e & 127)];
}

// ---------------------------------------------------------------------------
// K7: ktv — fused C_k + K^T V. Non-atomic partials to KTVp[nc][bh][j][d].
__global__ __launch_bounds__(256) void ktv_fused(
    const __half* __restrict__ K, const __half* __restrict__ QL,
    const float* __restrict__ LM, const __half* __restrict__ V,
    float* __restrict__ KTVp) {
  int jt = blockIdx.x;   // 4 (32 j each)
  int bh = blockIdx.y;   // 16
  int nc = blockIdx.z;   // 8 (128 n each)
  int b = bh >> 3, h = bh & 7;
  int j0 = jt * 32;
  __shared__ __align__(16) float qls[32 * 68];
  __shared__ __align__(16) float Ks[32 * 68];
  __shared__ __align__(16) float Vs[32 * 68];
  __shared__ float P[32 * 36];
  int tid = threadIdx.x;
  int sr = tid >> 3, sd8 = (tid & 7) * 8;
  {
    half8 q = *(const half8*)(QL + (size_t)bh * 8192 + (size_t)(j0 + sr) * 64 + sd8);
    float4 f0 = {(float)q[0], (float)q[1], (float)q[2], (float)q[3]};
    float4 f1 = {(float)q[4], (float)q[5], (float)q[6], (float)q[7]};
    *(float4*)&qls[sr * 68 + sd8] = f0;
    *(float4*)&qls[sr * 68 + sd8 + 4] = f1;
  }
  int jq = tid & 15, nq = tid >> 4;
  int dq2 = tid & 7, jl = tid >> 3;
  float acc[8] = {};
  for (int nt = 0; nt < 4; ++nt) {
    int n0 = nc * 128 + nt * 32;
    __syncthreads();
    {
      size_t gi = (size_t)b * (Nn * Cc) + (size_t)(n0 + sr) * 512 + h * 64 + sd8;
      half8 kv = *(const half8*)(K + gi);
      half8 vv = *(const half8*)(V + gi);
      float4 k0 = {(float)kv[0], (float)kv[1], (float)kv[2], (float)kv[3]};
      float4 k1 = {(float)kv[4], (float)kv[5], (float)kv[6], (float)kv[7]};
      float4 v0 = {(float)vv[0], (float)vv[1], (float)vv[2], (float)vv[3]};
      float4 v1 = {(float)vv[4], (float)vv[5], (float)vv[6], (float)vv[7]};
      *(float4*)&Ks[sr * 68 + sd8] = k0;
      *(float4*)&Ks[sr * 68 + sd8 + 4] = k1;
      *(float4*)&Vs[sr * 68 + sd8] = v0;
      *(float4*)&Vs[sr * 68 + sd8 + 4] = v1;
    }
    __syncthreads();
    {
      const float4* q0p = (const float4*)&qls[(jq * 2) * 68];
      const float4* q1p = (const float4*)&qls[(jq * 2 + 1) * 68];
      const float4* k0p = (const float4*)&Ks[(nq * 2) * 68];
      const float4* k1p = (const float4*)&Ks[(nq * 2 + 1) * 68];
      float s00 = 0.f, s01 = 0.f, s10 = 0.f, s11 = 0.f;
#pragma unroll
      for (int i = 0; i < 16; ++i) {
        int dq = (i + tid) & 15;
        float4 q0 = q0p[dq], q1 = q1p[dq];
        float4 k0 = k0p[dq], k1 = k1p[dq];
        s00 += fabsf(q0.x - k0.x) + fabsf(q0.y - k0.y) + fabsf(q0.z - k0.z) + fabsf(q0.w - k0.w);
        s01 += fabsf(q0.x - k1.x) + fabsf(q0.y - k1.y) + fabsf(q0.z - k1.z) + fabsf(q0.w - k1.w);
        s10 += fabsf(q1.x - k0.x) + fabsf(q1.y - k0.y) + fabsf(q1.z - k0.z) + fabsf(q1.w - k0.w);
        s11 += fabsf(q1.x - k1.x) + fabsf(q1.y - k1.y) + fabsf(q1.z - k1.z) + fabsf(q1.w - k1.w);
      }
      P[(nq * 2) * 36 + jq * 2] = expf(-s00 * 0.25f);
      P[(nq * 2) * 36 + jq * 2 + 1] = expf(-s10 * 0.25f);
      P[(nq * 2 + 1) * 36 + jq * 2] = expf(-s01 * 0.25f);
      P[(nq * 2 + 1) * 36 + jq * 2 + 1] = expf(-s11 * 0.25f);
    }
    __syncthreads();
    {
#pragma unroll 4
      for (int n = 0; n < 32; ++n) {
        float p = P[n * 36 + jl];
        float4 v0 = *(const float4*)&Vs[n * 68 + dq2 * 8];
        float4 v1 = *(const float4*)&Vs[n * 68 + dq2 * 8 + 4];
        acc[0] += p * v0.x; acc[1] += p * v0.y; acc[2] += p * v0.z; acc[3] += p * v0.w;
        acc[4] += p * v1.x; acc[5] += p * v1.y; acc[6] += p * v1.z; acc[7] += p * v1.w;
      }
    }
  }
  {
    float lm = LM[b * 128 + j0 + jl];
    float* dst = &KTVp[((size_t)nc * 16 + bh) * 8192 + (size_t)(j0 + jl) * 64 + dq2 * 8];
    float4 o0 = {acc[0] * lm, acc[1] * lm, acc[2] * lm, acc[3] * lm};
    float4 o1 = {acc[4] * lm, acc[5] * lm, acc[6] * lm, acc[7] * lm};
    *(float4*)dst = o0;
    *(float4*)(dst + 4) = o1;
  }
}

// ---------------------------------------------------------------------------
// K8: ctx v2 — fused nc-reduction of KTVp (LDS) + CTX = X @ KTV.
__global__ __launch_bounds__(256) void ctx_kernel(const float* __restrict__ X,
                                                  const float* __restrict__ KTVp,
                                                  __half* __restrict__ CTX) {
  int it = blockIdx.x;  // 0..7
  int bh = blockIdx.y;  // 16
  int i0 = it * 16;
  __shared__ __align__(16) float KTVs[8192];
  __shared__ float Xs[16][132];
  int tid = threadIdx.x;
  const float4* src = (const float4*)KTVp;
  for (int e = tid; e < 2048; e += 256) {
    float4 s = src[(size_t)bh * 2048 + e];
#pragma unroll
    for (int nc = 1; nc < 8; ++nc) {
      float4 v = src[((size_t)nc * 16 + bh) * 2048 + e];
      s.x += v.x; s.y += v.y; s.z += v.z; s.w += v.w;
    }
    *(float4*)&KTVs[e * 4] = s;
  }
  for (int e = tid; e < 2048; e += 256)
    Xs[e >> 7][e & 127] = X[(size_t)bh * 16384 + (size_t)(i0 + (e >> 7)) * 128 + (e & 127)];
  __syncthreads();
  int il = tid >> 4, dg = tid & 15;
  float a0 = 0.f, a1 = 0.f, a2 = 0.f, a3 = 0.f;
#pragma unroll 4
  for (int j = 0; j < 128; ++j) {
    float xv = Xs[il][j];
    float4 kv = *(const float4*)&KTVs[j * 64 + dg * 4];
    a0 += xv * kv.x; a1 += xv * kv.y; a2 += xv * kv.z; a3 += xv * kv.w;
  }
  size_t ob = (size_t)bh * 8192 + (size_t)(i0 + il) * 64 + dg * 4;
  CTX[ob] = f2h(a0);
  CTX[ob + 1] = f2h(a1);
  CTX[ob + 2] = f2h(a2);
  CTX[ob + 3] = f2h(a3);
}

// ---------------------------------------------------------------------------
// K9: stats_partial v3 — float4 LDS reads, 2j x 4n register tile.
__global__ __launch_bounds__(256) void stats_partial(
    const __half* __restrict__ Q, const __half* __restrict__ KL,
    const float* __restrict__ LM, const float* __restrict__ tm,
    float* __restrict__ PS, __half* __restrict__ Pbuf) {
  int nt = blockIdx.x;   // 64
  int bh = blockIdx.y;   // 16
  int b = bh >> 3, h = bh & 7;
  int n0 = nt * 16;
  __shared__ __align__(16) float kls[128 * 68];
  __shared__ __align__(16) float qs[16 * 68];
  __shared__ __half ps[16 * 132];
  __shared__ float part[128 * 12];
  int tid = threadIdx.x;
  for (int e = tid; e < 8192; e += 256)
    kls[(e >> 6) * 68 + (e & 63)] = h2f(KL[(size_t)bh * 8192 + e]);
  for (int e = tid; e < 1024; e += 256)
    qs[(e >> 6) * 68 + (e & 63)] =
        h2f(Q[(size_t)b * (Nn * Cc) + (size_t)(n0 + (e >> 6)) * 512 + h * 64 + (e & 63)]);
  __syncthreads();
  int jg = tid & 63, ng = tid >> 6;
  int j = jg * 2;
  const float4* kA = (const float4*)&kls[j * 68];
  const float4* kB = (const float4*)&kls[(j + 1) * 68];
  float sA[4] = {}, sB[4] = {};
#pragma unroll
  for (int i = 0; i < 16; ++i) {
    int dq = (i + jg) & 15;
    float4 ka = kA[dq];
    float4 kb = kB[dq];
#pragma unroll
    for (int r = 0; r < 4; ++r) {
      float4 qv = *(const float4*)&qs[(ng * 4 + r) * 68 + dq * 4];
      sA[r] += fabsf(qv.x - ka.x) + fabsf(qv.y - ka.y) + fabsf(qv.z - ka.z) + fabsf(qv.w - ka.w);
      sB[r] += fabsf(qv.x - kb.x) + fabsf(qv.y - kb.y) + fabsf(qv.z - kb.z) + fabsf(qv.w - kb.w);
    }
  }
  float lmA = LM[b * 128 + j], lmB = LM[b * 128 + j + 1];
  float a1 = 0.f, a2 = 0.f, a3 = 0.f, b1 = 0.f, b2 = 0.f, b3 = 0.f;
#pragma unroll
  for (int r = 0; r < 4; ++r) {
    int nn = ng * 4 + r;
    float t = tm[b * 1024 + n0 + nn];
    float xa = expf(-sA[r] * 0.25f) * lmA;
    float xb = expf(-sB[r] * 0.25f) * lmB;
    ps[nn * 132 + j] = f2h(xa);
    ps[nn * 132 + j + 1] = f2h(xb);
    float xta = xa * t, xtb = xb * t;
    a1 += xta; a2 += xta * xta; a3 += xta * t;
    b1 += xtb; b2 += xtb * xtb; b3 += xtb * t;
  }
  part[j * 12 + ng * 3 + 0] = a1;
  part[j * 12 + ng * 3 + 1] = a2;
  part[j * 12 + ng * 3 + 2] = a3;
  part[(j + 1) * 12 + ng * 3 + 0] = b1;
  part[(j + 1) * 12 + ng * 3 + 1] = b2;
  part[(j + 1) * 12 + ng * 3 + 2] = b3;
  __syncthreads();
  for (int e = tid; e < 2048; e += 256)
    Pbuf[((size_t)bh * 1024 + n0 + (e >> 7)) * 128 + (e & 127)] =
        ps[(e >> 7) * 132 + (e & 127)];
  if (tid < 128) {
    float s1 = part[tid * 12 + 0] + part[tid * 12 + 3] + part[tid * 12 + 6] + part[tid * 12 + 9];
    float s2 = part[tid * 12 + 1] + part[tid * 12 + 4] + part[tid * 12 + 7] + part[tid * 12 + 10];
    float s3 = part[tid * 12 + 2] + part[tid * 12 + 5] + part[tid * 12 + 8] + part[tid * 12 + 11];
    size_t base = ((size_t)(b * 64 + nt) * 8 + h) * 384 + tid * 3;
    PS[base] = s1; PS[base + 1] = s2; PS[base + 2] = s3;
  }
}

// ---------------------------------------------------------------------------
// K10: stats_final — reduce PS over 128 (b,nt) tiles per (h,j).
__global__ __launch_bounds__(256) void stats_final(const float* __restrict__ PS,
                                                   const float* __restrict__ tm,
                                                   float* __restrict__ MU,
                                                   float* __restrict__ RS) {
  __shared__ float red[256][2];
  __shared__ float ts0, ts1;
  int tid = threadIdx.x;
  float a = 0.f, c = 0.f;
  for (int i = tid; i < 2048; i += 256) { float t = tm[i]; a += t; c += t * t; }
  red[tid][0] = a; red[tid][1] = c;
  __syncthreads();
  for (int off = 128; off > 0; off >>= 1) {
    if (tid < off) { red[tid][0] += red[tid + off][0]; red[tid][1] += red[tid + off][1]; }
    __syncthreads();
  }
  if (tid == 0) { ts0 = red[0][0]; ts1 = red[0][1]; }
  __syncthreads();
  int hj = blockIdx.x * 256 + tid;
  int h = hj >> 7, j = hj & 127;
  float s1 = 0.f, s2 = 0.f, s3 = 0.f;
  for (int bnt = 0; bnt < 128; ++bnt) {
    const float* p = PS + ((size_t)bnt * 8 + h) * 384 + j * 3;
    s1 += p[0]; s2 += p[1]; s3 += p[2];
  }
  float valid = fmaxf(ts0, 1.f);
  float mu = s1 / valid;
  float var = (s2 - 2.f * mu * s3 + mu * mu * ts1) / valid;
  var = fmaxf(var, 0.f);
  MU[hj] = mu;
  RS[hj] = rsqrtf(var + WHITE_EPS);
}

// ---------------------------------------------------------------------------
// K12: ga v3 — P whiten @ context + inline scrambled depthwise conv; writes
// VL once.
__global__ __launch_bounds__(256) void ga_fused(
    const __half* __restrict__ Pbuf, const float* __restrict__ MU,
    const float* __restrict__ RS, const __half* __restrict__ CTXg,
    const __half* __restrict__ V, const float* __restrict__ dwc_w,
    const float* __restrict__ dwc_b, const float* __restrict__ tm,
    __half* __restrict__ VL) {
  int bh = blockIdx.y;
  int b = bh >> 3, h = bh & 7;
  int n0 = blockIdx.x * 16;
  __shared__ __half Ps[16][130];
  __shared__ __align__(16) __half2 ctx2[128][32];
  __shared__ float musr[128][2];
  int tid = threadIdx.x;
  for (int e = tid; e < 2048; e += 256)
    Ps[e >> 7][e & 127] = Pbuf[((size_t)bh * 1024 + n0 + (e >> 7)) * 128 + (e & 127)];
  {
    const __half2* cg = (const __half2*)(CTXg + (size_t)bh * 8192);
    for (int e = tid; e < 4096; e += 256) ctx2[e >> 5][e & 31] = cg[e];
  }
  if (tid < 128) { musr[tid][0] = MU[h * 128 + tid]; musr[tid][1] = RS[h * 128 + tid]; }
  __syncthreads();
  int nn = tid >> 4, dq = tid & 15;
  float a0 = 0.f, a1 = 0.f, a2 = 0.f, a3 = 0.f;
#pragma unroll 4
  for (int j = 0; j < 128; ++j) {
    float pj = (h2f(Ps[nn][j]) - musr[j][0]) * musr[j][1];
    uint2 cc = *(const uint2*)&ctx2[j][dq * 2];
    __half2 c01 = __builtin_bit_cast(__half2, cc.x);
    __half2 c23 = __builtin_bit_cast(__half2, cc.y);
    a0 += pj * h2f(c01.x); a1 += pj * h2f(c01.y);
    a2 += pj * h2f(c23.x); a3 += pj * h2f(c23.y);
  }
  int t = n0 + nn;
  float tmv = tm[b * 1024 + t];
  float t2 = tmv * tmv;
  float acc[4] = {a0 * t2, a1 * t2, a2 * t2, a3 * t2};
#pragma unroll
  for (int q = 0; q < 4; ++q) {
    int c = h * 64 + dq * 4 + q;
    float vacc = dwc_b[c];
#pragma unroll
    for (int k = 0; k < 3; ++k) {
      int u = t - 1 + k;
      if (u >= 0 && u < 1024) {
        int n = 2 * c + (u >> 9), ch = u & 511;
        vacc += dwc_w[c * 3 + k] * h2f(V[(size_t)b * (Nn * Cc) + (size_t)n * 512 + ch]);
      }
    }
    acc[q] += vacc * tmv;
  }
  size_t base = (size_t)b * (Nn * Cc) + (size_t)t * 512 + h * 64 + dq * 4;
  VL[base] = f2h(acc[0]);
  VL[base + 1] = f2h(acc[1]);
  VL[base + 2] = f2h(acc[2]);
  VL[base + 3] = f2h(acc[3]);
}

// ---------------------------------------------------------------------------
// K13: proj via MFMA f16. M=2048, N=512, K=512.
__global__ __launch_bounds__(256) void proj_gemm(
    const __half* __restrict__ Ain, const float* __restrict__ w,
    const float* __restrict__ bias, const float* __restrict__ tm,
    float* __restrict__ out) {
  __shared__ _Float16 As[128 * 40];
  __shared__ _Float16 Bs[128 * 40];
  int m0 = blockIdx.x * 128, n0 = blockIdx.y * 128;
  int tid = threadIdx.x;
  int lane = tid & 63, wv = tid >> 6;
  int wm = (wv >> 1) * 64, wn = (wv & 1) * 64;
  int l15 = lane & 15, quad = lane >> 4;
  int srow = tid >> 1, shalf = tid & 1;
  float4v acc[4][4] = {};
  for (int k0 = 0; k0 < 512; k0 += 32) {
    __syncthreads();
    {
      const half8* ga = (const half8*)(Ain + (size_t)(m0 + srow) * 512 + k0 + shalf * 16);
      const float4* gb = (const float4*)(w + (size_t)(n0 + srow) * 512 + k0 + shalf * 16);
      half8 ha0 = ga[0], ha1 = ga[1];
      float4 b0 = gb[0], b1 = gb[1], b2 = gb[2], b3 = gb[3];
      half8 hb0 = {(_Float16)b0.x, (_Float16)b0.y, (_Float16)b0.z, (_Float16)b0.w,
                   (_Float16)b1.x, (_Float16)b1.y, (_Float16)b1.z, (_Float16)b1.w};
      half8 hb1 = {(_Float16)b2.x, (_Float16)b2.y, (_Float16)b2.z, (_Float16)b2.w,
                   (_Float16)b3.x, (_Float16)b3.y, (_Float16)b3.z, (_Float16)b3.w};
      int lo = srow * 40 + shalf * 16;
      *(half8*)&As[lo] = ha0;
      *(half8*)&As[lo + 8] = ha1;
      *(half8*)&Bs[lo] = hb0;
      *(half8*)&Bs[lo + 8] = hb1;
    }
    __syncthreads();
    half8 a[4], b[4];
#pragma unroll
    for (int mt = 0; mt < 4; ++mt)
      a[mt] = *(const half8*)&As[(wm + mt * 16 + l15) * 40 + quad * 8];
#pragma unroll
    for (int nt = 0; nt < 4; ++nt)
      b[nt] = *(const half8*)&Bs[(wn + nt * 16 + l15) * 40 + quad * 8];
#pragma unroll
    for (int mt = 0; mt < 4; ++mt)
#pragma unroll
      for (int nt = 0; nt < 4; ++nt)
        acc[mt][nt] =
            __builtin_amdgcn_mfma_f32_16x16x32_f16(a[mt], b[nt], acc[mt][nt], 0, 0, 0);
  }
#pragma unroll
  for (int mt = 0; mt < 4; ++mt) {
#pragma unroll
    for (int r = 0; r < 4; ++r) {
      int row = m0 + wm + mt * 16 + quad * 4 + r;
      int b_ = row >> 10, n_ = row & 1023;
      float t = tm[b_ * 1024 + n_];
#pragma unroll
      for (int nt = 0; nt < 4; ++nt) {
        int co = n0 + wn + nt * 16 + l15;
        out[(size_t)row * 512 + co] = (acc[mt][nt][r] + bias[co]) * t;
      }
    }
  }
}

// ---------------------------------------------------------------------------
// d_ws 11.26 MiB (proven). d_out (4 MiB): Wf f32 (NS) -> KTVp f32 partials
// (ktv->ctx) -> Pbuf f16 (stats->ga) -> final f32 output. Stream-ordered.
extern "C" void kernel_launch(void* const* d_in, const int* in_sizes, int n_in,
                              void* d_out, int out_size, void* d_ws, size_t ws_size,
                              hipStream_t stream) {
  const float* x      = (const float*)d_in[0];
  const float* tm     = (const float*)d_in[1];
  const float* qkv_w  = (const float*)d_in[2];
  const float* qkv_b  = (const float*)d_in[3];
  const float* proj_w = (const float*)d_in[4];
  const float* proj_b = (const float*)d_in[5];
  const float* dwc_w  = (const float*)d_in[6];
  const float* dwc_b  = (const float*)d_in[7];
  float* out = (float*)d_out;

  char* wsb = (char*)d_ws;
  __half* Qh  = (__half*)(wsb + 0);
  __half* Kh  = (__half*)(wsb + 2097152);
  __half* Vh  = (__half*)(wsb + 4194304);
  __half* VLh = (__half*)(wsb + 6291456);
  __half* QLh = (__half*)(wsb + 8388608);
  __half* KLh = (__half*)(wsb + 8650752);
  float*  LM  = (float*)(wsb + 8912896);
  float*  MU  = (float*)(wsb + 8913920);
  float*  RS  = (float*)(wsb + 8918016);
  __half* CTX = (__half*)(wsb + 9446400);
  float*  XA  = (float*)(wsb + 9708544);
  float*  PS  = (float*)(wsb + 9708544 + 1048576);  // after XA (XB slot reused)

  char* ob = (char*)d_out;
  float*  Wf   = (float*)ob;     // NS phase
  float*  KTVp = (float*)ob;     // ktv partials (4 MiB, after NS)
  __half* Pbuf = (__half*)ob;    // stats->ga phase

  qkv_gemm<<<dim3(16, 12), 256, 0, stream>>>(x, qkv_w, qkv_b, tm, Qh, Kh, Vh);
  pool_kernel<<<dim3(16, 16), 256, 0, stream>>>(Qh, Kh, tm, QLh, KLh, LM);
  wbuild_kernel<<<dim3(2, 16), 256, 0, stream>>>(QLh, KLh, LM, Wf);
  ns_solve<<<16, 256, 0, stream>>>(Wf, XA);
  ktv_fused<<<dim3(4, 16, 8), 256, 0, stream>>>(Kh, QLh, LM, Vh, KTVp);
  ctx_kernel<<<dim3(8, 16), 256, 0, stream>>>(XA, KTVp, CTX);
  stats_partial<<<dim3(64, 16), 256, 0, stream>>>(Qh, KLh, LM, tm, PS, Pbuf);
  stats_final<<<4, 256, 0, stream>>>(PS, tm, MU, RS);
  ga_fused<<<dim3(64, 16), 256, 0, stream>>>(Pbuf, MU, RS, CTX, Vh, dwc_w, dwc_b, tm, VLh);
  proj_gemm<<<dim3(16, 4), 256, 0, stream>>>(VLh, proj_w, proj_b, tm, out);
}

// Round 15
// 249.370 us; speedup vs baseline: 1.8489x; 1.1134x over previous
//
#include <hip/hip_runtime.h>
#include <hip/hip_bf16.h>
#include <hip/hip_fp16.h>

// B=2, N=1024, C=512, H=8, D=64, m=128, p=8
#define Hh 8
#define Bz 2
#define Nn 1024
#define Cc 512
#define Dd 64
#define Mm 128
#define NS_EPS 1e-4f
#define WHITE_EPS 1e-5f

__device__ __forceinline__ float h2f(__half v) { return __half2float(v); }
__device__ __forceinline__ __half f2h(float v) { return __float2half(v); }

typedef _Float16 half8 __attribute__((ext_vector_type(8)));
typedef float float4v __attribute__((ext_vector_type(4)));

// ---------------------------------------------------------------------------
// K1: QKV GEMM via MFMA f16. M=2048, N=1536, K=512. Block tile 128x128.
__global__ __launch_bounds__(256) void qkv_gemm(
    const float* __restrict__ x, const float* __restrict__ w,
    const float* __restrict__ bias, const float* __restrict__ tm,
    __half* __restrict__ Q, __half* __restrict__ K, __half* __restrict__ V) {
  __shared__ _Float16 As[128 * 40];
  __shared__ _Float16 Bs[128 * 40];
  int m0 = blockIdx.x * 128, n0 = blockIdx.y * 128;
  int tid = threadIdx.x;
  int lane = tid & 63, wv = tid >> 6;
  int wm = (wv >> 1) * 64, wn = (wv & 1) * 64;
  int l15 = lane & 15, quad = lane >> 4;
  int srow = tid >> 1, shalf = tid & 1;
  float4v acc[4][4] = {};
  for (int k0 = 0; k0 < 512; k0 += 32) {
    __syncthreads();
    {
      const float4* ga = (const float4*)(x + (size_t)(m0 + srow) * 512 + k0 + shalf * 16);
      const float4* gb = (const float4*)(w + (size_t)(n0 + srow) * 512 + k0 + shalf * 16);
      float4 a0 = ga[0], a1 = ga[1], a2 = ga[2], a3 = ga[3];
      float4 b0 = gb[0], b1 = gb[1], b2 = gb[2], b3 = gb[3];
      half8 ha0 = {(_Float16)a0.x, (_Float16)a0.y, (_Float16)a0.z, (_Float16)a0.w,
                   (_Float16)a1.x, (_Float16)a1.y, (_Float16)a1.z, (_Float16)a1.w};
      half8 ha1 = {(_Float16)a2.x, (_Float16)a2.y, (_Float16)a2.z, (_Float16)a2.w,
                   (_Float16)a3.x, (_Float16)a3.y, (_Float16)a3.z, (_Float16)a3.w};
      half8 hb0 = {(_Float16)b0.x, (_Float16)b0.y, (_Float16)b0.z, (_Float16)b0.w,
                   (_Float16)b1.x, (_Float16)b1.y, (_Float16)b1.z, (_Float16)b1.w};
      half8 hb1 = {(_Float16)b2.x, (_Float16)b2.y, (_Float16)b2.z, (_Float16)b2.w,
                   (_Float16)b3.x, (_Float16)b3.y, (_Float16)b3.z, (_Float16)b3.w};
      int lo = srow * 40 + shalf * 16;
      *(half8*)&As[lo] = ha0;
      *(half8*)&As[lo + 8] = ha1;
      *(half8*)&Bs[lo] = hb0;
      *(half8*)&Bs[lo + 8] = hb1;
    }
    __syncthreads();
    half8 a[4], b[4];
#pragma unroll
    for (int mt = 0; mt < 4; ++mt)
      a[mt] = *(const half8*)&As[(wm + mt * 16 + l15) * 40 + quad * 8];
#pragma unroll
    for (int nt = 0; nt < 4; ++nt)
      b[nt] = *(const half8*)&Bs[(wn + nt * 16 + l15) * 40 + quad * 8];
#pragma unroll
    for (int mt = 0; mt < 4; ++mt)
#pragma unroll
      for (int nt = 0; nt < 4; ++nt)
        acc[mt][nt] =
            __builtin_amdgcn_mfma_f32_16x16x32_f16(a[mt], b[nt], acc[mt][nt], 0, 0, 0);
  }
#pragma unroll
  for (int mt = 0; mt < 4; ++mt) {
#pragma unroll
    for (int r = 0; r < 4; ++r) {
      int row = m0 + wm + mt * 16 + quad * 4 + r;
      int b_ = row >> 10, n_ = row & 1023;
      float t = tm[b_ * 1024 + n_];
#pragma unroll
      for (int nt = 0; nt < 4; ++nt) {
        int c3 = n0 + wn + nt * 16 + l15;
        float v = (acc[mt][nt][r] + bias[c3]) * t;
        int sec = c3 >> 9, ch = c3 & 511;
        __half* dst = (sec == 0) ? Q : (sec == 1 ? K : V);
        dst[(size_t)b_ * (Nn * Cc) + (size_t)n_ * 512 + ch] = f2h(v);
      }
    }
  }
}

// ---------------------------------------------------------------------------
// K2: pool — block per (b,h,u-tile of 64). Coalesced row staging.
__global__ __launch_bounds__(256) void pool_kernel(
    const __half* __restrict__ Q, const __half* __restrict__ K,
    const float* __restrict__ tm, __half* __restrict__ QL,
    __half* __restrict__ KL, float* __restrict__ LM) {
  int ut = blockIdx.x;
  int bh = blockIdx.y;
  int b = bh >> 3, h = bh & 7;
  int u0 = ut * 64;
  int delta = u0 >> 9;
  int ch0 = u0 & 511;
  __shared__ float Qs[64][65];
  __shared__ float Ks[64][65];
  int tid = threadIdx.x;
  for (int e = tid; e < 4096; e += 256) {
    int d = e >> 6, uu = e & 63;
    int row = 2 * (h * 64 + d) + delta;
    size_t gi = (size_t)b * (Nn * Cc) + (size_t)row * 512 + ch0 + uu;
    Qs[d][uu] = h2f(Q[gi]);
    Ks[d][uu] = h2f(K[gi]);
  }
  __syncthreads();
  int d = tid & 63, s = tid >> 6;
#pragma unroll
  for (int jr = 0; jr < 2; ++jr) {
    int jl = s + 4 * jr;
    int j = ut * 8 + jl;
    float pm = 0.f, sq = 0.f, sk = 0.f;
#pragma unroll
    for (int i = 0; i < 8; ++i) {
      float t = tm[b * 1024 + 8 * j + i];
      pm += t;
      sq += Qs[d][8 * jl + i] * t;
      sk += Ks[d][8 * jl + i] * t;
    }
    pm *= 0.125f;
    float pms = fmaxf(pm, 1e-6f);
    size_t oi = ((size_t)bh * 128 + j) * 64 + d;
    QL[oi] = f2h(sq * 0.125f / pms);
    KL[oi] = f2h(sk * 0.125f / pms);
    if (h == 0 && d == 0) LM[b * 128 + j] = (pm > 0.f) ? 1.f : 0.f;
  }
}

// ---------------------------------------------------------------------------
// K3: wbuild v2 — stats_partial-style: grid (8 i-tiles, 16 bh), float4 LDS
// reads, 2j x 4i register tile, coalesced f32 stores via LDS stage.
__global__ __launch_bounds__(256) void wbuild_kernel(
    const __half* __restrict__ QL, const __half* __restrict__ KL,
    const float* __restrict__ LM, float* __restrict__ W) {
  int it = blockIdx.x;   // 0..7 (16 i each)
  int bh = blockIdx.y;   // 16
  int b = bh >> 3;
  int i0 = it * 16;
  __shared__ __align__(16) float kls[128 * 68];
  __shared__ __align__(16) float qs[16 * 68];
  __shared__ float ps[16 * 132];
  int tid = threadIdx.x;
  for (int e = tid; e < 8192; e += 256)
    kls[(e >> 6) * 68 + (e & 63)] = h2f(KL[(size_t)bh * 8192 + e]);
  for (int e = tid; e < 1024; e += 256)
    qs[(e >> 6) * 68 + (e & 63)] =
        h2f(QL[(size_t)bh * 8192 + (size_t)(i0 + (e >> 6)) * 64 + (e & 63)]);
  __syncthreads();
  int jg = tid & 63, ng = tid >> 6;
  int j = jg * 2;
  const float4* kA = (const float4*)&kls[j * 68];
  const float4* kB = (const float4*)&kls[(j + 1) * 68];
  float sA[4] = {}, sB[4] = {};
#pragma unroll
  for (int i = 0; i < 16; ++i) {
    int dq = (i + jg) & 15;
    float4 ka = kA[dq];
    float4 kb = kB[dq];
#pragma unroll
    for (int r = 0; r < 4; ++r) {
      float4 qv = *(const float4*)&qs[(ng * 4 + r) * 68 + dq * 4];
      sA[r] += fabsf(qv.x - ka.x) + fabsf(qv.y - ka.y) + fabsf(qv.z - ka.z) + fabsf(qv.w - ka.w);
      sB[r] += fabsf(qv.x - kb.x) + fabsf(qv.y - kb.y) + fabsf(qv.z - kb.z) + fabsf(qv.w - kb.w);
    }
  }
  float lmA = LM[b * Mm + j], lmB = LM[b * Mm + j + 1];
#pragma unroll
  for (int r = 0; r < 4; ++r) {
    int i = i0 + ng * 4 + r;
    float lmi = LM[b * Mm + i];
    float prA = lmi * lmA, prB = lmi * lmB;
    float dA = (i == j) ? 1.f : 0.f;
    float dB = (i == j + 1) ? 1.f : 0.f;
    ps[(ng * 4 + r) * 132 + j] = expf(-sA[r] * 0.25f) * prA + dA * (1.f - prA) + dA * NS_EPS;
    ps[(ng * 4 + r) * 132 + j + 1] = expf(-sB[r] * 0.25f) * prB + dB * (1.f - prB) + dB * NS_EPS;
  }
  __syncthreads();
  for (int e = tid; e < 2048; e += 256)
    W[(size_t)bh * (Mm * Mm) + (size_t)(i0 + (e >> 7)) * 128 + (e & 127)] =
        ps[(e >> 7) * 132 + (e & 127)];
}

// ---------------------------------------------------------------------------
// K4: ns_solve — entire Newton-Schulz in one launch. One block per bh.
__global__ __launch_bounds__(256) void ns_solve(const float* __restrict__ Wg,
                                                float* __restrict__ Xout) {
  int bh = blockIdx.x;
  __shared__ _Float16 Ws[128 * 136];
  __shared__ _Float16 Xa[128 * 136];
  __shared__ _Float16 Xb[128 * 136];
  __shared__ _Float16 Tt[128 * 136];
  __shared__ float red[256];
  int tid = threadIdx.x;
  const float* Wb = Wg + (size_t)bh * 16384;
  float fro = 0.f;
  for (int e = tid; e < 16384; e += 256) {
    float wv = Wb[e];
    Ws[(e >> 7) * 136 + (e & 127)] = (_Float16)wv;
    fro += wv * wv;
  }
  red[tid] = fro;
  __syncthreads();
  for (int off = 128; off > 0; off >>= 1) {
    if (tid < off) red[tid] += red[tid + off];
    __syncthreads();
  }
  float scale = 2.f / (sqrtf(red[0]) + 1e-8f);
  for (int e = tid; e < 16384; e += 256) {
    int i = e >> 7, k = e & 127;
    Xa[i * 136 + k] = (_Float16)(scale * (float)Ws[k * 136 + i]);
    Xb[i * 136 + k] = (_Float16)(scale * (float)Ws[i * 136 + k]);
  }
  __syncthreads();
  int lane = tid & 63, wv_ = tid >> 6;
  int wm = (wv_ >> 1) * 64, wn = (wv_ & 1) * 64;
  int l15 = lane & 15, quad = lane >> 4;
  for (int it = 0; it < 5; ++it) {
    {
      float4v acc[4][4] = {};
#pragma unroll
      for (int kt = 0; kt < 4; ++kt) {
        half8 a[4], b[4];
#pragma unroll
        for (int mt = 0; mt < 4; ++mt)
          a[mt] = *(const half8*)&Ws[(wm + mt * 16 + l15) * 136 + kt * 32 + quad * 8];
#pragma unroll
        for (int nt = 0; nt < 4; ++nt)
          b[nt] = *(const half8*)&Xb[(wn + nt * 16 + l15) * 136 + kt * 32 + quad * 8];
#pragma unroll
        for (int mt = 0; mt < 4; ++mt)
#pragma unroll
          for (int nt = 0; nt < 4; ++nt)
            acc[mt][nt] =
                __builtin_amdgcn_mfma_f32_16x16x32_f16(a[mt], b[nt], acc[mt][nt], 0, 0, 0);
      }
#pragma unroll
      for (int mt = 0; mt < 4; ++mt)
#pragma unroll
        for (int r = 0; r < 4; ++r) {
          int i = wm + mt * 16 + quad * 4 + r;
#pragma unroll
          for (int nt = 0; nt < 4; ++nt) {
            int j = wn + nt * 16 + l15;
            Tt[j * 136 + i] = (_Float16)(((i == j) ? 2.f : 0.f) - acc[mt][nt][r]);
          }
        }
    }
    __syncthreads();
    {
      float4v acc[4][4] = {};
#pragma unroll
      for (int kt = 0; kt < 4; ++kt) {
        half8 a[4], b[4];
#pragma unroll
        for (int mt = 0; mt < 4; ++mt)
          a[mt] = *(const half8*)&Xa[(wm + mt * 16 + l15) * 136 + kt * 32 + quad * 8];
#pragma unroll
        for (int nt = 0; nt < 4; ++nt)
          b[nt] = *(const half8*)&Tt[(wn + nt * 16 + l15) * 136 + kt * 32 + quad * 8];
#pragma unroll
        for (int mt = 0; mt < 4; ++mt)
#pragma unroll
          for (int nt = 0; nt < 4; ++nt)
            acc[mt][nt] =
                __builtin_amdgcn_mfma_f32_16x16x32_f16(a[mt], b[nt], acc[mt][nt], 0, 0, 0);
      }
      __syncthreads();
#pragma unroll
      for (int mt = 0; mt < 4; ++mt)
#pragma unroll
        for (int r = 0; r < 4; ++r) {
          int i = wm + mt * 16 + quad * 4 + r;
#pragma unroll
          for (int nt = 0; nt < 4; ++nt) {
            int j = wn + nt * 16 + l15;
            _Float16 v = (_Float16)acc[mt][nt][r];
            Xa[i * 136 + j] = v;
            Xb[j * 136 + i] = v;
          }
        }
    }
    __syncthreads();
  }
  for (int e = tid; e < 16384; e += 256)
    Xout[(size_t)bh * 16384 + e] = (float)Xa[(e >> 7) * 136 + (e & 127)];
}

// ---------------------------------------------------------------------------
// K7: ktv — fused C_k + K^T V. Non-atomic partials to KTVp[nc][bh][j][d].
__global__ __launch_bounds__(256) void ktv_fused(
    const __half* __restrict__ K, const __half* __restrict__ QL,
    const float* __restrict__ LM, const __half* __restrict__ V,
    float* __restrict__ KTVp) {
  int jt = blockIdx.x;   // 4 (32 j each)
  int bh = blockIdx.y;   // 16
  int nc = blockIdx.z;   // 8 (128 n each)
  int b = bh >> 3, h = bh & 7;
  int j0 = jt * 32;
  __shared__ __align__(16) float qls[32 * 68];
  __shared__ __align__(16) float Ks[32 * 68];
  __shared__ __align__(16) float Vs[32 * 68];
  __shared__ float P[32 * 36];
  int tid = threadIdx.x;
  int sr = tid >> 3, sd8 = (tid & 7) * 8;
  {
    half8 q = *(const half8*)(QL + (size_t)bh * 8192 + (size_t)(j0 + sr) * 64 + sd8);
    float4 f0 = {(float)q[0], (float)q[1], (float)q[2], (float)q[3]};
    float4 f1 = {(float)q[4], (float)q[5], (float)q[6], (float)q[7]};
    *(float4*)&qls[sr * 68 + sd8] = f0;
    *(float4*)&qls[sr * 68 + sd8 + 4] = f1;
  }
  int jq = tid & 15, nq = tid >> 4;
  int dq2 = tid & 7, jl = tid >> 3;
  float acc[8] = {};
  for (int nt = 0; nt < 4; ++nt) {
    int n0 = nc * 128 + nt * 32;
    __syncthreads();
    {
      size_t gi = (size_t)b * (Nn * Cc) + (size_t)(n0 + sr) * 512 + h * 64 + sd8;
      half8 kv = *(const half8*)(K + gi);
      half8 vv = *(const half8*)(V + gi);
      float4 k0 = {(float)kv[0], (float)kv[1], (float)kv[2], (float)kv[3]};
      float4 k1 = {(float)kv[4], (float)kv[5], (float)kv[6], (float)kv[7]};
      float4 v0 = {(float)vv[0], (float)vv[1], (float)vv[2], (float)vv[3]};
      float4 v1 = {(float)vv[4], (float)vv[5], (float)vv[6], (float)vv[7]};
      *(float4*)&Ks[sr * 68 + sd8] = k0;
      *(float4*)&Ks[sr * 68 + sd8 + 4] = k1;
      *(float4*)&Vs[sr * 68 + sd8] = v0;
      *(float4*)&Vs[sr * 68 + sd8 + 4] = v1;
    }
    __syncthreads();
    {
      const float4* q0p = (const float4*)&qls[(jq * 2) * 68];
      const float4* q1p = (const float4*)&qls[(jq * 2 + 1) * 68];
      const float4* k0p = (const float4*)&Ks[(nq * 2) * 68];
      const float4* k1p = (const float4*)&Ks[(nq * 2 + 1) * 68];
      float s00 = 0.f, s01 = 0.f, s10 = 0.f, s11 = 0.f;
#pragma unroll
      for (int i = 0; i < 16; ++i) {
        int dq = (i + tid) & 15;
        float4 q0 = q0p[dq], q1 = q1p[dq];
        float4 k0 = k0p[dq], k1 = k1p[dq];
        s00 += fabsf(q0.x - k0.x) + fabsf(q0.y - k0.y) + fabsf(q0.z - k0.z) + fabsf(q0.w - k0.w);
        s01 += fabsf(q0.x - k1.x) + fabsf(q0.y - k1.y) + fabsf(q0.z - k1.z) + fabsf(q0.w - k1.w);
        s10 += fabsf(q1.x - k0.x) + fabsf(q1.y - k0.y) + fabsf(q1.z - k0.z) + fabsf(q1.w - k0.w);
        s11 += fabsf(q1.x - k1.x) + fabsf(q1.y - k1.y) + fabsf(q1.z - k1.z) + fabsf(q1.w - k1.w);
      }
      P[(nq * 2) * 36 + jq * 2] = expf(-s00 * 0.25f);
      P[(nq * 2) * 36 + jq * 2 + 1] = expf(-s10 * 0.25f);
      P[(nq * 2 + 1) * 36 + jq * 2] = expf(-s01 * 0.25f);
      P[(nq * 2 + 1) * 36 + jq * 2 + 1] = expf(-s11 * 0.25f);
    }
    __syncthreads();
    {
#pragma unroll 4
      for (int n = 0; n < 32; ++n) {
        float p = P[n * 36 + jl];
        float4 v0 = *(const float4*)&Vs[n * 68 + dq2 * 8];
        float4 v1 = *(const float4*)&Vs[n * 68 + dq2 * 8 + 4];
        acc[0] += p * v0.x; acc[1] += p * v0.y; acc[2] += p * v0.z; acc[3] += p * v0.w;
        acc[4] += p * v1.x; acc[5] += p * v1.y; acc[6] += p * v1.z; acc[7] += p * v1.w;
      }
    }
  }
  {
    float lm = LM[b * 128 + j0 + jl];
    float* dst = &KTVp[((size_t)nc * 16 + bh) * 8192 + (size_t)(j0 + jl) * 64 + dq2 * 8];
    float4 o0 = {acc[0] * lm, acc[1] * lm, acc[2] * lm, acc[3] * lm};
    float4 o1 = {acc[4] * lm, acc[5] * lm, acc[6] * lm, acc[7] * lm};
    *(float4*)dst = o0;
    *(float4*)(dst + 4) = o1;
  }
}

// ---------------------------------------------------------------------------
// K8: ctx v2 — fused nc-reduction of KTVp (LDS) + CTX = X @ KTV.
__global__ __launch_bounds__(256) void ctx_kernel(const float* __restrict__ X,
                                                  const float* __restrict__ KTVp,
                                                  __half* __restrict__ CTX) {
  int it = blockIdx.x;  // 0..7
  int bh = blockIdx.y;  // 16
  int i0 = it * 16;
  __shared__ __align__(16) float KTVs[8192];
  __shared__ float Xs[16][132];
  int tid = threadIdx.x;
  const float4* src = (const float4*)KTVp;
  for (int e = tid; e < 2048; e += 256) {
    float4 s = src[(size_t)bh * 2048 + e];
#pragma unroll
    for (int nc = 1; nc < 8; ++nc) {
      float4 v = src[((size_t)nc * 16 + bh) * 2048 + e];
      s.x += v.x; s.y += v.y; s.z += v.z; s.w += v.w;
    }
    *(float4*)&KTVs[e * 4] = s;
  }
  for (int e = tid; e < 2048; e += 256)
    Xs[e >> 7][e & 127] = X[(size_t)bh * 16384 + (size_t)(i0 + (e >> 7)) * 128 + (e & 127)];
  __syncthreads();
  int il = tid >> 4, dg = tid & 15;
  float a0 = 0.f, a1 = 0.f, a2 = 0.f, a3 = 0.f;
#pragma unroll 4
  for (int j = 0; j < 128; ++j) {
    float xv = Xs[il][j];
    float4 kv = *(const float4*)&KTVs[j * 64 + dg * 4];
    a0 += xv * kv.x; a1 += xv * kv.y; a2 += xv * kv.z; a3 += xv * kv.w;
  }
  size_t ob = (size_t)bh * 8192 + (size_t)(i0 + il) * 64 + dg * 4;
  CTX[ob] = f2h(a0);
  CTX[ob + 1] = f2h(a1);
  CTX[ob + 2] = f2h(a2);
  CTX[ob + 3] = f2h(a3);
}

// ---------------------------------------------------------------------------
// K9: stats_partial v3 — float4 LDS reads, 2j x 4n register tile.
__global__ __launch_bounds__(256) void stats_partial(
    const __half* __restrict__ Q, const __half* __restrict__ KL,
    const float* __restrict__ LM, const float* __restrict__ tm,
    float* __restrict__ PS, __half* __restrict__ Pbuf) {
  int nt = blockIdx.x;   // 64
  int bh = blockIdx.y;   // 16
  int b = bh >> 3, h = bh & 7;
  int n0 = nt * 16;
  __shared__ __align__(16) float kls[128 * 68];
  __shared__ __align__(16) float qs[16 * 68];
  __shared__ __half ps[16 * 132];
  __shared__ float part[128 * 12];
  int tid = threadIdx.x;
  for (int e = tid; e < 8192; e += 256)
    kls[(e >> 6) * 68 + (e & 63)] = h2f(KL[(size_t)bh * 8192 + e]);
  for (int e = tid; e < 1024; e += 256)
    qs[(e >> 6) * 68 + (e & 63)] =
        h2f(Q[(size_t)b * (Nn * Cc) + (size_t)(n0 + (e >> 6)) * 512 + h * 64 + (e & 63)]);
  __syncthreads();
  int jg = tid & 63, ng = tid >> 6;
  int j = jg * 2;
  const float4* kA = (const float4*)&kls[j * 68];
  const float4* kB = (const float4*)&kls[(j + 1) * 68];
  float sA[4] = {}, sB[4] = {};
#pragma unroll
  for (int i = 0; i < 16; ++i) {
    int dq = (i + jg) & 15;
    float4 ka = kA[dq];
    float4 kb = kB[dq];
#pragma unroll
    for (int r = 0; r < 4; ++r) {
      float4 qv = *(const float4*)&qs[(ng * 4 + r) * 68 + dq * 4];
      sA[r] += fabsf(qv.x - ka.x) + fabsf(qv.y - ka.y) + fabsf(qv.z - ka.z) + fabsf(qv.w - ka.w);
      sB[r] += fabsf(qv.x - kb.x) + fabsf(qv.y - kb.y) + fabsf(qv.z - kb.z) + fabsf(qv.w - kb.w);
    }
  }
  float lmA = LM[b * 128 + j], lmB = LM[b * 128 + j + 1];
  float a1 = 0.f, a2 = 0.f, a3 = 0.f, b1 = 0.f, b2 = 0.f, b3 = 0.f;
#pragma unroll
  for (int r = 0; r < 4; ++r) {
    int nn = ng * 4 + r;
    float t = tm[b * 1024 + n0 + nn];
    float xa = expf(-sA[r] * 0.25f) * lmA;
    float xb = expf(-sB[r] * 0.25f) * lmB;
    ps[nn * 132 + j] = f2h(xa);
    ps[nn * 132 + j + 1] = f2h(xb);
    float xta = xa * t, xtb = xb * t;
    a1 += xta; a2 += xta * xta; a3 += xta * t;
    b1 += xtb; b2 += xtb * xtb; b3 += xtb * t;
  }
  part[j * 12 + ng * 3 + 0] = a1;
  part[j * 12 + ng * 3 + 1] = a2;
  part[j * 12 + ng * 3 + 2] = a3;
  part[(j + 1) * 12 + ng * 3 + 0] = b1;
  part[(j + 1) * 12 + ng * 3 + 1] = b2;
  part[(j + 1) * 12 + ng * 3 + 2] = b3;
  __syncthreads();
  for (int e = tid; e < 2048; e += 256)
    Pbuf[((size_t)bh * 1024 + n0 + (e >> 7)) * 128 + (e & 127)] =
        ps[(e >> 7) * 132 + (e & 127)];
  if (tid < 128) {
    float s1 = part[tid * 12 + 0] + part[tid * 12 + 3] + part[tid * 12 + 6] + part[tid * 12 + 9];
    float s2 = part[tid * 12 + 1] + part[tid * 12 + 4] + part[tid * 12 + 7] + part[tid * 12 + 10];
    float s3 = part[tid * 12 + 2] + part[tid * 12 + 5] + part[tid * 12 + 8] + part[tid * 12 + 11];
    size_t base = ((size_t)(b * 64 + nt) * 8 + h) * 384 + tid * 3;
    PS[base] = s1; PS[base + 1] = s2; PS[base + 2] = s3;
  }
}

// ---------------------------------------------------------------------------
// K10: stats_final — reduce PS over 128 (b,nt) tiles per (h,j).
__global__ __launch_bounds__(256) void stats_final(const float* __restrict__ PS,
                                                   const float* __restrict__ tm,
                                                   float* __restrict__ MU,
                                                   float* __restrict__ RS) {
  __shared__ float red[256][2];
  __shared__ float ts0, ts1;
  int tid = threadIdx.x;
  float a = 0.f, c = 0.f;
  for (int i = tid; i < 2048; i += 256) { float t = tm[i]; a += t; c += t * t; }
  red[tid][0] = a; red[tid][1] = c;
  __syncthreads();
  for (int off = 128; off > 0; off >>= 1) {
    if (tid < off) { red[tid][0] += red[tid + off][0]; red[tid][1] += red[tid + off][1]; }
    __syncthreads();
  }
  if (tid == 0) { ts0 = red[0][0]; ts1 = red[0][1]; }
  __syncthreads();
  int hj = blockIdx.x * 256 + tid;
  int h = hj >> 7, j = hj & 127;
  float s1 = 0.f, s2 = 0.f, s3 = 0.f;
  for (int bnt = 0; bnt < 128; ++bnt) {
    const float* p = PS + ((size_t)bnt * 8 + h) * 384 + j * 3;
    s1 += p[0]; s2 += p[1]; s3 += p[2];
  }
  float valid = fmaxf(ts0, 1.f);
  float mu = s1 / valid;
  float var = (s2 - 2.f * mu * s3 + mu * mu * ts1) / valid;
  var = fmaxf(var, 0.f);
  MU[hj] = mu;
  RS[hj] = rsqrtf(var + WHITE_EPS);
}

// ---------------------------------------------------------------------------
// K12: ga v3 — P whiten @ context + inline scrambled depthwise conv; writes
// VL once.
__global__ __launch_bounds__(256) void ga_fused(
    const __half* __restrict__ Pbuf, const float* __restrict__ MU,
    const float* __restrict__ RS, const __half* __restrict__ CTXg,
    const __half* __restrict__ V, const float* __restrict__ dwc_w,
    const float* __restrict__ dwc_b, const float* __restrict__ tm,
    __half* __restrict__ VL) {
  int bh = blockIdx.y;
  int b = bh >> 3, h = bh & 7;
  int n0 = blockIdx.x * 16;
  __shared__ __half Ps[16][130];
  __shared__ __align__(16) __half2 ctx2[128][32];
  __shared__ float musr[128][2];
  int tid = threadIdx.x;
  for (int e = tid; e < 2048; e += 256)
    Ps[e >> 7][e & 127] = Pbuf[((size_t)bh * 1024 + n0 + (e >> 7)) * 128 + (e & 127)];
  {
    const __half2* cg = (const __half2*)(CTXg + (size_t)bh * 8192);
    for (int e = tid; e < 4096; e += 256) ctx2[e >> 5][e & 31] = cg[e];
  }
  if (tid < 128) { musr[tid][0] = MU[h * 128 + tid]; musr[tid][1] = RS[h * 128 + tid]; }
  __syncthreads();
  int nn = tid >> 4, dq = tid & 15;
  float a0 = 0.f, a1 = 0.f, a2 = 0.f, a3 = 0.f;
#pragma unroll 4
  for (int j = 0; j < 128; ++j) {
    float pj = (h2f(Ps[nn][j]) - musr[j][0]) * musr[j][1];
    uint2 cc = *(const uint2*)&ctx2[j][dq * 2];
    __half2 c01 = __builtin_bit_cast(__half2, cc.x);
    __half2 c23 = __builtin_bit_cast(__half2, cc.y);
    a0 += pj * h2f(c01.x); a1 += pj * h2f(c01.y);
    a2 += pj * h2f(c23.x); a3 += pj * h2f(c23.y);
  }
  int t = n0 + nn;
  float tmv = tm[b * 1024 + t];
  float t2 = tmv * tmv;
  float acc[4] = {a0 * t2, a1 * t2, a2 * t2, a3 * t2};
#pragma unroll
  for (int q = 0; q < 4; ++q) {
    int c = h * 64 + dq * 4 + q;
    float vacc = dwc_b[c];
#pragma unroll
    for (int k = 0; k < 3; ++k) {
      int u = t - 1 + k;
      if (u >= 0 && u < 1024) {
        int n = 2 * c + (u >> 9), ch = u & 511;
        vacc += dwc_w[c * 3 + k] * h2f(V[(size_t)b * (Nn * Cc) + (size_t)n * 512 + ch]);
      }
    }
    acc[q] += vacc * tmv;
  }
  size_t base = (size_t)b * (Nn * Cc) + (size_t)t * 512 + h * 64 + dq * 4;
  VL[base] = f2h(acc[0]);
  VL[base + 1] = f2h(acc[1]);
  VL[base + 2] = f2h(acc[2]);
  VL[base + 3] = f2h(acc[3]);
}

// ---------------------------------------------------------------------------
// K13: proj via MFMA f16. M=2048, N=512, K=512.
__global__ __launch_bounds__(256) void proj_gemm(
    const __half* __restrict__ Ain, const float* __restrict__ w,
    const float* __restrict__ bias, const float* __restrict__ tm,
    float* __restrict__ out) {
  __shared__ _Float16 As[128 * 40];
  __shared__ _Float16 Bs[128 * 40];
  int m0 = blockIdx.x * 128, n0 = blockIdx.y * 128;
  int tid = threadIdx.x;
  int lane = tid & 63, wv = tid >> 6;
  int wm = (wv >> 1) * 64, wn = (wv & 1) * 64;
  int l15 = lane & 15, quad = lane >> 4;
  int srow = tid >> 1, shalf = tid & 1;
  float4v acc[4][4] = {};
  for (int k0 = 0; k0 < 512; k0 += 32) {
    __syncthreads();
    {
      const half8* ga = (const half8*)(Ain + (size_t)(m0 + srow) * 512 + k0 + shalf * 16);
      const float4* gb = (const float4*)(w + (size_t)(n0 + srow) * 512 + k0 + shalf * 16);
      half8 ha0 = ga[0], ha1 = ga[1];
      float4 b0 = gb[0], b1 = gb[1], b2 = gb[2], b3 = gb[3];
      half8 hb0 = {(_Float16)b0.x, (_Float16)b0.y, (_Float16)b0.z, (_Float16)b0.w,
                   (_Float16)b1.x, (_Float16)b1.y, (_Float16)b1.z, (_Float16)b1.w};
      half8 hb1 = {(_Float16)b2.x, (_Float16)b2.y, (_Float16)b2.z, (_Float16)b2.w,
                   (_Float16)b3.x, (_Float16)b3.y, (_Float16)b3.z, (_Float16)b3.w};
      int lo = srow * 40 + shalf * 16;
      *(half8*)&As[lo] = ha0;
      *(half8*)&As[lo + 8] = ha1;
      *(half8*)&Bs[lo] = hb0;
      *(half8*)&Bs[lo + 8] = hb1;
    }
    __syncthreads();
    half8 a[4], b[4];
#pragma unroll
    for (int mt = 0; mt < 4; ++mt)
      a[mt] = *(const half8*)&As[(wm + mt * 16 + l15) * 40 + quad * 8];
#pragma unroll
    for (int nt = 0; nt < 4; ++nt)
      b[nt] = *(const half8*)&Bs[(wn + nt * 16 + l15) * 40 + quad * 8];
#pragma unroll
    for (int mt = 0; mt < 4; ++mt)
#pragma unroll
      for (int nt = 0; nt < 4; ++nt)
        acc[mt][nt] =
            __builtin_amdgcn_mfma_f32_16x16x32_f16(a[mt], b[nt], acc[mt][nt], 0, 0, 0);
  }
#pragma unroll
  for (int mt = 0; mt < 4; ++mt) {
#pragma unroll
    for (int r = 0; r < 4; ++r) {
      int row = m0 + wm + mt * 16 + quad * 4 + r;
      int b_ = row >> 10, n_ = row & 1023;
      float t = tm[b_ * 1024 + n_];
#pragma unroll
      for (int nt = 0; nt < 4; ++nt) {
        int co = n0 + wn + nt * 16 + l15;
        out[(size_t)row * 512 + co] = (acc[mt][nt][r] + bias[co]) * t;
      }
    }
  }
}

// ---------------------------------------------------------------------------
// d_ws 11.26 MiB (proven). d_out (4 MiB): Wf f32 (NS) -> KTVp f32 partials
// (ktv->ctx) -> Pbuf f16 (stats->ga) -> final f32 output. Stream-ordered.
extern "C" void kernel_launch(void* const* d_in, const int* in_sizes, int n_in,
                              void* d_out, int out_size, void* d_ws, size_t ws_size,
                              hipStream_t stream) {
  const float* x      = (const float*)d_in[0];
  const float* tm     = (const float*)d_in[1];
  const float* qkv_w  = (const float*)d_in[2];
  const float* qkv_b  = (const float*)d_in[3];
  const float* proj_w = (const float*)d_in[4];
  const float* proj_b = (const float*)d_in[5];
  const float* dwc_w  = (const float*)d_in[6];
  const float* dwc_b  = (const float*)d_in[7];
  float* out = (float*)d_out;

  char* wsb = (char*)d_ws;
  __half* Qh  = (__half*)(wsb + 0);
  __half* Kh  = (__half*)(wsb + 2097152);
  __half* Vh  = (__half*)(wsb + 4194304);
  __half* VLh = (__half*)(wsb + 6291456);
  __half* QLh = (__half*)(wsb + 8388608);
  __half* KLh = (__half*)(wsb + 8650752);
  float*  LM  = (float*)(wsb + 8912896);
  float*  MU  = (float*)(wsb + 8913920);
  float*  RS  = (float*)(wsb + 8918016);
  __half* CTX = (__half*)(wsb + 9446400);
  float*  XA  = (float*)(wsb + 9708544);
  float*  PS  = (float*)(wsb + 9708544 + 1048576);

  char* ob = (char*)d_out;
  float*  Wf   = (float*)ob;     // NS phase
  float*  KTVp = (float*)ob;     // ktv partials (4 MiB, after NS)
  __half* Pbuf = (__half*)ob;    // stats->ga phase

  qkv_gemm<<<dim3(16, 12), 256, 0, stream>>>(x, qkv_w, qkv_b, tm, Qh, Kh, Vh);
  pool_kernel<<<dim3(16, 16), 256, 0, stream>>>(Qh, Kh, tm, QLh, KLh, LM);
  wbuild_kernel<<<dim3(8, 16), 256, 0, stream>>>(QLh, KLh, LM, Wf);
  ns_solve<<<16, 256, 0, stream>>>(Wf, XA);
  ktv_fused<<<dim3(4, 16, 8), 256, 0, stream>>>(Kh, QLh, LM, Vh, KTVp);
  ctx_kernel<<<dim3(8, 16), 256, 0, stream>>>(XA, KTVp, CTX);
  stats_partial<<<dim3(64, 16), 256, 0, stream>>>(Qh, KLh, LM, tm, PS, Pbuf);
  stats_final<<<4, 256, 0, stream>>>(PS, tm, MU, RS);
  ga_fused<<<dim3(64, 16), 256, 0, stream>>>(Pbuf, MU, RS, CTX, Vh, dwc_w, dwc_b, tm, VLh);
  proj_gemm<<<dim3(16, 4), 256, 0, stream>>>(VLh, proj_w, proj_b, tm, out);
}

// Round 16
// 235.243 us; speedup vs baseline: 1.9599x; 1.0601x over previous
//
#include <hip/hip_runtime.h>
#include <hip/hip_bf16.h>
#include <hip/hip_fp16.h>

// B=2, N=1024, C=512, H=8, D=64, m=128, p=8
#define Hh 8
#define Bz 2
#define Nn 1024
#define Cc 512
#define Dd 64
#define Mm 128
#define NS_EPS 1e-4f
#define WHITE_EPS 1e-5f

__device__ __forceinline__ float h2f(__half v) { return __half2float(v); }
__device__ __forceinline__ __half f2h(float v) { return __float2half(v); }

typedef _Float16 half8 __attribute__((ext_vector_type(8)));
typedef float float4v __attribute__((ext_vector_type(4)));

// ---------------------------------------------------------------------------
// K1: QKV GEMM via MFMA f16. M=2048, N=1536, K=512. Block tile 128x128.
__global__ __launch_bounds__(256) void qkv_gemm(
    const float* __restrict__ x, const float* __restrict__ w,
    const float* __restrict__ bias, const float* __restrict__ tm,
    __half* __restrict__ Q, __half* __restrict__ K, __half* __restrict__ V) {
  __shared__ _Float16 As[128 * 40];
  __shared__ _Float16 Bs[128 * 40];
  int m0 = blockIdx.x * 128, n0 = blockIdx.y * 128;
  int tid = threadIdx.x;
  int lane = tid & 63, wv = tid >> 6;
  int wm = (wv >> 1) * 64, wn = (wv & 1) * 64;
  int l15 = lane & 15, quad = lane >> 4;
  int srow = tid >> 1, shalf = tid & 1;
  float4v acc[4][4] = {};
  for (int k0 = 0; k0 < 512; k0 += 32) {
    __syncthreads();
    {
      const float4* ga = (const float4*)(x + (size_t)(m0 + srow) * 512 + k0 + shalf * 16);
      const float4* gb = (const float4*)(w + (size_t)(n0 + srow) * 512 + k0 + shalf * 16);
      float4 a0 = ga[0], a1 = ga[1], a2 = ga[2], a3 = ga[3];
      float4 b0 = gb[0], b1 = gb[1], b2 = gb[2], b3 = gb[3];
      half8 ha0 = {(_Float16)a0.x, (_Float16)a0.y, (_Float16)a0.z, (_Float16)a0.w,
                   (_Float16)a1.x, (_Float16)a1.y, (_Float16)a1.z, (_Float16)a1.w};
      half8 ha1 = {(_Float16)a2.x, (_Float16)a2.y, (_Float16)a2.z, (_Float16)a2.w,
                   (_Float16)a3.x, (_Float16)a3.y, (_Float16)a3.z, (_Float16)a3.w};
      half8 hb0 = {(_Float16)b0.x, (_Float16)b0.y, (_Float16)b0.z, (_Float16)b0.w,
                   (_Float16)b1.x, (_Float16)b1.y, (_Float16)b1.z, (_Float16)b1.w};
      half8 hb1 = {(_Float16)b2.x, (_Float16)b2.y, (_Float16)b2.z, (_Float16)b2.w,
                   (_Float16)b3.x, (_Float16)b3.y, (_Float16)b3.z, (_Float16)b3.w};
      int lo = srow * 40 + shalf * 16;
      *(half8*)&As[lo] = ha0;
      *(half8*)&As[lo + 8] = ha1;
      *(half8*)&Bs[lo] = hb0;
      *(half8*)&Bs[lo + 8] = hb1;
    }
    __syncthreads();
    half8 a[4], b[4];
#pragma unroll
    for (int mt = 0; mt < 4; ++mt)
      a[mt] = *(const half8*)&As[(wm + mt * 16 + l15) * 40 + quad * 8];
#pragma unroll
    for (int nt = 0; nt < 4; ++nt)
      b[nt] = *(const half8*)&Bs[(wn + nt * 16 + l15) * 40 + quad * 8];
#pragma unroll
    for (int mt = 0; mt < 4; ++mt)
#pragma unroll
      for (int nt = 0; nt < 4; ++nt)
        acc[mt][nt] =
            __builtin_amdgcn_mfma_f32_16x16x32_f16(a[mt], b[nt], acc[mt][nt], 0, 0, 0);
  }
#pragma unroll
  for (int mt = 0; mt < 4; ++mt) {
#pragma unroll
    for (int r = 0; r < 4; ++r) {
      int row = m0 + wm + mt * 16 + quad * 4 + r;
      int b_ = row >> 10, n_ = row & 1023;
      float t = tm[b_ * 1024 + n_];
#pragma unroll
      for (int nt = 0; nt < 4; ++nt) {
        int c3 = n0 + wn + nt * 16 + l15;
        float v = (acc[mt][nt][r] + bias[c3]) * t;
        int sec = c3 >> 9, ch = c3 & 511;
        __half* dst = (sec == 0) ? Q : (sec == 1 ? K : V);
        dst[(size_t)b_ * (Nn * Cc) + (size_t)n_ * 512 + ch] = f2h(v);
      }
    }
  }
}

// ---------------------------------------------------------------------------
// K2: pool — block per (b,h,u-tile of 64). Coalesced row staging.
__global__ __launch_bounds__(256) void pool_kernel(
    const __half* __restrict__ Q, const __half* __restrict__ K,
    const float* __restrict__ tm, __half* __restrict__ QL,
    __half* __restrict__ KL, float* __restrict__ LM) {
  int ut = blockIdx.x;
  int bh = blockIdx.y;
  int b = bh >> 3, h = bh & 7;
  int u0 = ut * 64;
  int delta = u0 >> 9;
  int ch0 = u0 & 511;
  __shared__ float Qs[64][65];
  __shared__ float Ks[64][65];
  int tid = threadIdx.x;
  for (int e = tid; e < 4096; e += 256) {
    int d = e >> 6, uu = e & 63;
    int row = 2 * (h * 64 + d) + delta;
    size_t gi = (size_t)b * (Nn * Cc) + (size_t)row * 512 + ch0 + uu;
    Qs[d][uu] = h2f(Q[gi]);
    Ks[d][uu] = h2f(K[gi]);
  }
  __syncthreads();
  int d = tid & 63, s = tid >> 6;
#pragma unroll
  for (int jr = 0; jr < 2; ++jr) {
    int jl = s + 4 * jr;
    int j = ut * 8 + jl;
    float pm = 0.f, sq = 0.f, sk = 0.f;
#pragma unroll
    for (int i = 0; i < 8; ++i) {
      float t = tm[b * 1024 + 8 * j + i];
      pm += t;
      sq += Qs[d][8 * jl + i] * t;
      sk += Ks[d][8 * jl + i] * t;
    }
    pm *= 0.125f;
    float pms = fmaxf(pm, 1e-6f);
    size_t oi = ((size_t)bh * 128 + j) * 64 + d;
    QL[oi] = f2h(sq * 0.125f / pms);
    KL[oi] = f2h(sk * 0.125f / pms);
    if (h == 0 && d == 0) LM[b * 128 + j] = (pm > 0.f) ? 1.f : 0.f;
  }
}

// ---------------------------------------------------------------------------
// K3: wbuild v2 — stats-style: grid (8 i-tiles, 16 bh), float4 LDS reads.
__global__ __launch_bounds__(256) void wbuild_kernel(
    const __half* __restrict__ QL, const __half* __restrict__ KL,
    const float* __restrict__ LM, float* __restrict__ W) {
  int it = blockIdx.x;   // 0..7 (16 i each)
  int bh = blockIdx.y;   // 16
  int b = bh >> 3;
  int i0 = it * 16;
  __shared__ __align__(16) float kls[128 * 68];
  __shared__ __align__(16) float qs[16 * 68];
  __shared__ float ps[16 * 132];
  int tid = threadIdx.x;
  for (int e = tid; e < 8192; e += 256)
    kls[(e >> 6) * 68 + (e & 63)] = h2f(KL[(size_t)bh * 8192 + e]);
  for (int e = tid; e < 1024; e += 256)
    qs[(e >> 6) * 68 + (e & 63)] =
        h2f(QL[(size_t)bh * 8192 + (size_t)(i0 + (e >> 6)) * 64 + (e & 63)]);
  __syncthreads();
  int jg = tid & 63, ng = tid >> 6;
  int j = jg * 2;
  const float4* kA = (const float4*)&kls[j * 68];
  const float4* kB = (const float4*)&kls[(j + 1) * 68];
  float sA[4] = {}, sB[4] = {};
#pragma unroll
  for (int i = 0; i < 16; ++i) {
    int dq = (i + jg) & 15;
    float4 ka = kA[dq];
    float4 kb = kB[dq];
#pragma unroll
    for (int r = 0; r < 4; ++r) {
      float4 qv = *(const float4*)&qs[(ng * 4 + r) * 68 + dq * 4];
      sA[r] += fabsf(qv.x - ka.x) + fabsf(qv.y - ka.y) + fabsf(qv.z - ka.z) + fabsf(qv.w - ka.w);
      sB[r] += fabsf(qv.x - kb.x) + fabsf(qv.y - kb.y) + fabsf(qv.z - kb.z) + fabsf(qv.w - kb.w);
    }
  }
  float lmA = LM[b * Mm + j], lmB = LM[b * Mm + j + 1];
#pragma unroll
  for (int r = 0; r < 4; ++r) {
    int i = i0 + ng * 4 + r;
    float lmi = LM[b * Mm + i];
    float prA = lmi * lmA, prB = lmi * lmB;
    float dA = (i == j) ? 1.f : 0.f;
    float dB = (i == j + 1) ? 1.f : 0.f;
    ps[(ng * 4 + r) * 132 + j] = expf(-sA[r] * 0.25f) * prA + dA * (1.f - prA) + dA * NS_EPS;
    ps[(ng * 4 + r) * 132 + j + 1] = expf(-sB[r] * 0.25f) * prB + dB * (1.f - prB) + dB * NS_EPS;
  }
  __syncthreads();
  for (int e = tid; e < 2048; e += 256)
    W[(size_t)bh * (Mm * Mm) + (size_t)(i0 + (e >> 7)) * 128 + (e & 127)] =
        ps[(e >> 7) * 132 + (e & 127)];
}

// ---------------------------------------------------------------------------
// K4: ns_solve — entire Newton-Schulz in one launch. One block per bh.
__global__ __launch_bounds__(256) void ns_solve(const float* __restrict__ Wg,
                                                float* __restrict__ Xout) {
  int bh = blockIdx.x;
  __shared__ _Float16 Ws[128 * 136];
  __shared__ _Float16 Xa[128 * 136];
  __shared__ _Float16 Xb[128 * 136];
  __shared__ _Float16 Tt[128 * 136];
  __shared__ float red[256];
  int tid = threadIdx.x;
  const float* Wb = Wg + (size_t)bh * 16384;
  float fro = 0.f;
  for (int e = tid; e < 16384; e += 256) {
    float wv = Wb[e];
    Ws[(e >> 7) * 136 + (e & 127)] = (_Float16)wv;
    fro += wv * wv;
  }
  red[tid] = fro;
  __syncthreads();
  for (int off = 128; off > 0; off >>= 1) {
    if (tid < off) red[tid] += red[tid + off];
    __syncthreads();
  }
  float scale = 2.f / (sqrtf(red[0]) + 1e-8f);
  for (int e = tid; e < 16384; e += 256) {
    int i = e >> 7, k = e & 127;
    Xa[i * 136 + k] = (_Float16)(scale * (float)Ws[k * 136 + i]);
    Xb[i * 136 + k] = (_Float16)(scale * (float)Ws[i * 136 + k]);
  }
  __syncthreads();
  int lane = tid & 63, wv_ = tid >> 6;
  int wm = (wv_ >> 1) * 64, wn = (wv_ & 1) * 64;
  int l15 = lane & 15, quad = lane >> 4;
  for (int it = 0; it < 5; ++it) {
    {
      float4v acc[4][4] = {};
#pragma unroll
      for (int kt = 0; kt < 4; ++kt) {
        half8 a[4], b[4];
#pragma unroll
        for (int mt = 0; mt < 4; ++mt)
          a[mt] = *(const half8*)&Ws[(wm + mt * 16 + l15) * 136 + kt * 32 + quad * 8];
#pragma unroll
        for (int nt = 0; nt < 4; ++nt)
          b[nt] = *(const half8*)&Xb[(wn + nt * 16 + l15) * 136 + kt * 32 + quad * 8];
#pragma unroll
        for (int mt = 0; mt < 4; ++mt)
#pragma unroll
          for (int nt = 0; nt < 4; ++nt)
            acc[mt][nt] =
                __builtin_amdgcn_mfma_f32_16x16x32_f16(a[mt], b[nt], acc[mt][nt], 0, 0, 0);
      }
#pragma unroll
      for (int mt = 0; mt < 4; ++mt)
#pragma unroll
        for (int r = 0; r < 4; ++r) {
          int i = wm + mt * 16 + quad * 4 + r;
#pragma unroll
          for (int nt = 0; nt < 4; ++nt) {
            int j = wn + nt * 16 + l15;
            Tt[j * 136 + i] = (_Float16)(((i == j) ? 2.f : 0.f) - acc[mt][nt][r]);
          }
        }
    }
    __syncthreads();
    {
      float4v acc[4][4] = {};
#pragma unroll
      for (int kt = 0; kt < 4; ++kt) {
        half8 a[4], b[4];
#pragma unroll
        for (int mt = 0; mt < 4; ++mt)
          a[mt] = *(const half8*)&Xa[(wm + mt * 16 + l15) * 136 + kt * 32 + quad * 8];
#pragma unroll
        for (int nt = 0; nt < 4; ++nt)
          b[nt] = *(const half8*)&Tt[(wn + nt * 16 + l15) * 136 + kt * 32 + quad * 8];
#pragma unroll
        for (int mt = 0; mt < 4; ++mt)
#pragma unroll
          for (int nt = 0; nt < 4; ++nt)
            acc[mt][nt] =
                __builtin_amdgcn_mfma_f32_16x16x32_f16(a[mt], b[nt], acc[mt][nt], 0, 0, 0);
      }
      __syncthreads();
#pragma unroll
      for (int mt = 0; mt < 4; ++mt)
#pragma unroll
        for (int r = 0; r < 4; ++r) {
          int i = wm + mt * 16 + quad * 4 + r;
#pragma unroll
          for (int nt = 0; nt < 4; ++nt) {
            int j = wn + nt * 16 + l15;
            _Float16 v = (_Float16)acc[mt][nt][r];
            Xa[i * 136 + j] = v;
            Xb[j * 136 + i] = v;
          }
        }
    }
    __syncthreads();
  }
  for (int e = tid; e < 16384; e += 256)
    Xout[(size_t)bh * 16384 + e] = (float)Xa[(e >> 7) * 136 + (e & 127)];
}

// ---------------------------------------------------------------------------
// K7: ktv — fused C_k + K^T V. Non-atomic partials to KTVp[nc][bh][j][d].
__global__ __launch_bounds__(256) void ktv_fused(
    const __half* __restrict__ K, const __half* __restrict__ QL,
    const float* __restrict__ LM, const __half* __restrict__ V,
    float* __restrict__ KTVp) {
  int jt = blockIdx.x;   // 4 (32 j each)
  int bh = blockIdx.y;   // 16
  int nc = blockIdx.z;   // 8 (128 n each)
  int b = bh >> 3, h = bh & 7;
  int j0 = jt * 32;
  __shared__ __align__(16) float qls[32 * 68];
  __shared__ __align__(16) float Ks[32 * 68];
  __shared__ __align__(16) float Vs[32 * 68];
  __shared__ float P[32 * 36];
  int tid = threadIdx.x;
  int sr = tid >> 3, sd8 = (tid & 7) * 8;
  {
    half8 q = *(const half8*)(QL + (size_t)bh * 8192 + (size_t)(j0 + sr) * 64 + sd8);
    float4 f0 = {(float)q[0], (float)q[1], (float)q[2], (float)q[3]};
    float4 f1 = {(float)q[4], (float)q[5], (float)q[6], (float)q[7]};
    *(float4*)&qls[sr * 68 + sd8] = f0;
    *(float4*)&qls[sr * 68 + sd8 + 4] = f1;
  }
  int jq = tid & 15, nq = tid >> 4;
  int dq2 = tid & 7, jl = tid >> 3;
  float acc[8] = {};
  for (int nt = 0; nt < 4; ++nt) {
    int n0 = nc * 128 + nt * 32;
    __syncthreads();
    {
      size_t gi = (size_t)b * (Nn * Cc) + (size_t)(n0 + sr) * 512 + h * 64 + sd8;
      half8 kv = *(const half8*)(K + gi);
      half8 vv = *(const half8*)(V + gi);
      float4 k0 = {(float)kv[0], (float)kv[1], (float)kv[2], (float)kv[3]};
      float4 k1 = {(float)kv[4], (float)kv[5], (float)kv[6], (float)kv[7]};
      float4 v0 = {(float)vv[0], (float)vv[1], (float)vv[2], (float)vv[3]};
      float4 v1 = {(float)vv[4], (float)vv[5], (float)vv[6], (float)vv[7]};
      *(float4*)&Ks[sr * 68 + sd8] = k0;
      *(float4*)&Ks[sr * 68 + sd8 + 4] = k1;
      *(float4*)&Vs[sr * 68 + sd8] = v0;
      *(float4*)&Vs[sr * 68 + sd8 + 4] = v1;
    }
    __syncthreads();
    {
      const float4* q0p = (const float4*)&qls[(jq * 2) * 68];
      const float4* q1p = (const float4*)&qls[(jq * 2 + 1) * 68];
      const float4* k0p = (const float4*)&Ks[(nq * 2) * 68];
      const float4* k1p = (const float4*)&Ks[(nq * 2 + 1) * 68];
      float s00 = 0.f, s01 = 0.f, s10 = 0.f, s11 = 0.f;
#pragma unroll
      for (int i = 0; i < 16; ++i) {
        int dq = (i + tid) & 15;
        float4 q0 = q0p[dq], q1 = q1p[dq];
        float4 k0 = k0p[dq], k1 = k1p[dq];
        s00 += fabsf(q0.x - k0.x) + fabsf(q0.y - k0.y) + fabsf(q0.z - k0.z) + fabsf(q0.w - k0.w);
        s01 += fabsf(q0.x - k1.x) + fabsf(q0.y - k1.y) + fabsf(q0.z - k1.z) + fabsf(q0.w - k1.w);
        s10 += fabsf(q1.x - k0.x) + fabsf(q1.y - k0.y) + fabsf(q1.z - k0.z) + fabsf(q1.w - k0.w);
        s11 += fabsf(q1.x - k1.x) + fabsf(q1.y - k1.y) + fabsf(q1.z - k1.z) + fabsf(q1.w - k1.w);
      }
      P[(nq * 2) * 36 + jq * 2] = expf(-s00 * 0.25f);
      P[(nq * 2) * 36 + jq * 2 + 1] = expf(-s10 * 0.25f);
      P[(nq * 2 + 1) * 36 + jq * 2] = expf(-s01 * 0.25f);
      P[(nq * 2 + 1) * 36 + jq * 2 + 1] = expf(-s11 * 0.25f);
    }
    __syncthreads();
    {
#pragma unroll 4
      for (int n = 0; n < 32; ++n) {
        float p = P[n * 36 + jl];
        float4 v0 = *(const float4*)&Vs[n * 68 + dq2 * 8];
        float4 v1 = *(const float4*)&Vs[n * 68 + dq2 * 8 + 4];
        acc[0] += p * v0.x; acc[1] += p * v0.y; acc[2] += p * v0.z; acc[3] += p * v0.w;
        acc[4] += p * v1.x; acc[5] += p * v1.y; acc[6] += p * v1.z; acc[7] += p * v1.w;
      }
    }
  }
  {
    float lm = LM[b * 128 + j0 + jl];
    float* dst = &KTVp[((size_t)nc * 16 + bh) * 8192 + (size_t)(j0 + jl) * 64 + dq2 * 8];
    float4 o0 = {acc[0] * lm, acc[1] * lm, acc[2] * lm, acc[3] * lm};
    float4 o1 = {acc[4] * lm, acc[5] * lm, acc[6] * lm, acc[7] * lm};
    *(float4*)dst = o0;
    *(float4*)(dst + 4) = o1;
  }
}

// ---------------------------------------------------------------------------
// K8: ctx v2 — fused nc-reduction of KTVp (LDS) + CTX = X @ KTV.
__global__ __launch_bounds__(256) void ctx_kernel(const float* __restrict__ X,
                                                  const float* __restrict__ KTVp,
                                                  __half* __restrict__ CTX) {
  int it = blockIdx.x;  // 0..7
  int bh = blockIdx.y;  // 16
  int i0 = it * 16;
  __shared__ __align__(16) float KTVs[8192];
  __shared__ float Xs[16][132];
  int tid = threadIdx.x;
  const float4* src = (const float4*)KTVp;
  for (int e = tid; e < 2048; e += 256) {
    float4 s = src[(size_t)bh * 2048 + e];
#pragma unroll
    for (int nc = 1; nc < 8; ++nc) {
      float4 v = src[((size_t)nc * 16 + bh) * 2048 + e];
      s.x += v.x; s.y += v.y; s.z += v.z; s.w += v.w;
    }
    *(float4*)&KTVs[e * 4] = s;
  }
  for (int e = tid; e < 2048; e += 256)
    Xs[e >> 7][e & 127] = X[(size_t)bh * 16384 + (size_t)(i0 + (e >> 7)) * 128 + (e & 127)];
  __syncthreads();
  int il = tid >> 4, dg = tid & 15;
  float a0 = 0.f, a1 = 0.f, a2 = 0.f, a3 = 0.f;
#pragma unroll 4
  for (int j = 0; j < 128; ++j) {
    float xv = Xs[il][j];
    float4 kv = *(const float4*)&KTVs[j * 64 + dg * 4];
    a0 += xv * kv.x; a1 += xv * kv.y; a2 += xv * kv.z; a3 += xv * kv.w;
  }
  size_t ob = (size_t)bh * 8192 + (size_t)(i0 + il) * 64 + dg * 4;
  CTX[ob] = f2h(a0);
  CTX[ob + 1] = f2h(a1);
  CTX[ob + 2] = f2h(a2);
  CTX[ob + 3] = f2h(a3);
}

// ---------------------------------------------------------------------------
// K9: stats_partial v4 — ktv-style j-split: grid (4 jt, 16 bh, 8 nc).
// Computes C_q tile, writes Pbuf, accumulates per-j stats partials -> PS.
__global__ __launch_bounds__(256) void stats_partial(
    const __half* __restrict__ Q, const __half* __restrict__ KL,
    const float* __restrict__ LM, const float* __restrict__ tm,
    float* __restrict__ PS, __half* __restrict__ Pbuf) {
  int jt = blockIdx.x;   // 4 (32 j each)
  int bh = blockIdx.y;   // 16
  int nc = blockIdx.z;   // 8 (128 n each)
  int b = bh >> 3, h = bh & 7;
  int j0 = jt * 32;
  __shared__ __align__(16) float kls[32 * 68];
  __shared__ __align__(16) float Qs[32 * 68];
  __shared__ float red[32 * 8 * 3];
  int tid = threadIdx.x;
  int sr = tid >> 3, sd8 = (tid & 7) * 8;
  {
    half8 q = *(const half8*)(KL + (size_t)bh * 8192 + (size_t)(j0 + sr) * 64 + sd8);
    float4 f0 = {(float)q[0], (float)q[1], (float)q[2], (float)q[3]};
    float4 f1 = {(float)q[4], (float)q[5], (float)q[6], (float)q[7]};
    *(float4*)&kls[sr * 68 + sd8] = f0;
    *(float4*)&kls[sr * 68 + sd8 + 4] = f1;
  }
  int jq = tid & 15, nq = tid >> 4;
  int jA = j0 + jq * 2, jB = jA + 1;
  float lmA = LM[b * 128 + jA], lmB = LM[b * 128 + jB];
  float aA1 = 0.f, aA2 = 0.f, aA3 = 0.f, aB1 = 0.f, aB2 = 0.f, aB3 = 0.f;
  for (int nt = 0; nt < 4; ++nt) {
    int n0 = nc * 128 + nt * 32;
    __syncthreads();
    {
      size_t gi = (size_t)b * (Nn * Cc) + (size_t)(n0 + sr) * 512 + h * 64 + sd8;
      half8 kv = *(const half8*)(Q + gi);
      float4 k0 = {(float)kv[0], (float)kv[1], (float)kv[2], (float)kv[3]};
      float4 k1 = {(float)kv[4], (float)kv[5], (float)kv[6], (float)kv[7]};
      *(float4*)&Qs[sr * 68 + sd8] = k0;
      *(float4*)&Qs[sr * 68 + sd8 + 4] = k1;
    }
    __syncthreads();
    const float4* q0p = (const float4*)&kls[(jq * 2) * 68];
    const float4* q1p = (const float4*)&kls[(jq * 2 + 1) * 68];
    const float4* k0p = (const float4*)&Qs[(nq * 2) * 68];
    const float4* k1p = (const float4*)&Qs[(nq * 2 + 1) * 68];
    float s00 = 0.f, s01 = 0.f, s10 = 0.f, s11 = 0.f;
#pragma unroll
    for (int i = 0; i < 16; ++i) {
      int dq = (i + tid) & 15;
      float4 q0 = q0p[dq], q1 = q1p[dq];
      float4 k0 = k0p[dq], k1 = k1p[dq];
      s00 += fabsf(q0.x - k0.x) + fabsf(q0.y - k0.y) + fabsf(q0.z - k0.z) + fabsf(q0.w - k0.w);
      s01 += fabsf(q0.x - k1.x) + fabsf(q0.y - k1.y) + fabsf(q0.z - k1.z) + fabsf(q0.w - k1.w);
      s10 += fabsf(q1.x - k0.x) + fabsf(q1.y - k0.y) + fabsf(q1.z - k0.z) + fabsf(q1.w - k0.w);
      s11 += fabsf(q1.x - k1.x) + fabsf(q1.y - k1.y) + fabsf(q1.z - k1.z) + fabsf(q1.w - k1.w);
    }
    int nA = n0 + nq * 2, nB = nA + 1;
    float tA = tm[b * 1024 + nA], tB = tm[b * 1024 + nB];
    float xAa = expf(-s00 * 0.25f) * lmA;  // (jA, nA)
    float xAb = expf(-s01 * 0.25f) * lmA;  // (jA, nB)
    float xBa = expf(-s10 * 0.25f) * lmB;  // (jB, nA)
    float xBb = expf(-s11 * 0.25f) * lmB;  // (jB, nB)
    Pbuf[((size_t)bh * 1024 + nA) * 128 + jA] = f2h(xAa);
    Pbuf[((size_t)bh * 1024 + nB) * 128 + jA] = f2h(xAb);
    Pbuf[((size_t)bh * 1024 + nA) * 128 + jB] = f2h(xBa);
    Pbuf[((size_t)bh * 1024 + nB) * 128 + jB] = f2h(xBb);
    float xt;
    xt = xAa * tA; aA1 += xt; aA2 += xt * xt; aA3 += xt * tA;
    xt = xAb * tB; aA1 += xt; aA2 += xt * xt; aA3 += xt * tB;
    xt = xBa * tA; aB1 += xt; aB2 += xt * xt; aB3 += xt * tA;
    xt = xBb * tB; aB1 += xt; aB2 += xt * xt; aB3 += xt * tB;
  }
  int jl = jq * 2;
  red[(jl * 8 + nq) * 3 + 0] = aA1;
  red[(jl * 8 + nq) * 3 + 1] = aA2;
  red[(jl * 8 + nq) * 3 + 2] = aA3;
  red[((jl + 1) * 8 + nq) * 3 + 0] = aB1;
  red[((jl + 1) * 8 + nq) * 3 + 1] = aB2;
  red[((jl + 1) * 8 + nq) * 3 + 2] = aB3;
  __syncthreads();
  if (tid < 32) {
    float s1 = 0.f, s2 = 0.f, s3 = 0.f;
#pragma unroll
    for (int q = 0; q < 8; ++q) {
      s1 += red[(tid * 8 + q) * 3 + 0];
      s2 += red[(tid * 8 + q) * 3 + 1];
      s3 += red[(tid * 8 + q) * 3 + 2];
    }
    size_t base = ((size_t)(nc * 16 + bh) * 128 + j0 + tid) * 3;
    PS[base] = s1; PS[base + 1] = s2; PS[base + 2] = s3;
  }
}

// ---------------------------------------------------------------------------
// K10: stats_final v2 — reduce PS over 16 (nc,b) slots per (h,j).
__global__ __launch_bounds__(256) void stats_final(const float* __restrict__ PS,
                                                   const float* __restrict__ tm,
                                                   float* __restrict__ MU,
                                                   float* __restrict__ RS) {
  __shared__ float red[256][2];
  __shared__ float ts0, ts1;
  int tid = threadIdx.x;
  float a = 0.f, c = 0.f;
  for (int i = tid; i < 2048; i += 256) { float t = tm[i]; a += t; c += t * t; }
  red[tid][0] = a; red[tid][1] = c;
  __syncthreads();
  for (int off = 128; off > 0; off >>= 1) {
    if (tid < off) { red[tid][0] += red[tid + off][0]; red[tid][1] += red[tid + off][1]; }
    __syncthreads();
  }
  if (tid == 0) { ts0 = red[0][0]; ts1 = red[0][1]; }
  __syncthreads();
  int hj = blockIdx.x * 256 + tid;
  int h = hj >> 7, j = hj & 127;
  float s1 = 0.f, s2 = 0.f, s3 = 0.f;
#pragma unroll
  for (int nc = 0; nc < 8; ++nc)
#pragma unroll
    for (int b = 0; b < 2; ++b) {
      const float* p = PS + ((size_t)(nc * 16 + b * 8 + h) * 128 + j) * 3;
      s1 += p[0]; s2 += p[1]; s3 += p[2];
    }
  float valid = fmaxf(ts0, 1.f);
  float mu = s1 / valid;
  float var = (s2 - 2.f * mu * s3 + mu * mu * ts1) / valid;
  var = fmaxf(var, 0.f);
  MU[hj] = mu;
  RS[hj] = rsqrtf(var + WHITE_EPS);
}

// ---------------------------------------------------------------------------
// K12: ga v3 — P whiten @ context + inline scrambled depthwise conv; writes
// VL once.
__global__ __launch_bounds__(256) void ga_fused(
    const __half* __restrict__ Pbuf, const float* __restrict__ MU,
    const float* __restrict__ RS, const __half* __restrict__ CTXg,
    const __half* __restrict__ V, const float* __restrict__ dwc_w,
    const float* __restrict__ dwc_b, const float* __restrict__ tm,
    __half* __restrict__ VL) {
  int bh = blockIdx.y;
  int b = bh >> 3, h = bh & 7;
  int n0 = blockIdx.x * 16;
  __shared__ __half Ps[16][130];
  __shared__ __align__(16) __half2 ctx2[128][32];
  __shared__ float musr[128][2];
  int tid = threadIdx.x;
  for (int e = tid; e < 2048; e += 256)
    Ps[e >> 7][e & 127] = Pbuf[((size_t)bh * 1024 + n0 + (e >> 7)) * 128 + (e & 127)];
  {
    const __half2* cg = (const __half2*)(CTXg + (size_t)bh * 8192);
    for (int e = tid; e < 4096; e += 256) ctx2[e >> 5][e & 31] = cg[e];
  }
  if (tid < 128) { musr[tid][0] = MU[h * 128 + tid]; musr[tid][1] = RS[h * 128 + tid]; }
  __syncthreads();
  int nn = tid >> 4, dq = tid & 15;
  float a0 = 0.f, a1 = 0.f, a2 = 0.f, a3 = 0.f;
#pragma unroll 4
  for (int j = 0; j < 128; ++j) {
    float pj = (h2f(Ps[nn][j]) - musr[j][0]) * musr[j][1];
    uint2 cc = *(const uint2*)&ctx2[j][dq * 2];
    __half2 c01 = __builtin_bit_cast(__half2, cc.x);
    __half2 c23 = __builtin_bit_cast(__half2, cc.y);
    a0 += pj * h2f(c01.x); a1 += pj * h2f(c01.y);
    a2 += pj * h2f(c23.x); a3 += pj * h2f(c23.y);
  }
  int t = n0 + nn;
  float tmv = tm[b * 1024 + t];
  float t2 = tmv * tmv;
  float acc[4] = {a0 * t2, a1 * t2, a2 * t2, a3 * t2};
#pragma unroll
  for (int q = 0; q < 4; ++q) {
    int c = h * 64 + dq * 4 + q;
    float vacc = dwc_b[c];
#pragma unroll
    for (int k = 0; k < 3; ++k) {
      int u = t - 1 + k;
      if (u >= 0 && u < 1024) {
        int n = 2 * c + (u >> 9), ch = u & 511;
        vacc += dwc_w[c * 3 + k] * h2f(V[(size_t)b * (Nn * Cc) + (size_t)n * 512 + ch]);
      }
    }
    acc[q] += vacc * tmv;
  }
  size_t base = (size_t)b * (Nn * Cc) + (size_t)t * 512 + h * 64 + dq * 4;
  VL[base] = f2h(acc[0]);
  VL[base + 1] = f2h(acc[1]);
  VL[base + 2] = f2h(acc[2]);
  VL[base + 3] = f2h(acc[3]);
}

// ---------------------------------------------------------------------------
// K13: proj via MFMA f16. M=2048, N=512, K=512.
__global__ __launch_bounds__(256) void proj_gemm(
    const __half* __restrict__ Ain, const float* __restrict__ w,
    const float* __restrict__ bias, const float* __restrict__ tm,
    float* __restrict__ out) {
  __shared__ _Float16 As[128 * 40];
  __shared__ _Float16 Bs[128 * 40];
  int m0 = blockIdx.x * 128, n0 = blockIdx.y * 128;
  int tid = threadIdx.x;
  int lane = tid & 63, wv = tid >> 6;
  int wm = (wv >> 1) * 64, wn = (wv & 1) * 64;
  int l15 = lane & 15, quad = lane >> 4;
  int srow = tid >> 1, shalf = tid & 1;
  float4v acc[4][4] = {};
  for (int k0 = 0; k0 < 512; k0 += 32) {
    __syncthreads();
    {
      const half8* ga = (const half8*)(Ain + (size_t)(m0 + srow) * 512 + k0 + shalf * 16);
      const float4* gb = (const float4*)(w + (size_t)(n0 + srow) * 512 + k0 + shalf * 16);
      half8 ha0 = ga[0], ha1 = ga[1];
      float4 b0 = gb[0], b1 = gb[1], b2 = gb[2], b3 = gb[3];
      half8 hb0 = {(_Float16)b0.x, (_Float16)b0.y, (_Float16)b0.z, (_Float16)b0.w,
                   (_Float16)b1.x, (_Float16)b1.y, (_Float16)b1.z, (_Float16)b1.w};
      half8 hb1 = {(_Float16)b2.x, (_Float16)b2.y, (_Float16)b2.z, (_Float16)b2.w,
                   (_Float16)b3.x, (_Float16)b3.y, (_Float16)b3.z, (_Float16)b3.w};
      int lo = srow * 40 + shalf * 16;
      *(half8*)&As[lo] = ha0;
      *(half8*)&As[lo + 8] = ha1;
      *(half8*)&Bs[lo] = hb0;
      *(half8*)&Bs[lo + 8] = hb1;
    }
    __syncthreads();
    half8 a[4], b[4];
#pragma unroll
    for (int mt = 0; mt < 4; ++mt)
      a[mt] = *(const half8*)&As[(wm + mt * 16 + l15) * 40 + quad * 8];
#pragma unroll
    for (int nt = 0; nt < 4; ++nt)
      b[nt] = *(const half8*)&Bs[(wn + nt * 16 + l15) * 40 + quad * 8];
#pragma unroll
    for (int mt = 0; mt < 4; ++mt)
#pragma unroll
      for (int nt = 0; nt < 4; ++nt)
        acc[mt][nt] =
            __builtin_amdgcn_mfma_f32_16x16x32_f16(a[mt], b[nt], acc[mt][nt], 0, 0, 0);
  }
#pragma unroll
  for (int mt = 0; mt < 4; ++mt) {
#pragma unroll
    for (int r = 0; r < 4; ++r) {
      int row = m0 + wm + mt * 16 + quad * 4 + r;
      int b_ = row >> 10, n_ = row & 1023;
      float t = tm[b_ * 1024 + n_];
#pragma unroll
      for (int nt = 0; nt < 4; ++nt) {
        int co = n0 + wn + nt * 16 + l15;
        out[(size_t)row * 512 + co] = (acc[mt][nt][r] + bias[co]) * t;
      }
    }
  }
}

// ---------------------------------------------------------------------------
// d_ws 11.26 MiB (proven). d_out (4 MiB): Wf f32 (NS) -> KTVp f32 partials
// (ktv->ctx) -> Pbuf f16 (stats->ga) -> final f32 output. Stream-ordered.
extern "C" void kernel_launch(void* const* d_in, const int* in_sizes, int n_in,
                              void* d_out, int out_size, void* d_ws, size_t ws_size,
                              hipStream_t stream) {
  const float* x      = (const float*)d_in[0];
  const float* tm     = (const float*)d_in[1];
  const float* qkv_w  = (const float*)d_in[2];
  const float* qkv_b  = (const float*)d_in[3];
  const float* proj_w = (const float*)d_in[4];
  const float* proj_b = (const float*)d_in[5];
  const float* dwc_w  = (const float*)d_in[6];
  const float* dwc_b  = (const float*)d_in[7];
  float* out = (float*)d_out;

  char* wsb = (char*)d_ws;
  __half* Qh  = (__half*)(wsb + 0);
  __half* Kh  = (__half*)(wsb + 2097152);
  __half* Vh  = (__half*)(wsb + 4194304);
  __half* VLh = (__half*)(wsb + 6291456);
  __half* QLh = (__half*)(wsb + 8388608);
  __half* KLh = (__half*)(wsb + 8650752);
  float*  LM  = (float*)(wsb + 8912896);
  float*  MU  = (float*)(wsb + 8913920);
  float*  RS  = (float*)(wsb + 8918016);
  __half* CTX = (__half*)(wsb + 9446400);
  float*  XA  = (float*)(wsb + 9708544);
  float*  PS  = (float*)(wsb + 9708544 + 1048576);

  char* ob = (char*)d_out;
  float*  Wf   = (float*)ob;     // NS phase
  float*  KTVp = (float*)ob;     // ktv partials (4 MiB, after NS)
  __half* Pbuf = (__half*)ob;    // stats->ga phase

  qkv_gemm<<<dim3(16, 12), 256, 0, stream>>>(x, qkv_w, qkv_b, tm, Qh, Kh, Vh);
  pool_kernel<<<dim3(16, 16), 256, 0, stream>>>(Qh, Kh, tm, QLh, KLh, LM);
  wbuild_kernel<<<dim3(8, 16), 256, 0, stream>>>(QLh, KLh, LM, Wf);
  ns_solve<<<16, 256, 0, stream>>>(Wf, XA);
  ktv_fused<<<dim3(4, 16, 8), 256, 0, stream>>>(Kh, QLh, LM, Vh, KTVp);
  ctx_kernel<<<dim3(8, 16), 256, 0, stream>>>(XA, KTVp, CTX);
  stats_partial<<<dim3(4, 16, 8), 256, 0, stream>>>(Qh, KLh, LM, tm, PS, Pbuf);
  stats_final<<<4, 256, 0, stream>>>(PS, tm, MU, RS);
  ga_fused<<<dim3(64, 16), 256, 0, stream>>>(Pbuf, MU, RS, CTX, Vh, dwc_w, dwc_b, tm, VLh);
  proj_gemm<<<dim3(16, 4), 256, 0, stream>>>(VLh, proj_w, proj_b, tm, out);
}